// Round 1
// baseline (2058.234 us; speedup 1.0000x reference)
//
#include <hip/hip_runtime.h>
#include <hip/hip_bf16.h>
#include <math.h>

// Fused MHA block: proj(Q,K,V) -> masked softmax attention -> out proj + residual -> LayerNorm
// Round 1: fp32 correctness-first baseline. All GEMMs tiled fp32 (64x64 block, 4x4 micro),
// flash-style attention with in-register online softmax. MFMA conversion planned next.

#define D_MODEL 1024
#define NHEADS  16
#define DHEAD   64
#define BATCH   2
#define SEQ     2048
#define MROWS   (BATCH * SEQ)   // 4096

// ---------------------------------------------------------------------------
// Mask dtype probe: harness may hand us bool as uint8 (1B), int32, or float32.
// Sample 64K words: all in {0,1} -> int32; all in {0,0x3F800000} -> float32; else uint8.
// Deterministic (same input every call).
// ---------------------------------------------------------------------------
__global__ void detect_mask(const unsigned int* __restrict__ m, int nwords,
                            int* __restrict__ flag) {
    __shared__ int not01, notf;
    if (threadIdx.x == 0) { not01 = 0; notf = 0; }
    __syncthreads();
    int a = 0, b = 0;
    for (int i = threadIdx.x; i < nwords; i += blockDim.x) {
        unsigned int w = m[i];
        if (w != 0u && w != 1u) a = 1;
        if (w != 0u && w != 0x3F800000u) b = 1;
    }
    if (a) atomicOr(&not01, 1);
    if (b) atomicOr(&notf, 1);
    __syncthreads();
    if (threadIdx.x == 0) {
        int f;
        if (!not01) f = 0;        // int32 0/1
        else if (!notf) f = 1;    // float32 0.0/1.0
        else f = 2;               // uint8 0/1
        *flag = f;
    }
}

// ---------------------------------------------------------------------------
// C[M,N] = A[M,K] @ W[K,N] + bias[N] (+ resid[M,N] if non-null)
// 64x64 block tile, BK=16, 256 threads, 4x4 micro-tile, float4 LDS reads.
// ---------------------------------------------------------------------------
__global__ __launch_bounds__(256) void gemm64(
    const float* __restrict__ A, const float* __restrict__ W,
    const float* __restrict__ bias, const float* __restrict__ resid,
    float* __restrict__ C, int M, int N, int K)
{
    __shared__ float As[16][64];   // [k][m]
    __shared__ float Bs[16][64];   // [k][n]
    const int tid = threadIdx.x;
    const int tx = tid & 15;       // n-group
    const int ty = tid >> 4;       // m-group
    const int bm = blockIdx.y * 64;
    const int bn = blockIdx.x * 64;

    const int arow = tid >> 2;            // 0..63
    const int acol = (tid & 3) << 2;      // 0,4,8,12
    const int brow = tid >> 4;            // 0..15
    const int bcol = (tid & 15) << 2;     // 0..60

    const float* Ap = A + (size_t)(bm + arow) * K + acol;
    const float* Wp = W + (size_t)brow * N + (bn + bcol);

    float acc[4][4] = {};

    for (int k0 = 0; k0 < K; k0 += 16) {
        float4 av = *(const float4*)(Ap + k0);
        float4 wv = *(const float4*)(Wp + (size_t)k0 * N);
        As[acol + 0][arow] = av.x;
        As[acol + 1][arow] = av.y;
        As[acol + 2][arow] = av.z;
        As[acol + 3][arow] = av.w;
        *(float4*)&Bs[brow][bcol] = wv;
        __syncthreads();
        #pragma unroll
        for (int kk = 0; kk < 16; ++kk) {
            float4 a = *(const float4*)&As[kk][ty << 2];
            float4 b = *(const float4*)&Bs[kk][tx << 2];
            float a_[4] = {a.x, a.y, a.z, a.w};
            float b_[4] = {b.x, b.y, b.z, b.w};
            #pragma unroll
            for (int i = 0; i < 4; ++i)
                #pragma unroll
                for (int j = 0; j < 4; ++j)
                    acc[i][j] += a_[i] * b_[j];
        }
        __syncthreads();
    }

    float4 bv = *(const float4*)(bias + bn + (tx << 2));
    float b_[4] = {bv.x, bv.y, bv.z, bv.w};
    #pragma unroll
    for (int i = 0; i < 4; ++i) {
        const int row = bm + (ty << 2) + i;
        float o[4];
        #pragma unroll
        for (int j = 0; j < 4; ++j) o[j] = acc[i][j] + b_[j];
        if (resid) {
            float4 r = *(const float4*)(resid + (size_t)row * N + bn + (tx << 2));
            o[0] += r.x; o[1] += r.y; o[2] += r.z; o[3] += r.w;
        }
        float4 ov = make_float4(o[0], o[1], o[2], o[3]);
        *(float4*)(C + (size_t)row * N + bn + (tx << 2)) = ov;
    }
}

// ---------------------------------------------------------------------------
// Flash-style attention, fp32. Block = (b, h, 64 q-rows), 256 threads.
// Q pre-scaled by 1/8 (exact). K-tile XOR-swizzled in 16B chunks (chunk ^= row>>2)
// to break the stride-256B same-bank pattern on QK^T reads.
// Online softmax fully in-register via 16-lane shfl_xor groups.
// ---------------------------------------------------------------------------
__global__ __launch_bounds__(256) void attn64(
    const float* __restrict__ qw, const float* __restrict__ kw,
    const float* __restrict__ vw, const void* __restrict__ mask,
    const int* __restrict__ mflag, float* __restrict__ ctx)
{
    __shared__ float Qs[64][64];
    __shared__ float Ks[64][64];   // swizzled
    __shared__ float Vs[64][64];
    __shared__ float Ps[64][64];

    const int tid = threadIdx.x;
    const int tx = tid & 15;       // k-group in phase A, d-group in phase C
    const int ty = tid >> 4;       // q-group
    const int q0 = blockIdx.x * 64;
    const int h  = blockIdx.y;
    const int b  = blockIdx.z;

    const size_t base = (size_t)b * SEQ * D_MODEL + (size_t)h * DHEAD;

    // load Q tile, pre-scaled by 1/sqrt(64)=0.125 (exact in fp32)
    #pragma unroll
    for (int u = 0; u < 4; ++u) {
        int f = tid + 256 * u;        // 0..1023
        int r = f >> 4;
        int c4 = f & 15;
        float4 v = *(const float4*)(qw + base + (size_t)(q0 + r) * D_MODEL + (c4 << 2));
        v.x *= 0.125f; v.y *= 0.125f; v.z *= 0.125f; v.w *= 0.125f;
        *(float4*)&Qs[r][c4 << 2] = v;
    }

    float acc[4][4] = {};
    float m_i[4], l_i[4];
    #pragma unroll
    for (int i = 0; i < 4; ++i) { m_i[i] = -INFINITY; l_i[i] = 0.f; }

    const int mf = *mflag;
    const size_t mbase = (size_t)b * SEQ * SEQ;

    for (int kt = 0; kt < SEQ / 64; ++kt) {
        __syncthreads();   // previous phase C done before overwriting K/V/P
        #pragma unroll
        for (int u = 0; u < 4; ++u) {
            int f = tid + 256 * u;
            int r = f >> 4;
            int c4 = f & 15;
            size_t goff = base + (size_t)(kt * 64 + r) * D_MODEL + (c4 << 2);
            float4 kv = *(const float4*)(kw + goff);
            *(float4*)&Ks[r][(c4 ^ (r >> 2)) << 2] = kv;
            float4 vv = *(const float4*)(vw + goff);
            *(float4*)&Vs[r][c4 << 2] = vv;
        }
        __syncthreads();

        // phase A: s[i][j] = Qs[ty*4+i][:] . K[tx*4+j][:]
        float s[4][4] = {};
        #pragma unroll
        for (int d0 = 0; d0 < 64; d0 += 4) {
            float4 qv[4];
            #pragma unroll
            for (int i = 0; i < 4; ++i)
                qv[i] = *(const float4*)&Qs[(ty << 2) + i][d0];
            #pragma unroll
            for (int j = 0; j < 4; ++j) {
                const int kr = (tx << 2) + j;                 // kr>>2 == tx
                float4 kv = *(const float4*)&Ks[kr][((d0 >> 2) ^ tx) << 2];
                #pragma unroll
                for (int i = 0; i < 4; ++i)
                    s[i][j] += qv[i].x * kv.x + qv[i].y * kv.y
                             + qv[i].z * kv.z + qv[i].w * kv.w;
            }
        }

        // mask: attn_mask[b][q][k] true -> -1e9
        #pragma unroll
        for (int i = 0; i < 4; ++i) {
            size_t mi = mbase + (size_t)(q0 + (ty << 2) + i) * SEQ
                      + (size_t)(kt * 64 + (tx << 2));
            if (mf == 2) {
                uchar4 mv = *(const uchar4*)((const unsigned char*)mask + mi);
                if (mv.x) s[i][0] = -1e9f;
                if (mv.y) s[i][1] = -1e9f;
                if (mv.z) s[i][2] = -1e9f;
                if (mv.w) s[i][3] = -1e9f;
            } else if (mf == 0) {
                int4 mv = *(const int4*)((const int*)mask + mi);
                if (mv.x) s[i][0] = -1e9f;
                if (mv.y) s[i][1] = -1e9f;
                if (mv.z) s[i][2] = -1e9f;
                if (mv.w) s[i][3] = -1e9f;
            } else {
                float4 mv = *(const float4*)((const float*)mask + mi);
                if (mv.x != 0.f) s[i][0] = -1e9f;
                if (mv.y != 0.f) s[i][1] = -1e9f;
                if (mv.z != 0.f) s[i][2] = -1e9f;
                if (mv.w != 0.f) s[i][3] = -1e9f;
            }
        }

        // phase B: in-register online softmax across the 16 lanes sharing ty
        #pragma unroll
        for (int i = 0; i < 4; ++i) {
            float rm = fmaxf(fmaxf(s[i][0], s[i][1]), fmaxf(s[i][2], s[i][3]));
            #pragma unroll
            for (int off = 1; off < 16; off <<= 1)
                rm = fmaxf(rm, __shfl_xor(rm, off, 64));
            const float mnew = fmaxf(m_i[i], rm);
            const float alpha = expf(m_i[i] - mnew);   // exp(-inf)=0 first tile
            float4 p;
            p.x = expf(s[i][0] - mnew);
            p.y = expf(s[i][1] - mnew);
            p.z = expf(s[i][2] - mnew);
            p.w = expf(s[i][3] - mnew);
            float ps = p.x + p.y + p.z + p.w;
            #pragma unroll
            for (int off = 1; off < 16; off <<= 1)
                ps += __shfl_xor(ps, off, 64);
            l_i[i] = l_i[i] * alpha + ps;
            m_i[i] = mnew;
            #pragma unroll
            for (int j = 0; j < 4; ++j) acc[i][j] *= alpha;
            *(float4*)&Ps[(ty << 2) + i][tx << 2] = p;
        }
        __syncthreads();

        // phase C: acc[i][j] += sum_k P[qr][k] * V[k][tx*4+j]
        #pragma unroll
        for (int k0 = 0; k0 < 64; k0 += 4) {
            float4 pv[4];
            #pragma unroll
            for (int i = 0; i < 4; ++i)
                pv[i] = *(const float4*)&Ps[(ty << 2) + i][k0];
            float4 vv[4];
            #pragma unroll
            for (int t = 0; t < 4; ++t)
                vv[t] = *(const float4*)&Vs[k0 + t][tx << 2];
            #pragma unroll
            for (int i = 0; i < 4; ++i) {
                float p_[4] = {pv[i].x, pv[i].y, pv[i].z, pv[i].w};
                #pragma unroll
                for (int t = 0; t < 4; ++t) {
                    float v_[4] = {vv[t].x, vv[t].y, vv[t].z, vv[t].w};
                    #pragma unroll
                    for (int j = 0; j < 4; ++j)
                        acc[i][j] += p_[t] * v_[j];
                }
            }
        }
    }

    // epilogue: ctx[b][q][h*64+d] = acc / l
    #pragma unroll
    for (int i = 0; i < 4; ++i) {
        const float inv = 1.f / l_i[i];
        float4 o = make_float4(acc[i][0] * inv, acc[i][1] * inv,
                               acc[i][2] * inv, acc[i][3] * inv);
        *(float4*)(ctx + base + (size_t)(q0 + (ty << 2) + i) * D_MODEL + (tx << 2)) = o;
    }
}

// ---------------------------------------------------------------------------
// LayerNorm over last dim (1024). One block per row, 256 threads, float4 each.
// Biased variance (jnp.var). Newton-refined rsqrt for accuracy.
// ---------------------------------------------------------------------------
__global__ __launch_bounds__(256) void layernorm1024(
    const float* __restrict__ x, const float* __restrict__ gamma,
    const float* __restrict__ beta, float* __restrict__ out)
{
    const int row = blockIdx.x;
    const int tid = threadIdx.x;
    const float* xr = x + (size_t)row * D_MODEL;
    float4 v = *(const float4*)(xr + (tid << 2));
    float s = v.x + v.y + v.z + v.w;
    float q = v.x * v.x + v.y * v.y + v.z * v.z + v.w * v.w;
    #pragma unroll
    for (int off = 1; off < 64; off <<= 1) {
        s += __shfl_xor(s, off, 64);
        q += __shfl_xor(q, off, 64);
    }
    __shared__ float sw[4], qw_[4];
    const int wid = tid >> 6;
    if ((tid & 63) == 0) { sw[wid] = s; qw_[wid] = q; }
    __syncthreads();
    s = sw[0] + sw[1] + sw[2] + sw[3];
    q = qw_[0] + qw_[1] + qw_[2] + qw_[3];
    const float mu  = s * (1.f / D_MODEL);
    const float var = q * (1.f / D_MODEL) - mu * mu;
    const float a = var + 1e-5f;
    float inv = rsqrtf(a);
    inv = inv * (1.5f - 0.5f * a * inv * inv);   // one Newton step
    float4 g  = *(const float4*)(gamma + (tid << 2));
    float4 bt = *(const float4*)(beta + (tid << 2));
    float4 o;
    o.x = (v.x - mu) * inv * g.x + bt.x;
    o.y = (v.y - mu) * inv * g.y + bt.y;
    o.z = (v.z - mu) * inv * g.z + bt.z;
    o.w = (v.w - mu) * inv * g.w + bt.w;
    *(float4*)(out + (size_t)row * D_MODEL + (tid << 2)) = o;
}

// ---------------------------------------------------------------------------
extern "C" void kernel_launch(void* const* d_in, const int* in_sizes, int n_in,
                              void* d_out, int out_size, void* d_ws, size_t ws_size,
                              hipStream_t stream)
{
    const float* Q    = (const float*)d_in[0];
    const float* K    = (const float*)d_in[1];
    const float* V    = (const float*)d_in[2];
    const void*  mask = d_in[3];
    const float* Wq   = (const float*)d_in[4];
    const float* bq   = (const float*)d_in[5];
    const float* Wk   = (const float*)d_in[6];
    const float* bk   = (const float*)d_in[7];
    const float* Wv   = (const float*)d_in[8];
    const float* bv   = (const float*)d_in[9];
    const float* Wo   = (const float*)d_in[10];
    const float* bo   = (const float*)d_in[11];
    const float* gam  = (const float*)d_in[12];
    const float* bet  = (const float*)d_in[13];
    float* out = (float*)d_out;

    const size_t SZ = (size_t)MROWS * D_MODEL;   // 4.2M floats per buffer
    float* ws   = (float*)d_ws;
    float* q_ws = ws;
    float* k_ws = ws + SZ;
    float* v_ws = ws + 2 * SZ;
    float* ctx  = ws + 3 * SZ;
    float* outp = q_ws;                 // q dead after attention -> reuse
    int*   mflag = (int*)(ws + 4 * SZ);
    if (ws_size < (4 * SZ + 4) * sizeof(float)) return;  // ws too small: fail loud

    detect_mask<<<1, 256, 0, stream>>>((const unsigned int*)mask, 65536, mflag);

    dim3 gg(D_MODEL / 64, MROWS / 64);
    gemm64<<<gg, 256, 0, stream>>>(Q, Wq, bq, nullptr, q_ws, MROWS, D_MODEL, D_MODEL);
    gemm64<<<gg, 256, 0, stream>>>(K, Wk, bk, nullptr, k_ws, MROWS, D_MODEL, D_MODEL);
    gemm64<<<gg, 256, 0, stream>>>(V, Wv, bv, nullptr, v_ws, MROWS, D_MODEL, D_MODEL);

    dim3 ag(SEQ / 64, NHEADS, BATCH);
    attn64<<<ag, 256, 0, stream>>>(q_ws, k_ws, v_ws, mask, mflag, ctx);

    gemm64<<<gg, 256, 0, stream>>>(ctx, Wo, bo, Q, outp, MROWS, D_MODEL, D_MODEL);

    layernorm1024<<<MROWS, 256, 0, stream>>>(outp, gam, bet, out);
}

// Round 2
// 723.278 us; speedup vs baseline: 2.8457x; 2.8457x over previous
//
#include <hip/hip_runtime.h>
#include <hip/hip_bf16.h>
#include <math.h>

// Fused MHA block: proj(Q,K,V) -> masked softmax attention -> out proj + residual -> LayerNorm
// Round 2: attention converted to bf16 MFMA (16x16x32), fp32 accum. Projection GEMMs
// stay fp32 but emit bf16 q/k/v. Mask pre-packed to bitmask. GEMM MFMA conversion next.

#define D_MODEL 1024
#define NHEADS  16
#define DHEAD   64
#define BATCH   2
#define SEQ     2048
#define MROWS   (BATCH * SEQ)   // 4096

typedef __attribute__((ext_vector_type(8))) short bf16x8;
typedef __attribute__((ext_vector_type(4))) float f32x4;

__device__ inline unsigned short f2bf(float f) {
    unsigned int u = __builtin_bit_cast(unsigned int, f);
    unsigned int r = (u + 0x7FFFu + ((u >> 16) & 1u)) >> 16;   // RNE
    return (unsigned short)r;
}

// ---------------------------------------------------------------------------
// Mask dtype probe (bool may arrive as uint8 / int32 / float32).
// ---------------------------------------------------------------------------
__global__ void detect_mask(const unsigned int* __restrict__ m, int nwords,
                            int* __restrict__ flag) {
    __shared__ int not01, notf;
    if (threadIdx.x == 0) { not01 = 0; notf = 0; }
    __syncthreads();
    int a = 0, b = 0;
    for (int i = threadIdx.x; i < nwords; i += blockDim.x) {
        unsigned int w = m[i];
        if (w != 0u && w != 1u) a = 1;
        if (w != 0u && w != 0x3F800000u) b = 1;
    }
    if (a) atomicOr(&not01, 1);
    if (b) atomicOr(&notf, 1);
    __syncthreads();
    if (threadIdx.x == 0) {
        int f;
        if (!not01) f = 0;        // int32 0/1
        else if (!notf) f = 1;    // float32 0.0/1.0
        else f = 2;               // uint8 0/1
        *flag = f;
    }
}

// ---------------------------------------------------------------------------
// Pack mask to 1 bit per entry: mbits[b][q][kword] (kword = 64 keys).
// ---------------------------------------------------------------------------
__global__ __launch_bounds__(256) void pack_mask(
    const void* __restrict__ mask, const int* __restrict__ mflag,
    unsigned long long* __restrict__ mbits, int nwords)
{
    int idx = blockIdx.x * blockDim.x + threadIdx.x;
    if (idx >= nwords) return;
    const int mf = *mflag;
    unsigned long long bits = 0ull;
    if (mf == 2) {
        const unsigned int* p = (const unsigned int*)mask + (size_t)idx * 16;
        #pragma unroll
        for (int i = 0; i < 16; ++i) {
            unsigned int w = p[i] & 0x01010101u;          // bytes are 0/1
            unsigned int nib = (w * 0x01020408u) >> 24;   // b0|b1<<1|b2<<2|b3<<3
            bits |= (unsigned long long)(nib & 0xFu) << (i * 4);
        }
    } else if (mf == 0) {
        const unsigned int* p = (const unsigned int*)mask + (size_t)idx * 64;
        #pragma unroll
        for (int i = 0; i < 64; ++i)
            bits |= (unsigned long long)(p[i] & 1u) << i;
    } else {
        const float* p = (const float*)mask + (size_t)idx * 64;
        #pragma unroll
        for (int i = 0; i < 64; ++i)
            bits |= (unsigned long long)(p[i] != 0.f) << i;
    }
    mbits[idx] = bits;
}

// ---------------------------------------------------------------------------
// C[M,N] = A[M,K] @ W[K,N] + bias[N] (+ resid if non-null).
// 64x64 tile, BK=16, 256 threads, 4x4 micro. OB=true -> bf16 output.
// ---------------------------------------------------------------------------
template<bool OB>
__global__ __launch_bounds__(256) void gemm64(
    const float* __restrict__ A, const float* __restrict__ W,
    const float* __restrict__ bias, const float* __restrict__ resid,
    void* __restrict__ C, int M, int N, int K)
{
    __shared__ float As[16][64];
    __shared__ float Bs[16][64];
    const int tid = threadIdx.x;
    const int tx = tid & 15;
    const int ty = tid >> 4;
    const int bm = blockIdx.y * 64;
    const int bn = blockIdx.x * 64;

    const int arow = tid >> 2;
    const int acol = (tid & 3) << 2;
    const int brow = tid >> 4;
    const int bcol = (tid & 15) << 2;

    const float* Ap = A + (size_t)(bm + arow) * K + acol;
    const float* Wp = W + (size_t)brow * N + (bn + bcol);

    float acc[4][4] = {};

    for (int k0 = 0; k0 < K; k0 += 16) {
        float4 av = *(const float4*)(Ap + k0);
        float4 wv = *(const float4*)(Wp + (size_t)k0 * N);
        As[acol + 0][arow] = av.x;
        As[acol + 1][arow] = av.y;
        As[acol + 2][arow] = av.z;
        As[acol + 3][arow] = av.w;
        *(float4*)&Bs[brow][bcol] = wv;
        __syncthreads();
        #pragma unroll
        for (int kk = 0; kk < 16; ++kk) {
            float4 a = *(const float4*)&As[kk][ty << 2];
            float4 b = *(const float4*)&Bs[kk][tx << 2];
            float a_[4] = {a.x, a.y, a.z, a.w};
            float b_[4] = {b.x, b.y, b.z, b.w};
            #pragma unroll
            for (int i = 0; i < 4; ++i)
                #pragma unroll
                for (int j = 0; j < 4; ++j)
                    acc[i][j] += a_[i] * b_[j];
        }
        __syncthreads();
    }

    float4 bv = *(const float4*)(bias + bn + (tx << 2));
    float b_[4] = {bv.x, bv.y, bv.z, bv.w};
    #pragma unroll
    for (int i = 0; i < 4; ++i) {
        const int row = bm + (ty << 2) + i;
        float o[4];
        #pragma unroll
        for (int j = 0; j < 4; ++j) o[j] = acc[i][j] + b_[j];
        if (resid) {
            float4 r = *(const float4*)(resid + (size_t)row * N + bn + (tx << 2));
            o[0] += r.x; o[1] += r.y; o[2] += r.z; o[3] += r.w;
        }
        if (OB) {
            ushort4 u;
            u.x = f2bf(o[0]); u.y = f2bf(o[1]); u.z = f2bf(o[2]); u.w = f2bf(o[3]);
            *(ushort4*)((unsigned short*)C + (size_t)row * N + bn + (tx << 2)) = u;
        } else {
            *(float4*)((float*)C + (size_t)row * N + bn + (tx << 2)) =
                make_float4(o[0], o[1], o[2], o[3]);
        }
    }
}

// ---------------------------------------------------------------------------
// MFMA flash attention. Block = (b, h, 64 q-rows), 4 waves, 16 q-rows/wave.
// K-tile LDS XOR-swizzled; V staged transposed (Vt[d][key], swizzled).
// Online softmax in C-layout (16-lane shfl groups); P -> bf16 via padded LDS.
// ---------------------------------------------------------------------------
__global__ __launch_bounds__(256) void attn_mfma(
    const unsigned short* __restrict__ qb, const unsigned short* __restrict__ kb,
    const unsigned short* __restrict__ vb,
    const unsigned long long* __restrict__ mbits, float* __restrict__ ctx)
{
    __shared__ unsigned short Ks[64 * 64];      // [key][d] swizzled, 8KB
    __shared__ unsigned short Vt[64 * 64];      // [d][key] swizzled, 8KB
    __shared__ unsigned short Ps[4][16 * 72];   // per-wave P, padded rows (144B)

    const int tid  = threadIdx.x;
    const int lane = tid & 63;
    const int w    = tid >> 6;
    const int lo   = lane & 15;
    const int hi   = lane >> 4;
    const int q0   = blockIdx.x * 64;
    const int h    = blockIdx.y;
    const int b    = blockIdx.z;

    const size_t base = (size_t)b * SEQ * D_MODEL + (size_t)h * DHEAD;

    // Q A-fragments (held for whole kernel): rows q0 + w*16 + lo
    const int qrow = q0 + w * 16 + lo;
    bf16x8 qA[2];
    qA[0] = *(const bf16x8*)(qb + base + (size_t)qrow * D_MODEL + hi * 8);
    qA[1] = *(const bf16x8*)(qb + base + (size_t)qrow * D_MODEL + 32 + hi * 8);

    f32x4 acc[4];
    #pragma unroll
    for (int i = 0; i < 4; ++i) acc[i] = (f32x4){0.f, 0.f, 0.f, 0.f};
    float m_i[4], l_i[4];
    #pragma unroll
    for (int r = 0; r < 4; ++r) { m_i[r] = -INFINITY; l_i[r] = 0.f; }

    // staging roles: thread covers K/V row sr, 16B chunks sc2, sc2+1
    const int sr  = tid >> 2;
    const int sc2 = (tid & 3) * 2;

    const unsigned long long* mrow = mbits + ((size_t)b * SEQ + q0 + w * 16) * (SEQ / 64);

    for (int kt = 0; kt < SEQ / 64; ++kt) {
        __syncthreads();
        // ---- stage K (swizzled) and V (transposed, swizzled) ----
        {
            const unsigned short* ksrc = kb + base + (size_t)(kt * 64 + sr) * D_MODEL + sc2 * 8;
            bf16x8 k0 = *(const bf16x8*)(ksrc);
            bf16x8 k1 = *(const bf16x8*)(ksrc + 8);
            *(bf16x8*)&Ks[sr * 64 + ((sc2    ) ^ (sr & 7)) * 8] = k0;
            *(bf16x8*)&Ks[sr * 64 + ((sc2 + 1) ^ (sr & 7)) * 8] = k1;
            const unsigned short* vsrc = vb + base + (size_t)(kt * 64 + sr) * D_MODEL + sc2 * 8;
            bf16x8 v0 = *(const bf16x8*)(vsrc);
            bf16x8 v1 = *(const bf16x8*)(vsrc + 8);
            #pragma unroll
            for (int j = 0; j < 8; ++j) {
                const int d0 = sc2 * 8 + j;
                const int d1 = d0 + 8;
                Vt[d0 * 64 + (((sr >> 3) ^ (d0 & 7)) * 8) + (sr & 7)] = (unsigned short)v0[j];
                Vt[d1 * 64 + (((sr >> 3) ^ (d1 & 7)) * 8) + (sr & 7)] = (unsigned short)v1[j];
            }
        }
        __syncthreads();

        // ---- mask words (broadcast loads: 4 rows per lane) ----
        unsigned long long mw[4];
        #pragma unroll
        for (int r = 0; r < 4; ++r)
            mw[r] = mrow[(size_t)(hi * 4 + r) * (SEQ / 64) + kt];

        // ---- QK^T: S[16q x 64k] per wave ----
        f32x4 s[4];
        #pragma unroll
        for (int nt = 0; nt < 4; ++nt) s[nt] = (f32x4){0.f, 0.f, 0.f, 0.f};
        #pragma unroll
        for (int nt = 0; nt < 4; ++nt) {
            const int krow = nt * 16 + lo;
            #pragma unroll
            for (int st = 0; st < 2; ++st) {
                bf16x8 kf = *(const bf16x8*)&Ks[krow * 64 + ((st * 4 + hi) ^ (krow & 7)) * 8];
                s[nt] = __builtin_amdgcn_mfma_f32_16x16x32_bf16(qA[st], kf, s[nt], 0, 0, 0);
            }
        }

        // ---- mask + scale + online softmax (per C/D reg row) ----
        #pragma unroll
        for (int r = 0; r < 4; ++r) {
            float sv[4];
            #pragma unroll
            for (int nt = 0; nt < 4; ++nt) {
                float x = s[nt][r] * 0.125f;
                if ((mw[r] >> (nt * 16 + lo)) & 1ull) x = -1e9f;
                sv[nt] = x;
            }
            float rm = fmaxf(fmaxf(sv[0], sv[1]), fmaxf(sv[2], sv[3]));
            rm = fmaxf(rm, __shfl_xor(rm, 1, 64));
            rm = fmaxf(rm, __shfl_xor(rm, 2, 64));
            rm = fmaxf(rm, __shfl_xor(rm, 4, 64));
            rm = fmaxf(rm, __shfl_xor(rm, 8, 64));
            const float mn = fmaxf(m_i[r], rm);
            const float alpha = expf(m_i[r] - mn);
            float p[4], ps = 0.f;
            #pragma unroll
            for (int nt = 0; nt < 4; ++nt) { p[nt] = expf(sv[nt] - mn); ps += p[nt]; }
            ps += __shfl_xor(ps, 1, 64);
            ps += __shfl_xor(ps, 2, 64);
            ps += __shfl_xor(ps, 4, 64);
            ps += __shfl_xor(ps, 8, 64);
            l_i[r] = l_i[r] * alpha + ps;
            m_i[r] = mn;
            #pragma unroll
            for (int nt = 0; nt < 4; ++nt) acc[nt][r] *= alpha;
            #pragma unroll
            for (int nt = 0; nt < 4; ++nt)
                Ps[w][(hi * 4 + r) * 72 + nt * 16 + lo] = f2bf(p[nt]);
        }

        // ---- PV: acc[16q x 64d] += P[16q x 64k] @ V[64k x 64d] ----
        #pragma unroll
        for (int ks = 0; ks < 2; ++ks) {
            bf16x8 pf = *(const bf16x8*)&Ps[w][lo * 72 + ks * 32 + hi * 8];
            #pragma unroll
            for (int nt = 0; nt < 4; ++nt) {
                const int drow = nt * 16 + lo;
                bf16x8 vf = *(const bf16x8*)&Vt[drow * 64 + ((ks * 4 + hi) ^ (drow & 7)) * 8];
                acc[nt] = __builtin_amdgcn_mfma_f32_16x16x32_bf16(pf, vf, acc[nt], 0, 0, 0);
            }
        }
    }

    // ---- epilogue: ctx = acc / l ----
    float inv[4];
    #pragma unroll
    for (int r = 0; r < 4; ++r) inv[r] = 1.f / l_i[r];
    float* cdst = ctx + base;
    #pragma unroll
    for (int nt = 0; nt < 4; ++nt)
        #pragma unroll
        for (int r = 0; r < 4; ++r)
            cdst[(size_t)(q0 + w * 16 + hi * 4 + r) * D_MODEL + nt * 16 + lo] = acc[nt][r] * inv[r];
}

// ---------------------------------------------------------------------------
// LayerNorm over last dim (1024). One block per row.
// ---------------------------------------------------------------------------
__global__ __launch_bounds__(256) void layernorm1024(
    const float* __restrict__ x, const float* __restrict__ gamma,
    const float* __restrict__ beta, float* __restrict__ out)
{
    const int row = blockIdx.x;
    const int tid = threadIdx.x;
    const float* xr = x + (size_t)row * D_MODEL;
    float4 v = *(const float4*)(xr + (tid << 2));
    float s = v.x + v.y + v.z + v.w;
    float q = v.x * v.x + v.y * v.y + v.z * v.z + v.w * v.w;
    #pragma unroll
    for (int off = 1; off < 64; off <<= 1) {
        s += __shfl_xor(s, off, 64);
        q += __shfl_xor(q, off, 64);
    }
    __shared__ float sw[4], qw_[4];
    const int wid = tid >> 6;
    if ((tid & 63) == 0) { sw[wid] = s; qw_[wid] = q; }
    __syncthreads();
    s = sw[0] + sw[1] + sw[2] + sw[3];
    q = qw_[0] + qw_[1] + qw_[2] + qw_[3];
    const float mu  = s * (1.f / D_MODEL);
    const float var = q * (1.f / D_MODEL) - mu * mu;
    const float a = var + 1e-5f;
    float inv = rsqrtf(a);
    inv = inv * (1.5f - 0.5f * a * inv * inv);
    float4 g  = *(const float4*)(gamma + (tid << 2));
    float4 bt = *(const float4*)(beta + (tid << 2));
    float4 o;
    o.x = (v.x - mu) * inv * g.x + bt.x;
    o.y = (v.y - mu) * inv * g.y + bt.y;
    o.z = (v.z - mu) * inv * g.z + bt.z;
    o.w = (v.w - mu) * inv * g.w + bt.w;
    *(float4*)(out + (size_t)row * D_MODEL + (tid << 2)) = o;
}

// ---------------------------------------------------------------------------
extern "C" void kernel_launch(void* const* d_in, const int* in_sizes, int n_in,
                              void* d_out, int out_size, void* d_ws, size_t ws_size,
                              hipStream_t stream)
{
    const float* Q    = (const float*)d_in[0];
    const float* K    = (const float*)d_in[1];
    const float* V    = (const float*)d_in[2];
    const void*  mask = d_in[3];
    const float* Wq   = (const float*)d_in[4];
    const float* bq   = (const float*)d_in[5];
    const float* Wk   = (const float*)d_in[6];
    const float* bk   = (const float*)d_in[7];
    const float* Wv   = (const float*)d_in[8];
    const float* bv   = (const float*)d_in[9];
    const float* Wo   = (const float*)d_in[10];
    const float* bo   = (const float*)d_in[11];
    const float* gam  = (const float*)d_in[12];
    const float* bet  = (const float*)d_in[13];
    float* out = (float*)d_out;

    const size_t NE = (size_t)MROWS * D_MODEL;          // 4.2M elements
    unsigned short* qb = (unsigned short*)d_ws;
    unsigned short* kb = qb + NE;
    unsigned short* vb = kb + NE;
    float* ctx  = (float*)(vb + NE);
    float* outp = ctx + NE;
    unsigned long long* mbits = (unsigned long long*)(outp + NE);
    int* mflag = (int*)(mbits + (size_t)BATCH * SEQ * (SEQ / 64));
    if (ws_size < 3 * NE * sizeof(unsigned short) + 2 * NE * sizeof(float)
                 + (size_t)BATCH * SEQ * (SEQ / 64) * 8 + 64) return;

    detect_mask<<<1, 256, 0, stream>>>((const unsigned int*)mask, 65536, mflag);
    pack_mask<<<(BATCH * SEQ * (SEQ / 64) + 255) / 256, 256, 0, stream>>>(
        mask, mflag, mbits, BATCH * SEQ * (SEQ / 64));

    dim3 gg(D_MODEL / 64, MROWS / 64);
    gemm64<true><<<gg, 256, 0, stream>>>(Q, Wq, bq, nullptr, qb, MROWS, D_MODEL, D_MODEL);
    gemm64<true><<<gg, 256, 0, stream>>>(K, Wk, bk, nullptr, kb, MROWS, D_MODEL, D_MODEL);
    gemm64<true><<<gg, 256, 0, stream>>>(V, Wv, bv, nullptr, vb, MROWS, D_MODEL, D_MODEL);

    dim3 ag(SEQ / 64, NHEADS, BATCH);
    attn_mfma<<<ag, 256, 0, stream>>>(qb, kb, vb, mbits, ctx);

    gemm64<false><<<gg, 256, 0, stream>>>(ctx, Wo, bo, Q, outp, MROWS, D_MODEL, D_MODEL);

    layernorm1024<<<MROWS, 256, 0, stream>>>(outp, gam, bet, out);
}

// Round 3
// 423.408 us; speedup vs baseline: 4.8611x; 1.7082x over previous
//
#include <hip/hip_runtime.h>
#include <hip/hip_bf16.h>
#include <math.h>

// Fused MHA block: proj(Q,K,V) -> masked softmax attention -> out proj + residual -> LayerNorm
// Round 3: all GEMMs converted to bf16 MFMA (128x128 tile, BK=64, 2-phase dbuf LDS,
// global_load_lds 16B staging). Attention: exp2-domain softmax, 32-bit mask shifts,
// defer-max (T13). Residual/bias/LN remain fp32.

#define D_MODEL 1024
#define NHEADS  16
#define DHEAD   64
#define BATCH   2
#define SEQ     2048
#define MROWS   (BATCH * SEQ)   // 4096

typedef __attribute__((ext_vector_type(8))) short bf16x8;
typedef __attribute__((ext_vector_type(4))) float f32x4;

__device__ inline unsigned short f2bf(float f) {
    unsigned int u = __builtin_bit_cast(unsigned int, f);
    unsigned int r = (u + 0x7FFFu + ((u >> 16) & 1u)) >> 16;   // RNE
    return (unsigned short)r;
}

// global -> LDS direct copy, 16B per lane. lbase must be wave-uniform.
__device__ inline void gload16(const unsigned short* g, unsigned short* lbase, int lane) {
#if __has_builtin(__builtin_amdgcn_global_load_lds)
    __builtin_amdgcn_global_load_lds(
        (const __attribute__((address_space(1))) unsigned int*)g,
        (__attribute__((address_space(3))) unsigned int*)lbase, 16, 0, 0);
#else
    *(bf16x8*)(lbase + lane * 8) = *(const bf16x8*)g;
#endif
}

// ---------------------------------------------------------------------------
// Mask dtype probe (bool may arrive as uint8 / int32 / float32).
// ---------------------------------------------------------------------------
__global__ void detect_mask(const unsigned int* __restrict__ m, int nwords,
                            int* __restrict__ flag) {
    __shared__ int not01, notf;
    if (threadIdx.x == 0) { not01 = 0; notf = 0; }
    __syncthreads();
    int a = 0, b = 0;
    for (int i = threadIdx.x; i < nwords; i += blockDim.x) {
        unsigned int w = m[i];
        if (w != 0u && w != 1u) a = 1;
        if (w != 0u && w != 0x3F800000u) b = 1;
    }
    if (a) atomicOr(&not01, 1);
    if (b) atomicOr(&notf, 1);
    __syncthreads();
    if (threadIdx.x == 0) {
        int f;
        if (!not01) f = 0;        // int32 0/1
        else if (!notf) f = 1;    // float32 0.0/1.0
        else f = 2;               // uint8 0/1
        *flag = f;
    }
}

// ---------------------------------------------------------------------------
// Pack mask to 1 bit per entry: mbits[b][q][kword] (kword = 64 keys).
// ---------------------------------------------------------------------------
__global__ __launch_bounds__(256) void pack_mask(
    const void* __restrict__ mask, const int* __restrict__ mflag,
    unsigned long long* __restrict__ mbits, int nwords)
{
    int idx = blockIdx.x * blockDim.x + threadIdx.x;
    if (idx >= nwords) return;
    const int mf = *mflag;
    unsigned long long bits = 0ull;
    if (mf == 2) {
        const unsigned int* p = (const unsigned int*)mask + (size_t)idx * 16;
        #pragma unroll
        for (int i = 0; i < 16; ++i) {
            unsigned int w = p[i] & 0x01010101u;
            unsigned int nib = (w * 0x01020408u) >> 24;
            bits |= (unsigned long long)(nib & 0xFu) << (i * 4);
        }
    } else if (mf == 0) {
        const unsigned int* p = (const unsigned int*)mask + (size_t)idx * 64;
        #pragma unroll
        for (int i = 0; i < 64; ++i)
            bits |= (unsigned long long)(p[i] & 1u) << i;
    } else {
        const float* p = (const float*)mask + (size_t)idx * 64;
        #pragma unroll
        for (int i = 0; i < 64; ++i)
            bits |= (unsigned long long)(p[i] != 0.f) << i;
    }
    mbits[idx] = bits;
}

// ---------------------------------------------------------------------------
// fp32 -> bf16 convert for Q,K,V (blockIdx.y selects tensor). 8 elems/thread.
// ---------------------------------------------------------------------------
__global__ __launch_bounds__(256) void cvt_bf16(
    const float* __restrict__ s0, const float* __restrict__ s1,
    const float* __restrict__ s2,
    unsigned short* __restrict__ d0, unsigned short* __restrict__ d1,
    unsigned short* __restrict__ d2)
{
    const float* s = (blockIdx.y == 0) ? s0 : (blockIdx.y == 1) ? s1 : s2;
    unsigned short* d = (blockIdx.y == 0) ? d0 : (blockIdx.y == 1) ? d1 : d2;
    const int i = blockIdx.x * 256 + threadIdx.x;   // 8 elems per thread
    float4 a = ((const float4*)s)[i * 2];
    float4 b = ((const float4*)s)[i * 2 + 1];
    ushort4 u0, u1;
    u0.x = f2bf(a.x); u0.y = f2bf(a.y); u0.z = f2bf(a.z); u0.w = f2bf(a.w);
    u1.x = f2bf(b.x); u1.y = f2bf(b.y); u1.z = f2bf(b.z); u1.w = f2bf(b.w);
    ((ushort4*)d)[i * 2] = u0;
    ((ushort4*)d)[i * 2 + 1] = u1;
}

// ---------------------------------------------------------------------------
// Weight transpose-convert: W fp32 [K=1024][N=1024] -> Wt bf16 [N][K].
// 64x64 tile via padded LDS. blockIdx.z selects one of 4 weights.
// ---------------------------------------------------------------------------
__global__ __launch_bounds__(256) void cvt_wT(
    const float* __restrict__ w0, const float* __restrict__ w1,
    const float* __restrict__ w2, const float* __restrict__ w3,
    unsigned short* __restrict__ t0, unsigned short* __restrict__ t1,
    unsigned short* __restrict__ t2, unsigned short* __restrict__ t3)
{
    __shared__ float tile[64][65];
    const float* W = (blockIdx.z == 0) ? w0 : (blockIdx.z == 1) ? w1
                   : (blockIdx.z == 2) ? w2 : w3;
    unsigned short* T = (blockIdx.z == 0) ? t0 : (blockIdx.z == 1) ? t1
                      : (blockIdx.z == 2) ? t2 : t3;
    const int k0 = blockIdx.y * 64;
    const int n0 = blockIdx.x * 64;
    const int t  = threadIdx.x;
    const int r  = t >> 4;
    const int c4 = (t & 15) * 4;
    #pragma unroll
    for (int u = 0; u < 4; ++u) {
        float4 v = *(const float4*)(W + (size_t)(k0 + r + u * 16) * D_MODEL + n0 + c4);
        tile[r + u * 16][c4 + 0] = v.x;
        tile[r + u * 16][c4 + 1] = v.y;
        tile[r + u * 16][c4 + 2] = v.z;
        tile[r + u * 16][c4 + 3] = v.w;
    }
    __syncthreads();
    #pragma unroll
    for (int u = 0; u < 4; ++u) {
        const int nr = r + u * 16;
        ushort4 o;
        o.x = f2bf(tile[c4 + 0][nr]);
        o.y = f2bf(tile[c4 + 1][nr]);
        o.z = f2bf(tile[c4 + 2][nr]);
        o.w = f2bf(tile[c4 + 3][nr]);
        *(ushort4*)(T + (size_t)(n0 + nr) * D_MODEL + k0 + c4) = o;
    }
}

// ---------------------------------------------------------------------------
// MFMA GEMM: C[M,N] = A[M,K]bf16 @ Wt[N,K]bf16^T + bias (+resid fp32).
// 128x128 tile, BK=64, 256 threads (4 waves, 2x2, 64x64 out each).
// 2-phase double-buffered LDS, global_load_lds 16B staging.
// ---------------------------------------------------------------------------
#define BKK 64

template<bool OB>
__global__ __launch_bounds__(256, 1) void gemm_mfma(
    const unsigned short* __restrict__ A, const unsigned short* __restrict__ Bt,
    const float* __restrict__ bias, const float* __restrict__ resid,
    void* __restrict__ C, int M, int N, int K)
{
    __shared__ unsigned short As[2][128 * BKK];
    __shared__ unsigned short Bs[2][128 * BKK];
    const int tid  = threadIdx.x;
    const int w    = tid >> 6;
    const int lane = tid & 63;
    const int lo   = lane & 15;
    const int hi   = lane >> 4;
    const int wm   = (w >> 1) * 64;
    const int wn   = (w & 1) * 64;
    const int m0   = blockIdx.y * 128;
    const int n0   = blockIdx.x * 128;

    const unsigned short* Ab = A  + (size_t)m0 * K;
    const unsigned short* Bb = Bt + (size_t)n0 * K;

    f32x4 acc[4][4];
    #pragma unroll
    for (int i = 0; i < 4; ++i)
        #pragma unroll
        for (int j = 0; j < 4; ++j) acc[i][j] = (f32x4){0.f, 0.f, 0.f, 0.f};

    const int NT = K / BKK;

    // stage one K-tile (A+B) into buffer buf: 1024 chunks of 16B each matrix
    auto stage = [&](int buf, int t) {
        const int k0 = t * BKK;
        #pragma unroll
        for (int i = 0; i < 4; ++i) {
            const int c = i * 256 + tid;        // chunk id; lds base wave-uniform
            gload16(Ab + (size_t)(c >> 3) * K + k0 + (c & 7) * 8,
                    &As[buf][(i * 256 + w * 64) * 8], lane);
        }
        #pragma unroll
        for (int i = 0; i < 4; ++i) {
            const int c = i * 256 + tid;
            gload16(Bb + (size_t)(c >> 3) * K + k0 + (c & 7) * 8,
                    &Bs[buf][(i * 256 + w * 64) * 8], lane);
        }
    };

    stage(0, 0);
    __syncthreads();
    int cur = 0;
    for (int t = 0; t < NT; ++t) {
        if (t + 1 < NT) stage(cur ^ 1, t + 1);
        // compute on buf cur
        bf16x8 af[4][2], bfr[4][2];
        #pragma unroll
        for (int f = 0; f < 4; ++f)
            #pragma unroll
            for (int s = 0; s < 2; ++s) {
                af[f][s]  = *(const bf16x8*)&As[cur][(wm + f * 16 + lo) * BKK + s * 32 + hi * 8];
                bfr[f][s] = *(const bf16x8*)&Bs[cur][(wn + f * 16 + lo) * BKK + s * 32 + hi * 8];
            }
        #pragma unroll
        for (int s = 0; s < 2; ++s)
            #pragma unroll
            for (int fm = 0; fm < 4; ++fm)
                #pragma unroll
                for (int fn = 0; fn < 4; ++fn)
                    acc[fm][fn] = __builtin_amdgcn_mfma_f32_16x16x32_bf16(
                        af[fm][s], bfr[fn][s], acc[fm][fn], 0, 0, 0);
        __syncthreads();
        cur ^= 1;
    }

    // epilogue
    #pragma unroll
    for (int fm = 0; fm < 4; ++fm) {
        const int row = m0 + wm + fm * 16 + hi * 4;
        #pragma unroll
        for (int fn = 0; fn < 4; ++fn) {
            const int col = n0 + wn + fn * 16 + lo;
            const float bv = bias[col];
            #pragma unroll
            for (int r = 0; r < 4; ++r) {
                float o = acc[fm][fn][r] + bv;
                if (resid) o += resid[(size_t)(row + r) * N + col];
                if (OB)
                    ((unsigned short*)C)[(size_t)(row + r) * N + col] = f2bf(o);
                else
                    ((float*)C)[(size_t)(row + r) * N + col] = o;
            }
        }
    }
}

// ---------------------------------------------------------------------------
// MFMA flash attention. Block = (b, h, 64 q-rows), 4 waves, 16 q-rows/wave.
// exp2-domain softmax (scale folded), 32-bit mask shifts, defer-max (T13).
// Emits bf16 ctx.
// ---------------------------------------------------------------------------
__global__ __launch_bounds__(256) void attn_mfma(
    const unsigned short* __restrict__ qb, const unsigned short* __restrict__ kb,
    const unsigned short* __restrict__ vb,
    const unsigned long long* __restrict__ mbits, unsigned short* __restrict__ ctx)
{
    __shared__ unsigned short Ks[64 * 64];      // [key][d] swizzled
    __shared__ unsigned short Vt[64 * 64];      // [d][key] swizzled
    __shared__ unsigned short Ps[4][16 * 72];   // per-wave P, padded rows

    const int tid  = threadIdx.x;
    const int lane = tid & 63;
    const int w    = tid >> 6;
    const int lo   = lane & 15;
    const int hi   = lane >> 4;
    const int q0   = blockIdx.x * 64;
    const int h    = blockIdx.y;
    const int b    = blockIdx.z;

    const float SCL = 0.125f * 1.44269504f;     // 1/sqrt(64) * log2(e)

    const size_t base = (size_t)b * SEQ * D_MODEL + (size_t)h * DHEAD;

    const int qrow = q0 + w * 16 + lo;
    bf16x8 qA[2];
    qA[0] = *(const bf16x8*)(qb + base + (size_t)qrow * D_MODEL + hi * 8);
    qA[1] = *(const bf16x8*)(qb + base + (size_t)qrow * D_MODEL + 32 + hi * 8);

    f32x4 acc[4];
    #pragma unroll
    for (int i = 0; i < 4; ++i) acc[i] = (f32x4){0.f, 0.f, 0.f, 0.f};
    float m_i[4], l_i[4];
    #pragma unroll
    for (int r = 0; r < 4; ++r) { m_i[r] = -INFINITY; l_i[r] = 0.f; }

    const int sr  = tid >> 2;
    const int sc2 = (tid & 3) * 2;

    const unsigned long long* mrow = mbits + ((size_t)b * SEQ + q0 + w * 16) * (SEQ / 64);

    for (int kt = 0; kt < SEQ / 64; ++kt) {
        __syncthreads();
        // ---- stage K (swizzled) and V (transposed, swizzled) ----
        {
            const unsigned short* ksrc = kb + base + (size_t)(kt * 64 + sr) * D_MODEL + sc2 * 8;
            bf16x8 k0 = *(const bf16x8*)(ksrc);
            bf16x8 k1 = *(const bf16x8*)(ksrc + 8);
            *(bf16x8*)&Ks[sr * 64 + ((sc2    ) ^ (sr & 7)) * 8] = k0;
            *(bf16x8*)&Ks[sr * 64 + ((sc2 + 1) ^ (sr & 7)) * 8] = k1;
            const unsigned short* vsrc = vb + base + (size_t)(kt * 64 + sr) * D_MODEL + sc2 * 8;
            bf16x8 v0 = *(const bf16x8*)(vsrc);
            bf16x8 v1 = *(const bf16x8*)(vsrc + 8);
            #pragma unroll
            for (int j = 0; j < 8; ++j) {
                const int d0 = sc2 * 8 + j;
                const int d1 = d0 + 8;
                Vt[d0 * 64 + (((sr >> 3) ^ (d0 & 7)) * 8) + (sr & 7)] = (unsigned short)v0[j];
                Vt[d1 * 64 + (((sr >> 3) ^ (d1 & 7)) * 8) + (sr & 7)] = (unsigned short)v1[j];
            }
        }
        __syncthreads();

        // ---- QK^T: S[16q x 64k] per wave ----
        f32x4 s[4];
        #pragma unroll
        for (int nt = 0; nt < 4; ++nt) s[nt] = (f32x4){0.f, 0.f, 0.f, 0.f};
        #pragma unroll
        for (int nt = 0; nt < 4; ++nt) {
            const int krow = nt * 16 + lo;
            #pragma unroll
            for (int st = 0; st < 2; ++st) {
                bf16x8 kf = *(const bf16x8*)&Ks[krow * 64 + ((st * 4 + hi) ^ (krow & 7)) * 8];
                s[nt] = __builtin_amdgcn_mfma_f32_16x16x32_bf16(qA[st], kf, s[nt], 0, 0, 0);
            }
        }

        // ---- mask + scale (log2 domain) + row maxima ----
        float sv[4][4], rm[4];
        #pragma unroll
        for (int r = 0; r < 4; ++r) {
            const unsigned long long mw = mrow[(size_t)(hi * 4 + r) * (SEQ / 64) + kt];
            const unsigned int t0 = ((unsigned int)mw) >> lo;
            const unsigned int t1 = ((unsigned int)(mw >> 32)) >> lo;
            sv[r][0] = (t0 & 1u)         ? -1e9f : s[0][r] * SCL;
            sv[r][1] = ((t0 >> 16) & 1u) ? -1e9f : s[1][r] * SCL;
            sv[r][2] = (t1 & 1u)         ? -1e9f : s[2][r] * SCL;
            sv[r][3] = ((t1 >> 16) & 1u) ? -1e9f : s[3][r] * SCL;
            float m1 = fmaxf(fmaxf(sv[r][0], sv[r][1]), fmaxf(sv[r][2], sv[r][3]));
            m1 = fmaxf(m1, __shfl_xor(m1, 1, 64));
            m1 = fmaxf(m1, __shfl_xor(m1, 2, 64));
            m1 = fmaxf(m1, __shfl_xor(m1, 4, 64));
            m1 = fmaxf(m1, __shfl_xor(m1, 8, 64));
            rm[r] = m1;
        }

        // ---- defer-max: skip rescale when max growth bounded (T13) ----
        const float grow = fmaxf(fmaxf(rm[0] - m_i[0], rm[1] - m_i[1]),
                                 fmaxf(rm[2] - m_i[2], rm[3] - m_i[3]));
        const bool defer = __all(grow <= 11.5f);   // ~8 nats in log2 units

        #pragma unroll
        for (int r = 0; r < 4; ++r) {
            float mn;
            if (defer) mn = m_i[r];
            else       mn = fmaxf(m_i[r], rm[r]);
            float p0 = exp2f(sv[r][0] - mn);
            float p1 = exp2f(sv[r][1] - mn);
            float p2 = exp2f(sv[r][2] - mn);
            float p3 = exp2f(sv[r][3] - mn);
            float ps = (p0 + p1) + (p2 + p3);
            ps += __shfl_xor(ps, 1, 64);
            ps += __shfl_xor(ps, 2, 64);
            ps += __shfl_xor(ps, 4, 64);
            ps += __shfl_xor(ps, 8, 64);
            if (defer) {
                l_i[r] += ps;
            } else {
                const float alpha = exp2f(m_i[r] - mn);
                l_i[r] = l_i[r] * alpha + ps;
                m_i[r] = mn;
                acc[0][r] *= alpha; acc[1][r] *= alpha;
                acc[2][r] *= alpha; acc[3][r] *= alpha;
            }
            const int prow = (hi * 4 + r) * 72;
            Ps[w][prow +  0 + lo] = f2bf(p0);
            Ps[w][prow + 16 + lo] = f2bf(p1);
            Ps[w][prow + 32 + lo] = f2bf(p2);
            Ps[w][prow + 48 + lo] = f2bf(p3);
        }

        // ---- PV ----
        #pragma unroll
        for (int ks = 0; ks < 2; ++ks) {
            bf16x8 pf = *(const bf16x8*)&Ps[w][lo * 72 + ks * 32 + hi * 8];
            #pragma unroll
            for (int nt = 0; nt < 4; ++nt) {
                const int drow = nt * 16 + lo;
                bf16x8 vf = *(const bf16x8*)&Vt[drow * 64 + ((ks * 4 + hi) ^ (drow & 7)) * 8];
                acc[nt] = __builtin_amdgcn_mfma_f32_16x16x32_bf16(pf, vf, acc[nt], 0, 0, 0);
            }
        }
    }

    // ---- epilogue: ctx(bf16) = acc / l ----
    float inv[4];
    #pragma unroll
    for (int r = 0; r < 4; ++r) inv[r] = 1.f / l_i[r];
    unsigned short* cdst = ctx + base;
    #pragma unroll
    for (int nt = 0; nt < 4; ++nt)
        #pragma unroll
        for (int r = 0; r < 4; ++r)
            cdst[(size_t)(q0 + w * 16 + hi * 4 + r) * D_MODEL + nt * 16 + lo] =
                f2bf(acc[nt][r] * inv[r]);
}

// ---------------------------------------------------------------------------
// LayerNorm over last dim (1024). One block per row.
// ---------------------------------------------------------------------------
__global__ __launch_bounds__(256) void layernorm1024(
    const float* __restrict__ x, const float* __restrict__ gamma,
    const float* __restrict__ beta, float* __restrict__ out)
{
    const int row = blockIdx.x;
    const int tid = threadIdx.x;
    const float* xr = x + (size_t)row * D_MODEL;
    float4 v = *(const float4*)(xr + (tid << 2));
    float s = v.x + v.y + v.z + v.w;
    float q = v.x * v.x + v.y * v.y + v.z * v.z + v.w * v.w;
    #pragma unroll
    for (int off = 1; off < 64; off <<= 1) {
        s += __shfl_xor(s, off, 64);
        q += __shfl_xor(q, off, 64);
    }
    __shared__ float sw[4], qw_[4];
    const int wid = tid >> 6;
    if ((tid & 63) == 0) { sw[wid] = s; qw_[wid] = q; }
    __syncthreads();
    s = sw[0] + sw[1] + sw[2] + sw[3];
    q = qw_[0] + qw_[1] + qw_[2] + qw_[3];
    const float mu  = s * (1.f / D_MODEL);
    const float var = q * (1.f / D_MODEL) - mu * mu;
    const float a = var + 1e-5f;
    float inv = rsqrtf(a);
    inv = inv * (1.5f - 0.5f * a * inv * inv);
    float4 g  = *(const float4*)(gamma + (tid << 2));
    float4 bt = *(const float4*)(beta + (tid << 2));
    float4 o;
    o.x = (v.x - mu) * inv * g.x + bt.x;
    o.y = (v.y - mu) * inv * g.y + bt.y;
    o.z = (v.z - mu) * inv * g.z + bt.z;
    o.w = (v.w - mu) * inv * g.w + bt.w;
    *(float4*)(out + (size_t)row * D_MODEL + (tid << 2)) = o;
}

// ---------------------------------------------------------------------------
extern "C" void kernel_launch(void* const* d_in, const int* in_sizes, int n_in,
                              void* d_out, int out_size, void* d_ws, size_t ws_size,
                              hipStream_t stream)
{
    const float* Q    = (const float*)d_in[0];
    const float* K    = (const float*)d_in[1];
    const float* V    = (const float*)d_in[2];
    const void*  mask = d_in[3];
    const float* Wq   = (const float*)d_in[4];
    const float* bq   = (const float*)d_in[5];
    const float* Wk   = (const float*)d_in[6];
    const float* bk   = (const float*)d_in[7];
    const float* Wv   = (const float*)d_in[8];
    const float* bv   = (const float*)d_in[9];
    const float* Wo   = (const float*)d_in[10];
    const float* bo   = (const float*)d_in[11];
    const float* gam  = (const float*)d_in[12];
    const float* bet  = (const float*)d_in[13];
    float* out = (float*)d_out;

    const size_t NE = (size_t)MROWS * D_MODEL;           // 4,194,304 elems
    const size_t WE = (size_t)D_MODEL * D_MODEL;         // 1,048,576 elems
    unsigned short* Qbf = (unsigned short*)d_ws;         // later reused as ctxb
    unsigned short* Kbf = Qbf + NE;                      // Kbf..Vbf later = outp
    unsigned short* Vbf = Kbf + NE;
    unsigned short* qb  = Vbf + NE;
    unsigned short* kb  = qb + NE;
    unsigned short* vb  = kb + NE;
    unsigned short* Wt0 = vb + NE;
    unsigned short* Wt1 = Wt0 + WE;
    unsigned short* Wt2 = Wt1 + WE;
    unsigned short* Wt3 = Wt2 + WE;
    unsigned long long* mbits = (unsigned long long*)(Wt3 + WE);
    const size_t NMW = (size_t)BATCH * SEQ * (SEQ / 64); // 131072 mask words
    int* mflag = (int*)(mbits + NMW);
    unsigned short* ctxb = Qbf;
    float* outp = (float*)Kbf;
    if (ws_size < 6 * NE * 2 + 4 * WE * 2 + NMW * 8 + 64) return;

    detect_mask<<<1, 256, 0, stream>>>((const unsigned int*)mask, 65536, mflag);
    pack_mask<<<(int)((NMW + 255) / 256), 256, 0, stream>>>(mask, mflag, mbits, (int)NMW);

    cvt_bf16<<<dim3(NE / 8 / 256, 3), 256, 0, stream>>>(Q, K, V, Qbf, Kbf, Vbf);
    cvt_wT<<<dim3(16, 16, 4), 256, 0, stream>>>(Wq, Wk, Wv, Wo, Wt0, Wt1, Wt2, Wt3);

    dim3 gg(D_MODEL / 128, MROWS / 128);   // (8, 32)
    gemm_mfma<true><<<gg, 256, 0, stream>>>(Qbf, Wt0, bq, nullptr, qb, MROWS, D_MODEL, D_MODEL);
    gemm_mfma<true><<<gg, 256, 0, stream>>>(Kbf, Wt1, bk, nullptr, kb, MROWS, D_MODEL, D_MODEL);
    gemm_mfma<true><<<gg, 256, 0, stream>>>(Vbf, Wt2, bv, nullptr, vb, MROWS, D_MODEL, D_MODEL);

    dim3 ag(SEQ / 64, NHEADS, BATCH);
    attn_mfma<<<ag, 256, 0, stream>>>(qb, kb, vb, mbits, ctxb);

    gemm_mfma<false><<<gg, 256, 0, stream>>>(ctxb, Wt3, bo, Q, outp, MROWS, D_MODEL, D_MODEL);

    layernorm1024<<<MROWS, 256, 0, stream>>>(outp, gam, bet, out);
}

// Round 4
// 306.407 us; speedup vs baseline: 6.7173x; 1.3819x over previous
//
#include <hip/hip_runtime.h>
#include <hip/hip_bf16.h>
#include <math.h>

// Fused MHA block: proj(Q,K,V) -> masked softmax attention -> out proj + residual -> LayerNorm
// Round 4: attention restructured to swapped-QK^T 32x32 MFMA (m214/§B recipe):
// S^T=K·Q^T so softmax is lane-local; P->A-frag via v_cvt_pk_bf16_f32 + permlane32_swap;
// V produced pre-transposed by the V-projection GEMM epilogue (vt[b][h][d][tok]).
// GEMMs: bf16 MFMA 128x128 (unchanged core, epilogue mode templated).

#define D_MODEL 1024
#define NHEADS  16
#define DHEAD   64
#define BATCH   2
#define SEQ     2048
#define MROWS   (BATCH * SEQ)   // 4096

typedef __attribute__((ext_vector_type(8)))  short bf16x8;
typedef __attribute__((ext_vector_type(4)))  float f32x4;
typedef __attribute__((ext_vector_type(16))) float f32x16;

__device__ inline unsigned short f2bf(float f) {
    unsigned int u = __builtin_bit_cast(unsigned int, f);
    unsigned int r = (u + 0x7FFFu + ((u >> 16) & 1u)) >> 16;   // RNE
    return (unsigned short)r;
}

__device__ inline unsigned cvtpk_bf16(float lo, float hi2) {
    unsigned r;
    asm("v_cvt_pk_bf16_f32 %0, %1, %2" : "=v"(r) : "v"(lo), "v"(hi2));
    return r;
}

// global -> LDS direct copy, 16B per lane. lbase must be wave-uniform.
__device__ inline void gload16(const unsigned short* g, unsigned short* lbase, int lane) {
#if __has_builtin(__builtin_amdgcn_global_load_lds)
    __builtin_amdgcn_global_load_lds(
        (const __attribute__((address_space(1))) unsigned int*)g,
        (__attribute__((address_space(3))) unsigned int*)lbase, 16, 0, 0);
#else
    *(bf16x8*)(lbase + lane * 8) = *(const bf16x8*)g;
#endif
}

// ---------------------------------------------------------------------------
// Mask dtype probe (bool may arrive as uint8 / int32 / float32).
// ---------------------------------------------------------------------------
__global__ void detect_mask(const unsigned int* __restrict__ m, int nwords,
                            int* __restrict__ flag) {
    __shared__ int not01, notf;
    if (threadIdx.x == 0) { not01 = 0; notf = 0; }
    __syncthreads();
    int a = 0, b = 0;
    for (int i = threadIdx.x; i < nwords; i += blockDim.x) {
        unsigned int w = m[i];
        if (w != 0u && w != 1u) a = 1;
        if (w != 0u && w != 0x3F800000u) b = 1;
    }
    if (a) atomicOr(&not01, 1);
    if (b) atomicOr(&notf, 1);
    __syncthreads();
    if (threadIdx.x == 0) {
        int f;
        if (!not01) f = 0;        // int32 0/1
        else if (!notf) f = 1;    // float32 0.0/1.0
        else f = 2;               // uint8 0/1
        *flag = f;
    }
}

// ---------------------------------------------------------------------------
// Pack mask to 1 bit per entry: mbits[b][q][kword] (kword = 64 keys).
// ---------------------------------------------------------------------------
__global__ __launch_bounds__(256) void pack_mask(
    const void* __restrict__ mask, const int* __restrict__ mflag,
    unsigned long long* __restrict__ mbits, int nwords)
{
    int idx = blockIdx.x * blockDim.x + threadIdx.x;
    if (idx >= nwords) return;
    const int mf = *mflag;
    unsigned long long bits = 0ull;
    if (mf == 2) {
        const unsigned int* p = (const unsigned int*)mask + (size_t)idx * 16;
        #pragma unroll
        for (int i = 0; i < 16; ++i) {
            unsigned int w = p[i] & 0x01010101u;
            unsigned int nib = (w * 0x01020408u) >> 24;
            bits |= (unsigned long long)(nib & 0xFu) << (i * 4);
        }
    } else if (mf == 0) {
        const unsigned int* p = (const unsigned int*)mask + (size_t)idx * 64;
        #pragma unroll
        for (int i = 0; i < 64; ++i)
            bits |= (unsigned long long)(p[i] & 1u) << i;
    } else {
        const float* p = (const float*)mask + (size_t)idx * 64;
        #pragma unroll
        for (int i = 0; i < 64; ++i)
            bits |= (unsigned long long)(p[i] != 0.f) << i;
    }
    mbits[idx] = bits;
}

// ---------------------------------------------------------------------------
// fp32 -> bf16 convert for Q,K,V (blockIdx.y selects tensor). 8 elems/thread.
// ---------------------------------------------------------------------------
__global__ __launch_bounds__(256) void cvt_bf16(
    const float* __restrict__ s0, const float* __restrict__ s1,
    const float* __restrict__ s2,
    unsigned short* __restrict__ d0, unsigned short* __restrict__ d1,
    unsigned short* __restrict__ d2)
{
    const float* s = (blockIdx.y == 0) ? s0 : (blockIdx.y == 1) ? s1 : s2;
    unsigned short* d = (blockIdx.y == 0) ? d0 : (blockIdx.y == 1) ? d1 : d2;
    const int i = blockIdx.x * 256 + threadIdx.x;
    float4 a = ((const float4*)s)[i * 2];
    float4 b = ((const float4*)s)[i * 2 + 1];
    ushort4 u0, u1;
    u0.x = f2bf(a.x); u0.y = f2bf(a.y); u0.z = f2bf(a.z); u0.w = f2bf(a.w);
    u1.x = f2bf(b.x); u1.y = f2bf(b.y); u1.z = f2bf(b.z); u1.w = f2bf(b.w);
    ((ushort4*)d)[i * 2] = u0;
    ((ushort4*)d)[i * 2 + 1] = u1;
}

// ---------------------------------------------------------------------------
// Weight transpose-convert: W fp32 [K][N] -> Wt bf16 [N][K].
// ---------------------------------------------------------------------------
__global__ __launch_bounds__(256) void cvt_wT(
    const float* __restrict__ w0, const float* __restrict__ w1,
    const float* __restrict__ w2, const float* __restrict__ w3,
    unsigned short* __restrict__ t0, unsigned short* __restrict__ t1,
    unsigned short* __restrict__ t2, unsigned short* __restrict__ t3)
{
    __shared__ float tile[64][65];
    const float* W = (blockIdx.z == 0) ? w0 : (blockIdx.z == 1) ? w1
                   : (blockIdx.z == 2) ? w2 : w3;
    unsigned short* T = (blockIdx.z == 0) ? t0 : (blockIdx.z == 1) ? t1
                      : (blockIdx.z == 2) ? t2 : t3;
    const int k0 = blockIdx.y * 64;
    const int n0 = blockIdx.x * 64;
    const int t  = threadIdx.x;
    const int r  = t >> 4;
    const int c4 = (t & 15) * 4;
    #pragma unroll
    for (int u = 0; u < 4; ++u) {
        float4 v = *(const float4*)(W + (size_t)(k0 + r + u * 16) * D_MODEL + n0 + c4);
        tile[r + u * 16][c4 + 0] = v.x;
        tile[r + u * 16][c4 + 1] = v.y;
        tile[r + u * 16][c4 + 2] = v.z;
        tile[r + u * 16][c4 + 3] = v.w;
    }
    __syncthreads();
    #pragma unroll
    for (int u = 0; u < 4; ++u) {
        const int nr = r + u * 16;
        ushort4 o;
        o.x = f2bf(tile[c4 + 0][nr]);
        o.y = f2bf(tile[c4 + 1][nr]);
        o.z = f2bf(tile[c4 + 2][nr]);
        o.w = f2bf(tile[c4 + 3][nr]);
        *(ushort4*)(T + (size_t)(n0 + nr) * D_MODEL + k0 + c4) = o;
    }
}

// ---------------------------------------------------------------------------
// MFMA GEMM: C = A[M,K]bf16 @ Wt[N,K]^T + bias (+resid fp32 when OMODE==0).
// OMODE: 0 = fp32 row-major, 1 = bf16 row-major, 2 = bf16 per-head transposed
//        (vt[b][h][d][tok] : idx = (row>>11)*2097152 + col*2048 + (row&2047)).
// ---------------------------------------------------------------------------
#define BKK 64

template<int OMODE>
__global__ __launch_bounds__(256, 1) void gemm_mfma(
    const unsigned short* __restrict__ A, const unsigned short* __restrict__ Bt,
    const float* __restrict__ bias, const float* __restrict__ resid,
    void* __restrict__ C, int M, int N, int K)
{
    __shared__ unsigned short As[2][128 * BKK];
    __shared__ unsigned short Bs[2][128 * BKK];
    const int tid  = threadIdx.x;
    const int w    = tid >> 6;
    const int lane = tid & 63;
    const int lo   = lane & 15;
    const int hi   = lane >> 4;
    const int wm   = (w >> 1) * 64;
    const int wn   = (w & 1) * 64;
    const int m0   = blockIdx.y * 128;
    const int n0   = blockIdx.x * 128;

    const unsigned short* Ab = A  + (size_t)m0 * K;
    const unsigned short* Bb = Bt + (size_t)n0 * K;

    f32x4 acc[4][4];
    #pragma unroll
    for (int i = 0; i < 4; ++i)
        #pragma unroll
        for (int j = 0; j < 4; ++j) acc[i][j] = (f32x4){0.f, 0.f, 0.f, 0.f};

    const int NT = K / BKK;

    auto stage = [&](int buf, int t) {
        const int k0 = t * BKK;
        #pragma unroll
        for (int i = 0; i < 4; ++i) {
            const int c = i * 256 + tid;
            gload16(Ab + (size_t)(c >> 3) * K + k0 + (c & 7) * 8,
                    &As[buf][(i * 256 + w * 64) * 8], lane);
        }
        #pragma unroll
        for (int i = 0; i < 4; ++i) {
            const int c = i * 256 + tid;
            gload16(Bb + (size_t)(c >> 3) * K + k0 + (c & 7) * 8,
                    &Bs[buf][(i * 256 + w * 64) * 8], lane);
        }
    };

    stage(0, 0);
    __syncthreads();
    int cur = 0;
    for (int t = 0; t < NT; ++t) {
        if (t + 1 < NT) stage(cur ^ 1, t + 1);
        bf16x8 af[4][2], bfr[4][2];
        #pragma unroll
        for (int f = 0; f < 4; ++f)
            #pragma unroll
            for (int s = 0; s < 2; ++s) {
                af[f][s]  = *(const bf16x8*)&As[cur][(wm + f * 16 + lo) * BKK + s * 32 + hi * 8];
                bfr[f][s] = *(const bf16x8*)&Bs[cur][(wn + f * 16 + lo) * BKK + s * 32 + hi * 8];
            }
        #pragma unroll
        for (int s = 0; s < 2; ++s)
            #pragma unroll
            for (int fm = 0; fm < 4; ++fm)
                #pragma unroll
                for (int fn = 0; fn < 4; ++fn)
                    acc[fm][fn] = __builtin_amdgcn_mfma_f32_16x16x32_bf16(
                        af[fm][s], bfr[fn][s], acc[fm][fn], 0, 0, 0);
        __syncthreads();
        cur ^= 1;
    }

    #pragma unroll
    for (int fm = 0; fm < 4; ++fm) {
        const int row = m0 + wm + fm * 16 + hi * 4;
        #pragma unroll
        for (int fn = 0; fn < 4; ++fn) {
            const int col = n0 + wn + fn * 16 + lo;
            const float bv = bias[col];
            #pragma unroll
            for (int r = 0; r < 4; ++r) {
                float o = acc[fm][fn][r] + bv;
                if (OMODE == 0) {
                    o += resid[(size_t)(row + r) * N + col];
                    ((float*)C)[(size_t)(row + r) * N + col] = o;
                } else if (OMODE == 1) {
                    ((unsigned short*)C)[(size_t)(row + r) * N + col] = f2bf(o);
                } else {
                    ((unsigned short*)C)[(size_t)((row + r) >> 11) * 2097152
                                         + (size_t)col * 2048 + ((row + r) & 2047)] = f2bf(o);
                }
            }
        }
    }
}

// ---------------------------------------------------------------------------
// Swapped-QK^T 32x32 MFMA flash attention (m214/§B structure).
// Block = (b, h, 128 q-rows), 4 waves x 32 q-rows. KVBLK=64, dbuf LDS.
// S^T = mfma32x32x16(K, Q^T): lane's q = lane&31; 32 keys/lane in regs.
// Softmax lane-local (+1 shfl_xor(32)); P->A-frag via cvt_pk + permlane32_swap.
// V consumed from vt[b][h][d][tok] (pre-transposed by V-proj GEMM).
// ---------------------------------------------------------------------------
__global__ __launch_bounds__(256) void attn_mfma32(
    const unsigned short* __restrict__ qb, const unsigned short* __restrict__ kbm,
    const unsigned short* __restrict__ vt,
    const unsigned long long* __restrict__ mbits, unsigned short* __restrict__ ctx)
{
    __shared__ unsigned short Ks[2][64 * 64];   // [key][d] chunk-swizzled
    __shared__ unsigned short Vs[2][64 * 64];   // [d][key] chunk-swizzled
    const int tid  = threadIdx.x;
    const int w    = tid >> 6;
    const int lane = tid & 63;
    const int l31  = lane & 31;
    const int hi   = lane >> 5;
    const int q0   = blockIdx.x * 128;
    const int h    = blockIdx.y;
    const int b    = blockIdx.z;

    const float SCL = 0.125f * 1.44269504f;     // 1/sqrt(64) * log2(e)

    const size_t qkbase = (size_t)b * SEQ * D_MODEL + (size_t)h * DHEAD;
    const size_t vtbase = ((size_t)b * D_MODEL + h * DHEAD) * SEQ;

    // Q B-frags: lane's q-row = q0 + w*32 + l31; frag s covers d = s*16 + hi*8 ..+8
    const int qtok = q0 + w * 32 + l31;
    bf16x8 qA[4];
    #pragma unroll
    for (int s = 0; s < 4; ++s)
        qA[s] = *(const bf16x8*)(qb + qkbase + (size_t)qtok * D_MODEL + s * 16 + hi * 8);

    f32x16 o0 = {}, o1 = {};
    float m_i = -INFINITY, l_i = 0.f;

    const unsigned long long* mrow = mbits + ((size_t)b * SEQ + qtok) * (SEQ / 64);

    // staging: lane -> row (lane>>3), chunk (lane&7); source pre-swizzled so
    // linear glds dest yields chunk^=(row&7) layout (rule 21 / m173).
    const int srow = lane >> 3;
    const int sc   = lane & 7;

    auto stage = [&](int buf, int kt) {
        #pragma unroll
        for (int cc = 0; cc < 2; ++cc) {
            const int rb = w * 16 + cc * 8;
            const int r  = rb + srow;
            const int swz = sc ^ (r & 7);
            gload16(kbm + qkbase + (size_t)(kt * 64 + r) * D_MODEL + swz * 8,
                    &Ks[buf][rb * 64], lane);
            gload16(vt + vtbase + (size_t)r * SEQ + kt * 64 + swz * 8,
                    &Vs[buf][rb * 64], lane);
        }
    };

    stage(0, 0);
    __syncthreads();
    int cur = 0;

    for (int kt = 0; kt < SEQ / 64; ++kt) {
        if (kt + 1 < SEQ / 64) stage(cur ^ 1, kt + 1);
        const unsigned long long mw = mrow[kt] >> (4 * hi);

        // ---- QK^T: S^T[key][q], A=K rows, B=Q^T ----
        f32x16 st0 = {}, st1 = {};
        #pragma unroll
        for (int s = 0; s < 4; ++s) {
            bf16x8 kf0 = *(const bf16x8*)&Ks[cur][(l31) * 64 + ((2 * s + hi) ^ (l31 & 7)) * 8];
            st0 = __builtin_amdgcn_mfma_f32_32x32x16_bf16(kf0, qA[s], st0, 0, 0, 0);
            bf16x8 kf1 = *(const bf16x8*)&Ks[cur][(32 + l31) * 64 + ((2 * s + hi) ^ (l31 & 7)) * 8];
            st1 = __builtin_amdgcn_mfma_f32_32x32x16_bf16(kf1, qA[s], st1, 0, 0, 0);
        }

        // ---- mask + scale, lane-local max ----
        float rmax = -3.0e38f;
        #pragma unroll
        for (int r = 0; r < 16; ++r) {
            const int klo = (r & 3) + 8 * (r >> 2);   // +4*hi already folded into mw
            float x0 = st0[r] * SCL;
            float x1 = st1[r] * SCL;
            if ((mw >> klo) & 1ull)        x0 = -1e9f;
            if ((mw >> (klo + 32)) & 1ull) x1 = -1e9f;
            st0[r] = x0; st1[r] = x1;
            rmax = fmaxf(rmax, fmaxf(x0, x1));
        }
        rmax = fmaxf(rmax, __shfl_xor(rmax, 32, 64));

        // ---- defer-max (T13) ----
        const bool defer = (bool)__all(rmax - m_i <= 8.0f);
        float alpha = 1.f;
        if (!defer) {
            const float mn = fmaxf(m_i, rmax);
            alpha = exp2f(m_i - mn);
            m_i = mn;
        }
        float ls = 0.f;
        #pragma unroll
        for (int r = 0; r < 16; ++r) {
            float e0 = exp2f(st0[r] - m_i);
            float e1 = exp2f(st1[r] - m_i);
            st0[r] = e0; st1[r] = e1;
            ls += e0 + e1;
        }
        ls += __shfl_xor(ls, 32, 64);
        if (!defer) {
            l_i = l_i * alpha + ls;
            #pragma unroll
            for (int r = 0; r < 16; ++r) {
                const float aq = __shfl(alpha, (r & 3) + 8 * (r >> 2) + 4 * hi, 64);
                o0[r] *= aq; o1[r] *= aq;
            }
        } else {
            l_i += ls;
        }

        // ---- P -> bf16 A-frags (T12: cvt_pk + permlane32_swap) ----
        bf16x8 pa[4];
        #pragma unroll
        for (int s = 0; s < 4; ++s) {
            const int base = (s & 1) * 8;   // within st0 (s<2) or st1 (s>=2)
            unsigned av, bv2, cv, dv;
            if (s < 2) {
                av = cvtpk_bf16(st0[base + 0], st0[base + 1]);
                bv2 = cvtpk_bf16(st0[base + 4], st0[base + 5]);
                cv = cvtpk_bf16(st0[base + 2], st0[base + 3]);
                dv = cvtpk_bf16(st0[base + 6], st0[base + 7]);
            } else {
                av = cvtpk_bf16(st1[base + 0], st1[base + 1]);
                bv2 = cvtpk_bf16(st1[base + 4], st1[base + 5]);
                cv = cvtpk_bf16(st1[base + 2], st1[base + 3]);
                dv = cvtpk_bf16(st1[base + 6], st1[base + 7]);
            }
            asm("v_permlane32_swap_b32 %0, %1" : "+v"(av), "+v"(bv2));
            asm("v_permlane32_swap_b32 %0, %1" : "+v"(cv), "+v"(dv));
            int4 pk = make_int4((int)av, (int)cv, (int)bv2, (int)dv);
            pa[s] = __builtin_bit_cast(bf16x8, pk);
        }

        // ---- PV: O[q][d] += P @ V ; B-frag from Vs rows d, chunk 2s+hi ----
        #pragma unroll
        for (int s = 0; s < 4; ++s) {
            bf16x8 vf0 = *(const bf16x8*)&Vs[cur][(l31) * 64 + ((2 * s + hi) ^ (l31 & 7)) * 8];
            o0 = __builtin_amdgcn_mfma_f32_32x32x16_bf16(pa[s], vf0, o0, 0, 0, 0);
            bf16x8 vf1 = *(const bf16x8*)&Vs[cur][(32 + l31) * 64 + ((2 * s + hi) ^ (l31 & 7)) * 8];
            o1 = __builtin_amdgcn_mfma_f32_32x32x16_bf16(pa[s], vf1, o1, 0, 0, 0);
        }
        __syncthreads();
        cur ^= 1;
    }

    // ---- epilogue ----
    const float inv = 1.f / l_i;
    #pragma unroll
    for (int r = 0; r < 16; ++r) {
        const int qloc = (r & 3) + 8 * (r >> 2) + 4 * hi;
        const float iq = __shfl(inv, qloc, 64);
        unsigned short* dst = ctx + qkbase + (size_t)(q0 + w * 32 + qloc) * D_MODEL;
        dst[l31]      = f2bf(o0[r] * iq);
        dst[32 + l31] = f2bf(o1[r] * iq);
    }
}

// ---------------------------------------------------------------------------
// LayerNorm over last dim (1024). One block per row.
// ---------------------------------------------------------------------------
__global__ __launch_bounds__(256) void layernorm1024(
    const float* __restrict__ x, const float* __restrict__ gamma,
    const float* __restrict__ beta, float* __restrict__ out)
{
    const int row = blockIdx.x;
    const int tid = threadIdx.x;
    const float* xr = x + (size_t)row * D_MODEL;
    float4 v = *(const float4*)(xr + (tid << 2));
    float s = v.x + v.y + v.z + v.w;
    float q = v.x * v.x + v.y * v.y + v.z * v.z + v.w * v.w;
    #pragma unroll
    for (int off = 1; off < 64; off <<= 1) {
        s += __shfl_xor(s, off, 64);
        q += __shfl_xor(q, off, 64);
    }
    __shared__ float sw[4], qw_[4];
    const int wid = tid >> 6;
    if ((tid & 63) == 0) { sw[wid] = s; qw_[wid] = q; }
    __syncthreads();
    s = sw[0] + sw[1] + sw[2] + sw[3];
    q = qw_[0] + qw_[1] + qw_[2] + qw_[3];
    const float mu  = s * (1.f / D_MODEL);
    const float var = q * (1.f / D_MODEL) - mu * mu;
    const float a = var + 1e-5f;
    float inv = rsqrtf(a);
    inv = inv * (1.5f - 0.5f * a * inv * inv);
    float4 g  = *(const float4*)(gamma + (tid << 2));
    float4 bt = *(const float4*)(beta + (tid << 2));
    float4 o;
    o.x = (v.x - mu) * inv * g.x + bt.x;
    o.y = (v.y - mu) * inv * g.y + bt.y;
    o.z = (v.z - mu) * inv * g.z + bt.z;
    o.w = (v.w - mu) * inv * g.w + bt.w;
    *(float4*)(out + (size_t)row * D_MODEL + (tid << 2)) = o;
}

// ---------------------------------------------------------------------------
extern "C" void kernel_launch(void* const* d_in, const int* in_sizes, int n_in,
                              void* d_out, int out_size, void* d_ws, size_t ws_size,
                              hipStream_t stream)
{
    const float* Q    = (const float*)d_in[0];
    const float* K    = (const float*)d_in[1];
    const float* V    = (const float*)d_in[2];
    const void*  mask = d_in[3];
    const float* Wq   = (const float*)d_in[4];
    const float* bq   = (const float*)d_in[5];
    const float* Wk   = (const float*)d_in[6];
    const float* bk   = (const float*)d_in[7];
    const float* Wv   = (const float*)d_in[8];
    const float* bv   = (const float*)d_in[9];
    const float* Wo   = (const float*)d_in[10];
    const float* bo   = (const float*)d_in[11];
    const float* gam  = (const float*)d_in[12];
    const float* bet  = (const float*)d_in[13];
    float* out = (float*)d_out;

    const size_t NE = (size_t)MROWS * D_MODEL;           // 4,194,304 elems
    const size_t WE = (size_t)D_MODEL * D_MODEL;
    unsigned short* Qbf = (unsigned short*)d_ws;         // reused as ctxb
    unsigned short* Kbf = Qbf + NE;                      // Kbf+Vbf reused as outp
    unsigned short* Vbf = Kbf + NE;
    unsigned short* qb  = Vbf + NE;
    unsigned short* kb  = qb + NE;
    unsigned short* vt  = kb + NE;                       // [b][h][d][tok]
    unsigned short* Wt0 = vt + NE;
    unsigned short* Wt1 = Wt0 + WE;
    unsigned short* Wt2 = Wt1 + WE;
    unsigned short* Wt3 = Wt2 + WE;
    unsigned long long* mbits = (unsigned long long*)(Wt3 + WE);
    const size_t NMW = (size_t)BATCH * SEQ * (SEQ / 64);
    int* mflag = (int*)(mbits + NMW);
    unsigned short* ctxb = Qbf;
    float* outp = (float*)Kbf;
    if (ws_size < 6 * NE * 2 + 4 * WE * 2 + NMW * 8 + 64) return;

    detect_mask<<<1, 256, 0, stream>>>((const unsigned int*)mask, 65536, mflag);
    pack_mask<<<(int)((NMW + 255) / 256), 256, 0, stream>>>(mask, mflag, mbits, (int)NMW);

    cvt_bf16<<<dim3(NE / 8 / 256, 3), 256, 0, stream>>>(Q, K, V, Qbf, Kbf, Vbf);
    cvt_wT<<<dim3(16, 16, 4), 256, 0, stream>>>(Wq, Wk, Wv, Wo, Wt0, Wt1, Wt2, Wt3);

    dim3 gg(D_MODEL / 128, MROWS / 128);   // (8, 32)
    gemm_mfma<1><<<gg, 256, 0, stream>>>(Qbf, Wt0, bq, nullptr, qb, MROWS, D_MODEL, D_MODEL);
    gemm_mfma<1><<<gg, 256, 0, stream>>>(Kbf, Wt1, bk, nullptr, kb, MROWS, D_MODEL, D_MODEL);
    gemm_mfma<2><<<gg, 256, 0, stream>>>(Vbf, Wt2, bv, nullptr, vt, MROWS, D_MODEL, D_MODEL);

    dim3 ag(SEQ / 128, NHEADS, BATCH);     // (16, 16, 2)
    attn_mfma32<<<ag, 256, 0, stream>>>(qb, kb, vt, mbits, ctxb);

    gemm_mfma<0><<<gg, 256, 0, stream>>>(ctxb, Wt3, bo, Q, outp, MROWS, D_MODEL, D_MODEL);

    layernorm1024<<<MROWS, 256, 0, stream>>>(outp, gam, bet, out);
}

// Round 5
// 250.652 us; speedup vs baseline: 8.2115x; 1.2224x over previous
//
#include <hip/hip_runtime.h>
#include <hip/hip_bf16.h>
#include <math.h>

// Fused MHA block: proj(Q,K,V) -> masked softmax attention -> out proj + residual -> LayerNorm
// Round 5: parallelized mask-dtype probe (was a 113us serial single-block kernel!);
// Q/K/V projection GEMMs merged into one launch (blockIdx.z). Attention (swapped-QK^T
// 32x32 MFMA) and GEMM cores unchanged from round 4.

#define D_MODEL 1024
#define NHEADS  16
#define DHEAD   64
#define BATCH   2
#define SEQ     2048
#define MROWS   (BATCH * SEQ)   // 4096

typedef __attribute__((ext_vector_type(8)))  short bf16x8;
typedef __attribute__((ext_vector_type(4)))  float f32x4;
typedef __attribute__((ext_vector_type(16))) float f32x16;

__device__ inline unsigned short f2bf(float f) {
    unsigned int u = __builtin_bit_cast(unsigned int, f);
    unsigned int r = (u + 0x7FFFu + ((u >> 16) & 1u)) >> 16;   // RNE
    return (unsigned short)r;
}

__device__ inline unsigned cvtpk_bf16(float lo, float hi2) {
    unsigned r;
    asm("v_cvt_pk_bf16_f32 %0, %1, %2" : "=v"(r) : "v"(lo), "v"(hi2));
    return r;
}

// global -> LDS direct copy, 16B per lane. lbase must be wave-uniform.
__device__ inline void gload16(const unsigned short* g, unsigned short* lbase, int lane) {
#if __has_builtin(__builtin_amdgcn_global_load_lds)
    __builtin_amdgcn_global_load_lds(
        (const __attribute__((address_space(1))) unsigned int*)g,
        (__attribute__((address_space(3))) unsigned int*)lbase, 16, 0, 0);
#else
    *(bf16x8*)(lbase + lane * 8) = *(const bf16x8*)g;
#endif
}

// ---------------------------------------------------------------------------
// Parallel mask dtype probe. flags[0]: any word not in {0,1};
// flags[1]: any word not in {0, 0x3F800000}. flags pre-zeroed via memset.
// ---------------------------------------------------------------------------
__global__ __launch_bounds__(256) void detect_mask_par(
    const unsigned int* __restrict__ m, int nwords, int* __restrict__ flags)
{
    const int i = blockIdx.x * 256 + threadIdx.x;
    int a = 0, b = 0;
    if (i < nwords) {
        const unsigned int w = m[i];
        a = (w != 0u && w != 1u);
        b = (w != 0u && w != 0x3F800000u);
    }
    const int wa = (int)__any(a);
    const int wb = (int)__any(b);
    if ((threadIdx.x & 63) == 0) {
        if (wa) atomicOr(&flags[0], 1);
        if (wb) atomicOr(&flags[1], 1);
    }
}

// ---------------------------------------------------------------------------
// Pack mask to 1 bit per entry: mbits[b][q][kword] (kword = 64 keys).
// dtype derived from flags: !flags[0] -> int32; else !flags[1] -> f32; else u8.
// ---------------------------------------------------------------------------
__global__ __launch_bounds__(256) void pack_mask(
    const void* __restrict__ mask, const int* __restrict__ flags,
    unsigned long long* __restrict__ mbits, int nwords)
{
    int idx = blockIdx.x * blockDim.x + threadIdx.x;
    if (idx >= nwords) return;
    const int mf = (flags[0] == 0) ? 0 : (flags[1] == 0) ? 1 : 2;
    unsigned long long bits = 0ull;
    if (mf == 2) {
        const unsigned int* p = (const unsigned int*)mask + (size_t)idx * 16;
        #pragma unroll
        for (int i = 0; i < 16; ++i) {
            unsigned int w = p[i] & 0x01010101u;
            unsigned int nib = (w * 0x01020408u) >> 24;
            bits |= (unsigned long long)(nib & 0xFu) << (i * 4);
        }
    } else if (mf == 0) {
        const unsigned int* p = (const unsigned int*)mask + (size_t)idx * 64;
        #pragma unroll
        for (int i = 0; i < 64; ++i)
            bits |= (unsigned long long)(p[i] & 1u) << i;
    } else {
        const float* p = (const float*)mask + (size_t)idx * 64;
        #pragma unroll
        for (int i = 0; i < 64; ++i)
            bits |= (unsigned long long)(p[i] != 0.f) << i;
    }
    mbits[idx] = bits;
}

// ---------------------------------------------------------------------------
// fp32 -> bf16 convert for Q,K,V (blockIdx.y selects tensor). 8 elems/thread.
// ---------------------------------------------------------------------------
__global__ __launch_bounds__(256) void cvt_bf16(
    const float* __restrict__ s0, const float* __restrict__ s1,
    const float* __restrict__ s2,
    unsigned short* __restrict__ d0, unsigned short* __restrict__ d1,
    unsigned short* __restrict__ d2)
{
    const float* s = (blockIdx.y == 0) ? s0 : (blockIdx.y == 1) ? s1 : s2;
    unsigned short* d = (blockIdx.y == 0) ? d0 : (blockIdx.y == 1) ? d1 : d2;
    const int i = blockIdx.x * 256 + threadIdx.x;
    float4 a = ((const float4*)s)[i * 2];
    float4 b = ((const float4*)s)[i * 2 + 1];
    ushort4 u0, u1;
    u0.x = f2bf(a.x); u0.y = f2bf(a.y); u0.z = f2bf(a.z); u0.w = f2bf(a.w);
    u1.x = f2bf(b.x); u1.y = f2bf(b.y); u1.z = f2bf(b.z); u1.w = f2bf(b.w);
    ((ushort4*)d)[i * 2] = u0;
    ((ushort4*)d)[i * 2 + 1] = u1;
}

// ---------------------------------------------------------------------------
// Weight transpose-convert: W fp32 [K][N] -> Wt bf16 [N][K].
// ---------------------------------------------------------------------------
__global__ __launch_bounds__(256) void cvt_wT(
    const float* __restrict__ w0, const float* __restrict__ w1,
    const float* __restrict__ w2, const float* __restrict__ w3,
    unsigned short* __restrict__ t0, unsigned short* __restrict__ t1,
    unsigned short* __restrict__ t2, unsigned short* __restrict__ t3)
{
    __shared__ float tile[64][65];
    const float* W = (blockIdx.z == 0) ? w0 : (blockIdx.z == 1) ? w1
                   : (blockIdx.z == 2) ? w2 : w3;
    unsigned short* T = (blockIdx.z == 0) ? t0 : (blockIdx.z == 1) ? t1
                      : (blockIdx.z == 2) ? t2 : t3;
    const int k0 = blockIdx.y * 64;
    const int n0 = blockIdx.x * 64;
    const int t  = threadIdx.x;
    const int r  = t >> 4;
    const int c4 = (t & 15) * 4;
    #pragma unroll
    for (int u = 0; u < 4; ++u) {
        float4 v = *(const float4*)(W + (size_t)(k0 + r + u * 16) * D_MODEL + n0 + c4);
        tile[r + u * 16][c4 + 0] = v.x;
        tile[r + u * 16][c4 + 1] = v.y;
        tile[r + u * 16][c4 + 2] = v.z;
        tile[r + u * 16][c4 + 3] = v.w;
    }
    __syncthreads();
    #pragma unroll
    for (int u = 0; u < 4; ++u) {
        const int nr = r + u * 16;
        ushort4 o;
        o.x = f2bf(tile[c4 + 0][nr]);
        o.y = f2bf(tile[c4 + 1][nr]);
        o.z = f2bf(tile[c4 + 2][nr]);
        o.w = f2bf(tile[c4 + 3][nr]);
        *(ushort4*)(T + (size_t)(n0 + nr) * D_MODEL + k0 + c4) = o;
    }
}

// ---------------------------------------------------------------------------
// Shared MFMA GEMM core as a macro-like device function body via templates.
// 128x128 tile, BK=64, 256 threads (4 waves, 2x2, 64x64 out each),
// 2-phase double-buffered LDS, global_load_lds 16B staging.
// ---------------------------------------------------------------------------
#define BKK 64

// Merged Q/K/V projection GEMM. blockIdx.z selects tensor; z<2 -> bf16
// row-major out; z==2 -> bf16 per-head transposed vt[b][h][d][tok].
__global__ __launch_bounds__(256, 1) void gemm_qkv(
    const unsigned short* __restrict__ A0, const unsigned short* __restrict__ A1,
    const unsigned short* __restrict__ A2,
    const unsigned short* __restrict__ B0, const unsigned short* __restrict__ B1,
    const unsigned short* __restrict__ B2,
    const float* __restrict__ bias0, const float* __restrict__ bias1,
    const float* __restrict__ bias2,
    unsigned short* __restrict__ C0, unsigned short* __restrict__ C1,
    unsigned short* __restrict__ C2)
{
    const int z = blockIdx.z;
    const unsigned short* A  = (z == 0) ? A0 : (z == 1) ? A1 : A2;
    const unsigned short* Bt = (z == 0) ? B0 : (z == 1) ? B1 : B2;
    const float* bias        = (z == 0) ? bias0 : (z == 1) ? bias1 : bias2;
    unsigned short* C        = (z == 0) ? C0 : (z == 1) ? C1 : C2;
    const int K = D_MODEL, N = D_MODEL;

    __shared__ unsigned short As[2][128 * BKK];
    __shared__ unsigned short Bs[2][128 * BKK];
    const int tid  = threadIdx.x;
    const int w    = tid >> 6;
    const int lane = tid & 63;
    const int lo   = lane & 15;
    const int hi   = lane >> 4;
    const int wm   = (w >> 1) * 64;
    const int wn   = (w & 1) * 64;
    const int m0   = blockIdx.y * 128;
    const int n0   = blockIdx.x * 128;

    const unsigned short* Ab = A  + (size_t)m0 * K;
    const unsigned short* Bb = Bt + (size_t)n0 * K;

    f32x4 acc[4][4];
    #pragma unroll
    for (int i = 0; i < 4; ++i)
        #pragma unroll
        for (int j = 0; j < 4; ++j) acc[i][j] = (f32x4){0.f, 0.f, 0.f, 0.f};

    const int NT = K / BKK;
    auto stage = [&](int buf, int t) {
        const int k0 = t * BKK;
        #pragma unroll
        for (int i = 0; i < 4; ++i) {
            const int c = i * 256 + tid;
            gload16(Ab + (size_t)(c >> 3) * K + k0 + (c & 7) * 8,
                    &As[buf][(i * 256 + w * 64) * 8], lane);
        }
        #pragma unroll
        for (int i = 0; i < 4; ++i) {
            const int c = i * 256 + tid;
            gload16(Bb + (size_t)(c >> 3) * K + k0 + (c & 7) * 8,
                    &Bs[buf][(i * 256 + w * 64) * 8], lane);
        }
    };

    stage(0, 0);
    __syncthreads();
    int cur = 0;
    for (int t = 0; t < NT; ++t) {
        if (t + 1 < NT) stage(cur ^ 1, t + 1);
        bf16x8 af[4][2], bfr[4][2];
        #pragma unroll
        for (int f = 0; f < 4; ++f)
            #pragma unroll
            for (int s = 0; s < 2; ++s) {
                af[f][s]  = *(const bf16x8*)&As[cur][(wm + f * 16 + lo) * BKK + s * 32 + hi * 8];
                bfr[f][s] = *(const bf16x8*)&Bs[cur][(wn + f * 16 + lo) * BKK + s * 32 + hi * 8];
            }
        #pragma unroll
        for (int s = 0; s < 2; ++s)
            #pragma unroll
            for (int fm = 0; fm < 4; ++fm)
                #pragma unroll
                for (int fn = 0; fn < 4; ++fn)
                    acc[fm][fn] = __builtin_amdgcn_mfma_f32_16x16x32_bf16(
                        af[fm][s], bfr[fn][s], acc[fm][fn], 0, 0, 0);
        __syncthreads();
        cur ^= 1;
    }

    #pragma unroll
    for (int fm = 0; fm < 4; ++fm) {
        const int row = m0 + wm + fm * 16 + hi * 4;
        #pragma unroll
        for (int fn = 0; fn < 4; ++fn) {
            const int col = n0 + wn + fn * 16 + lo;
            const float bv = bias[col];
            #pragma unroll
            for (int r = 0; r < 4; ++r) {
                const float o = acc[fm][fn][r] + bv;
                if (z < 2)
                    C[(size_t)(row + r) * N + col] = f2bf(o);
                else
                    C[(size_t)((row + r) >> 11) * 2097152
                      + (size_t)col * 2048 + ((row + r) & 2047)] = f2bf(o);
            }
        }
    }
}

// Out-projection GEMM: fp32 out + residual add.
__global__ __launch_bounds__(256, 1) void gemm_out(
    const unsigned short* __restrict__ A, const unsigned short* __restrict__ Bt,
    const float* __restrict__ bias, const float* __restrict__ resid,
    float* __restrict__ C)
{
    const int K = D_MODEL, N = D_MODEL;
    __shared__ unsigned short As[2][128 * BKK];
    __shared__ unsigned short Bs[2][128 * BKK];
    const int tid  = threadIdx.x;
    const int w    = tid >> 6;
    const int lane = tid & 63;
    const int lo   = lane & 15;
    const int hi   = lane >> 4;
    const int wm   = (w >> 1) * 64;
    const int wn   = (w & 1) * 64;
    const int m0   = blockIdx.y * 128;
    const int n0   = blockIdx.x * 128;

    const unsigned short* Ab = A  + (size_t)m0 * K;
    const unsigned short* Bb = Bt + (size_t)n0 * K;

    f32x4 acc[4][4];
    #pragma unroll
    for (int i = 0; i < 4; ++i)
        #pragma unroll
        for (int j = 0; j < 4; ++j) acc[i][j] = (f32x4){0.f, 0.f, 0.f, 0.f};

    const int NT = K / BKK;
    auto stage = [&](int buf, int t) {
        const int k0 = t * BKK;
        #pragma unroll
        for (int i = 0; i < 4; ++i) {
            const int c = i * 256 + tid;
            gload16(Ab + (size_t)(c >> 3) * K + k0 + (c & 7) * 8,
                    &As[buf][(i * 256 + w * 64) * 8], lane);
        }
        #pragma unroll
        for (int i = 0; i < 4; ++i) {
            const int c = i * 256 + tid;
            gload16(Bb + (size_t)(c >> 3) * K + k0 + (c & 7) * 8,
                    &Bs[buf][(i * 256 + w * 64) * 8], lane);
        }
    };

    stage(0, 0);
    __syncthreads();
    int cur = 0;
    for (int t = 0; t < NT; ++t) {
        if (t + 1 < NT) stage(cur ^ 1, t + 1);
        bf16x8 af[4][2], bfr[4][2];
        #pragma unroll
        for (int f = 0; f < 4; ++f)
            #pragma unroll
            for (int s = 0; s < 2; ++s) {
                af[f][s]  = *(const bf16x8*)&As[cur][(wm + f * 16 + lo) * BKK + s * 32 + hi * 8];
                bfr[f][s] = *(const bf16x8*)&Bs[cur][(wn + f * 16 + lo) * BKK + s * 32 + hi * 8];
            }
        #pragma unroll
        for (int s = 0; s < 2; ++s)
            #pragma unroll
            for (int fm = 0; fm < 4; ++fm)
                #pragma unroll
                for (int fn = 0; fn < 4; ++fn)
                    acc[fm][fn] = __builtin_amdgcn_mfma_f32_16x16x32_bf16(
                        af[fm][s], bfr[fn][s], acc[fm][fn], 0, 0, 0);
        __syncthreads();
        cur ^= 1;
    }

    #pragma unroll
    for (int fm = 0; fm < 4; ++fm) {
        const int row = m0 + wm + fm * 16 + hi * 4;
        #pragma unroll
        for (int fn = 0; fn < 4; ++fn) {
            const int col = n0 + wn + fn * 16 + lo;
            const float bv = bias[col];
            #pragma unroll
            for (int r = 0; r < 4; ++r)
                C[(size_t)(row + r) * N + col] =
                    acc[fm][fn][r] + bv + resid[(size_t)(row + r) * N + col];
        }
    }
}

// ---------------------------------------------------------------------------
// Swapped-QK^T 32x32 MFMA flash attention (m214/§B structure).
// Block = (b, h, 128 q-rows), 4 waves x 32 q-rows. KVBLK=64, dbuf LDS.
// ---------------------------------------------------------------------------
__global__ __launch_bounds__(256) void attn_mfma32(
    const unsigned short* __restrict__ qb, const unsigned short* __restrict__ kbm,
    const unsigned short* __restrict__ vt,
    const unsigned long long* __restrict__ mbits, unsigned short* __restrict__ ctx)
{
    __shared__ unsigned short Ks[2][64 * 64];   // [key][d] chunk-swizzled
    __shared__ unsigned short Vs[2][64 * 64];   // [d][key] chunk-swizzled
    const int tid  = threadIdx.x;
    const int w    = tid >> 6;
    const int lane = tid & 63;
    const int l31  = lane & 31;
    const int hi   = lane >> 5;
    const int q0   = blockIdx.x * 128;
    const int h    = blockIdx.y;
    const int b    = blockIdx.z;

    const float SCL = 0.125f * 1.44269504f;     // 1/sqrt(64) * log2(e)

    const size_t qkbase = (size_t)b * SEQ * D_MODEL + (size_t)h * DHEAD;
    const size_t vtbase = ((size_t)b * D_MODEL + h * DHEAD) * SEQ;

    const int qtok = q0 + w * 32 + l31;
    bf16x8 qA[4];
    #pragma unroll
    for (int s = 0; s < 4; ++s)
        qA[s] = *(const bf16x8*)(qb + qkbase + (size_t)qtok * D_MODEL + s * 16 + hi * 8);

    f32x16 o0 = {}, o1 = {};
    float m_i = -INFINITY, l_i = 0.f;

    const unsigned long long* mrow = mbits + ((size_t)b * SEQ + qtok) * (SEQ / 64);

    const int srow = lane >> 3;
    const int sc   = lane & 7;

    auto stage = [&](int buf, int kt) {
        #pragma unroll
        for (int cc = 0; cc < 2; ++cc) {
            const int rb = w * 16 + cc * 8;
            const int r  = rb + srow;
            const int swz = sc ^ (r & 7);
            gload16(kbm + qkbase + (size_t)(kt * 64 + r) * D_MODEL + swz * 8,
                    &Ks[buf][rb * 64], lane);
            gload16(vt + vtbase + (size_t)r * SEQ + kt * 64 + swz * 8,
                    &Vs[buf][rb * 64], lane);
        }
    };

    stage(0, 0);
    __syncthreads();
    int cur = 0;

    for (int kt = 0; kt < SEQ / 64; ++kt) {
        if (kt + 1 < SEQ / 64) stage(cur ^ 1, kt + 1);
        const unsigned long long mw = mrow[kt] >> (4 * hi);

        f32x16 st0 = {}, st1 = {};
        #pragma unroll
        for (int s = 0; s < 4; ++s) {
            bf16x8 kf0 = *(const bf16x8*)&Ks[cur][(l31) * 64 + ((2 * s + hi) ^ (l31 & 7)) * 8];
            st0 = __builtin_amdgcn_mfma_f32_32x32x16_bf16(kf0, qA[s], st0, 0, 0, 0);
            bf16x8 kf1 = *(const bf16x8*)&Ks[cur][(32 + l31) * 64 + ((2 * s + hi) ^ (l31 & 7)) * 8];
            st1 = __builtin_amdgcn_mfma_f32_32x32x16_bf16(kf1, qA[s], st1, 0, 0, 0);
        }

        float rmax = -3.0e38f;
        #pragma unroll
        for (int r = 0; r < 16; ++r) {
            const int klo = (r & 3) + 8 * (r >> 2);
            float x0 = st0[r] * SCL;
            float x1 = st1[r] * SCL;
            if ((mw >> klo) & 1ull)        x0 = -1e9f;
            if ((mw >> (klo + 32)) & 1ull) x1 = -1e9f;
            st0[r] = x0; st1[r] = x1;
            rmax = fmaxf(rmax, fmaxf(x0, x1));
        }
        rmax = fmaxf(rmax, __shfl_xor(rmax, 32, 64));

        const bool defer = (bool)__all(rmax - m_i <= 8.0f);
        float alpha = 1.f;
        if (!defer) {
            const float mn = fmaxf(m_i, rmax);
            alpha = exp2f(m_i - mn);
            m_i = mn;
        }
        float ls = 0.f;
        #pragma unroll
        for (int r = 0; r < 16; ++r) {
            float e0 = exp2f(st0[r] - m_i);
            float e1 = exp2f(st1[r] - m_i);
            st0[r] = e0; st1[r] = e1;
            ls += e0 + e1;
        }
        ls += __shfl_xor(ls, 32, 64);
        if (!defer) {
            l_i = l_i * alpha + ls;
            #pragma unroll
            for (int r = 0; r < 16; ++r) {
                const float aq = __shfl(alpha, (r & 3) + 8 * (r >> 2) + 4 * hi, 64);
                o0[r] *= aq; o1[r] *= aq;
            }
        } else {
            l_i += ls;
        }

        bf16x8 pa[4];
        #pragma unroll
        for (int s = 0; s < 4; ++s) {
            const int base = (s & 1) * 8;
            unsigned av, bv2, cv, dv;
            if (s < 2) {
                av = cvtpk_bf16(st0[base + 0], st0[base + 1]);
                bv2 = cvtpk_bf16(st0[base + 4], st0[base + 5]);
                cv = cvtpk_bf16(st0[base + 2], st0[base + 3]);
                dv = cvtpk_bf16(st0[base + 6], st0[base + 7]);
            } else {
                av = cvtpk_bf16(st1[base + 0], st1[base + 1]);
                bv2 = cvtpk_bf16(st1[base + 4], st1[base + 5]);
                cv = cvtpk_bf16(st1[base + 2], st1[base + 3]);
                dv = cvtpk_bf16(st1[base + 6], st1[base + 7]);
            }
            asm("v_permlane32_swap_b32 %0, %1" : "+v"(av), "+v"(bv2));
            asm("v_permlane32_swap_b32 %0, %1" : "+v"(cv), "+v"(dv));
            int4 pk = make_int4((int)av, (int)cv, (int)bv2, (int)dv);
            pa[s] = __builtin_bit_cast(bf16x8, pk);
        }

        #pragma unroll
        for (int s = 0; s < 4; ++s) {
            bf16x8 vf0 = *(const bf16x8*)&Vs[cur][(l31) * 64 + ((2 * s + hi) ^ (l31 & 7)) * 8];
            o0 = __builtin_amdgcn_mfma_f32_32x32x16_bf16(pa[s], vf0, o0, 0, 0, 0);
            bf16x8 vf1 = *(const bf16x8*)&Vs[cur][(32 + l31) * 64 + ((2 * s + hi) ^ (l31 & 7)) * 8];
            o1 = __builtin_amdgcn_mfma_f32_32x32x16_bf16(pa[s], vf1, o1, 0, 0, 0);
        }
        __syncthreads();
        cur ^= 1;
    }

    const float inv = 1.f / l_i;
    #pragma unroll
    for (int r = 0; r < 16; ++r) {
        const int qloc = (r & 3) + 8 * (r >> 2) + 4 * hi;
        const float iq = __shfl(inv, qloc, 64);
        unsigned short* dst = ctx + qkbase + (size_t)(q0 + w * 32 + qloc) * D_MODEL;
        dst[l31]      = f2bf(o0[r] * iq);
        dst[32 + l31] = f2bf(o1[r] * iq);
    }
}

// ---------------------------------------------------------------------------
// LayerNorm over last dim (1024). One block per row.
// ---------------------------------------------------------------------------
__global__ __launch_bounds__(256) void layernorm1024(
    const float* __restrict__ x, const float* __restrict__ gamma,
    const float* __restrict__ beta, float* __restrict__ out)
{
    const int row = blockIdx.x;
    const int tid = threadIdx.x;
    const float* xr = x + (size_t)row * D_MODEL;
    float4 v = *(const float4*)(xr + (tid << 2));
    float s = v.x + v.y + v.z + v.w;
    float q = v.x * v.x + v.y * v.y + v.z * v.z + v.w * v.w;
    #pragma unroll
    for (int off = 1; off < 64; off <<= 1) {
        s += __shfl_xor(s, off, 64);
        q += __shfl_xor(q, off, 64);
    }
    __shared__ float sw[4], qw_[4];
    const int wid = tid >> 6;
    if ((tid & 63) == 0) { sw[wid] = s; qw_[wid] = q; }
    __syncthreads();
    s = sw[0] + sw[1] + sw[2] + sw[3];
    q = qw_[0] + qw_[1] + qw_[2] + qw_[3];
    const float mu  = s * (1.f / D_MODEL);
    const float var = q * (1.f / D_MODEL) - mu * mu;
    const float a = var + 1e-5f;
    float inv = rsqrtf(a);
    inv = inv * (1.5f - 0.5f * a * inv * inv);
    float4 g  = *(const float4*)(gamma + (tid << 2));
    float4 bt = *(const float4*)(beta + (tid << 2));
    float4 o;
    o.x = (v.x - mu) * inv * g.x + bt.x;
    o.y = (v.y - mu) * inv * g.y + bt.y;
    o.z = (v.z - mu) * inv * g.z + bt.z;
    o.w = (v.w - mu) * inv * g.w + bt.w;
    *(float4*)(out + (size_t)row * D_MODEL + (tid << 2)) = o;
}

// ---------------------------------------------------------------------------
extern "C" void kernel_launch(void* const* d_in, const int* in_sizes, int n_in,
                              void* d_out, int out_size, void* d_ws, size_t ws_size,
                              hipStream_t stream)
{
    const float* Q    = (const float*)d_in[0];
    const float* K    = (const float*)d_in[1];
    const float* V    = (const float*)d_in[2];
    const void*  mask = d_in[3];
    const float* Wq   = (const float*)d_in[4];
    const float* bq   = (const float*)d_in[5];
    const float* Wk   = (const float*)d_in[6];
    const float* bk   = (const float*)d_in[7];
    const float* Wv   = (const float*)d_in[8];
    const float* bv   = (const float*)d_in[9];
    const float* Wo   = (const float*)d_in[10];
    const float* bo   = (const float*)d_in[11];
    const float* gam  = (const float*)d_in[12];
    const float* bet  = (const float*)d_in[13];
    float* out = (float*)d_out;

    const size_t NE = (size_t)MROWS * D_MODEL;           // 4,194,304 elems
    const size_t WE = (size_t)D_MODEL * D_MODEL;
    unsigned short* Qbf = (unsigned short*)d_ws;         // reused as ctxb
    unsigned short* Kbf = Qbf + NE;                      // Kbf+Vbf reused as outp
    unsigned short* Vbf = Kbf + NE;
    unsigned short* qb  = Vbf + NE;
    unsigned short* kb  = qb + NE;
    unsigned short* vt  = kb + NE;                       // [b][h][d][tok]
    unsigned short* Wt0 = vt + NE;
    unsigned short* Wt1 = Wt0 + WE;
    unsigned short* Wt2 = Wt1 + WE;
    unsigned short* Wt3 = Wt2 + WE;
    unsigned long long* mbits = (unsigned long long*)(Wt3 + WE);
    const size_t NMW = (size_t)BATCH * SEQ * (SEQ / 64);
    int* mflags = (int*)(mbits + NMW);
    unsigned short* ctxb = Qbf;
    float* outp = (float*)Kbf;
    if (ws_size < 6 * NE * 2 + 4 * WE * 2 + NMW * 8 + 64) return;

    hipMemsetAsync(mflags, 0, 2 * sizeof(int), stream);
    detect_mask_par<<<256, 256, 0, stream>>>((const unsigned int*)mask, 65536, mflags);
    pack_mask<<<(int)((NMW + 255) / 256), 256, 0, stream>>>(mask, mflags, mbits, (int)NMW);

    cvt_bf16<<<dim3(NE / 8 / 256, 3), 256, 0, stream>>>(Q, K, V, Qbf, Kbf, Vbf);
    cvt_wT<<<dim3(16, 16, 4), 256, 0, stream>>>(Wq, Wk, Wv, Wo, Wt0, Wt1, Wt2, Wt3);

    gemm_qkv<<<dim3(8, 32, 3), 256, 0, stream>>>(Qbf, Kbf, Vbf, Wt0, Wt1, Wt2,
                                                 bq, bk, bv, qb, kb, vt);

    dim3 ag(SEQ / 128, NHEADS, BATCH);     // (16, 16, 2)
    attn_mfma32<<<ag, 256, 0, stream>>>(qb, kb, vt, mbits, ctxb);

    gemm_out<<<dim3(8, 32), 256, 0, stream>>>(ctxb, Wt3, bo, Q, outp);

    layernorm1024<<<MROWS, 256, 0, stream>>>(outp, gam, bet, out);
}

// Round 6
// 248.508 us; speedup vs baseline: 8.2824x; 1.0086x over previous
//
#include <hip/hip_runtime.h>
#include <hip/hip_bf16.h>
#include <math.h>

// Fused MHA block: proj(Q,K,V) -> masked softmax attention -> out proj + residual -> LayerNorm
// Round 6: attention occupancy 2x via in-block K-split (8 waves = 2 k-groups x 4 q-waves,
// flash-combine through LDS at the end); softmax scale folded into Q-projection epilogue;
// 32-bit mask extraction; s_setprio around MFMA clusters. GEMM cores unchanged.

#define D_MODEL 1024
#define NHEADS  16
#define DHEAD   64
#define BATCH   2
#define SEQ     2048
#define MROWS   (BATCH * SEQ)   // 4096
#define SCLF    0.18033688f     // 0.125 * log2(e), folded into Q projection

typedef __attribute__((ext_vector_type(8)))  short bf16x8;
typedef __attribute__((ext_vector_type(4)))  float f32x4;
typedef __attribute__((ext_vector_type(16))) float f32x16;

__device__ inline unsigned short f2bf(float f) {
    unsigned int u = __builtin_bit_cast(unsigned int, f);
    unsigned int r = (u + 0x7FFFu + ((u >> 16) & 1u)) >> 16;   // RNE
    return (unsigned short)r;
}

__device__ inline unsigned cvtpk_bf16(float lo, float hi2) {
    unsigned r;
    asm("v_cvt_pk_bf16_f32 %0, %1, %2" : "=v"(r) : "v"(lo), "v"(hi2));
    return r;
}

// global -> LDS direct copy, 16B per lane. lbase must be wave-uniform.
__device__ inline void gload16(const unsigned short* g, unsigned short* lbase, int lane) {
#if __has_builtin(__builtin_amdgcn_global_load_lds)
    __builtin_amdgcn_global_load_lds(
        (const __attribute__((address_space(1))) unsigned int*)g,
        (__attribute__((address_space(3))) unsigned int*)lbase, 16, 0, 0);
#else
    *(bf16x8*)(lbase + lane * 8) = *(const bf16x8*)g;
#endif
}

// ---------------------------------------------------------------------------
// Parallel mask dtype probe. flags[0]: any word not in {0,1};
// flags[1]: any word not in {0, 0x3F800000}. flags pre-zeroed via memset.
// ---------------------------------------------------------------------------
__global__ __launch_bounds__(256) void detect_mask_par(
    const unsigned int* __restrict__ m, int nwords, int* __restrict__ flags)
{
    const int i = blockIdx.x * 256 + threadIdx.x;
    int a = 0, b = 0;
    if (i < nwords) {
        const unsigned int w = m[i];
        a = (w != 0u && w != 1u);
        b = (w != 0u && w != 0x3F800000u);
    }
    const int wa = (int)__any(a);
    const int wb = (int)__any(b);
    if ((threadIdx.x & 63) == 0) {
        if (wa) atomicOr(&flags[0], 1);
        if (wb) atomicOr(&flags[1], 1);
    }
}

// ---------------------------------------------------------------------------
// Pack mask to 1 bit per entry: mbits[b][q][kword] (kword = 64 keys).
// ---------------------------------------------------------------------------
__global__ __launch_bounds__(256) void pack_mask(
    const void* __restrict__ mask, const int* __restrict__ flags,
    unsigned long long* __restrict__ mbits, int nwords)
{
    int idx = blockIdx.x * blockDim.x + threadIdx.x;
    if (idx >= nwords) return;
    const int mf = (flags[0] == 0) ? 0 : (flags[1] == 0) ? 1 : 2;
    unsigned long long bits = 0ull;
    if (mf == 2) {
        const unsigned int* p = (const unsigned int*)mask + (size_t)idx * 16;
        #pragma unroll
        for (int i = 0; i < 16; ++i) {
            unsigned int w = p[i] & 0x01010101u;
            unsigned int nib = (w * 0x01020408u) >> 24;
            bits |= (unsigned long long)(nib & 0xFu) << (i * 4);
        }
    } else if (mf == 0) {
        const unsigned int* p = (const unsigned int*)mask + (size_t)idx * 64;
        #pragma unroll
        for (int i = 0; i < 64; ++i)
            bits |= (unsigned long long)(p[i] & 1u) << i;
    } else {
        const float* p = (const float*)mask + (size_t)idx * 64;
        #pragma unroll
        for (int i = 0; i < 64; ++i)
            bits |= (unsigned long long)(p[i] != 0.f) << i;
    }
    mbits[idx] = bits;
}

// ---------------------------------------------------------------------------
// fp32 -> bf16 convert for Q,K,V (blockIdx.y selects tensor). 8 elems/thread.
// ---------------------------------------------------------------------------
__global__ __launch_bounds__(256) void cvt_bf16(
    const float* __restrict__ s0, const float* __restrict__ s1,
    const float* __restrict__ s2,
    unsigned short* __restrict__ d0, unsigned short* __restrict__ d1,
    unsigned short* __restrict__ d2)
{
    const float* s = (blockIdx.y == 0) ? s0 : (blockIdx.y == 1) ? s1 : s2;
    unsigned short* d = (blockIdx.y == 0) ? d0 : (blockIdx.y == 1) ? d1 : d2;
    const int i = blockIdx.x * 256 + threadIdx.x;
    float4 a = ((const float4*)s)[i * 2];
    float4 b = ((const float4*)s)[i * 2 + 1];
    ushort4 u0, u1;
    u0.x = f2bf(a.x); u0.y = f2bf(a.y); u0.z = f2bf(a.z); u0.w = f2bf(a.w);
    u1.x = f2bf(b.x); u1.y = f2bf(b.y); u1.z = f2bf(b.z); u1.w = f2bf(b.w);
    ((ushort4*)d)[i * 2] = u0;
    ((ushort4*)d)[i * 2 + 1] = u1;
}

// ---------------------------------------------------------------------------
// Weight transpose-convert: W fp32 [K][N] -> Wt bf16 [N][K].
// ---------------------------------------------------------------------------
__global__ __launch_bounds__(256) void cvt_wT(
    const float* __restrict__ w0, const float* __restrict__ w1,
    const float* __restrict__ w2, const float* __restrict__ w3,
    unsigned short* __restrict__ t0, unsigned short* __restrict__ t1,
    unsigned short* __restrict__ t2, unsigned short* __restrict__ t3)
{
    __shared__ float tile[64][65];
    const float* W = (blockIdx.z == 0) ? w0 : (blockIdx.z == 1) ? w1
                   : (blockIdx.z == 2) ? w2 : w3;
    unsigned short* T = (blockIdx.z == 0) ? t0 : (blockIdx.z == 1) ? t1
                      : (blockIdx.z == 2) ? t2 : t3;
    const int k0 = blockIdx.y * 64;
    const int n0 = blockIdx.x * 64;
    const int t  = threadIdx.x;
    const int r  = t >> 4;
    const int c4 = (t & 15) * 4;
    #pragma unroll
    for (int u = 0; u < 4; ++u) {
        float4 v = *(const float4*)(W + (size_t)(k0 + r + u * 16) * D_MODEL + n0 + c4);
        tile[r + u * 16][c4 + 0] = v.x;
        tile[r + u * 16][c4 + 1] = v.y;
        tile[r + u * 16][c4 + 2] = v.z;
        tile[r + u * 16][c4 + 3] = v.w;
    }
    __syncthreads();
    #pragma unroll
    for (int u = 0; u < 4; ++u) {
        const int nr = r + u * 16;
        ushort4 o;
        o.x = f2bf(tile[c4 + 0][nr]);
        o.y = f2bf(tile[c4 + 1][nr]);
        o.z = f2bf(tile[c4 + 2][nr]);
        o.w = f2bf(tile[c4 + 3][nr]);
        *(ushort4*)(T + (size_t)(n0 + nr) * D_MODEL + k0 + c4) = o;
    }
}

// ---------------------------------------------------------------------------
// MFMA GEMM core: 128x128 tile, BK=64, 256 threads, dbuf LDS, gload_lds 16B.
// ---------------------------------------------------------------------------
#define BKK 64

// Merged Q/K/V projection GEMM. z=0: Q (scaled by SCLF, row-major bf16);
// z=1: K (row-major bf16); z=2: V (per-head transposed vt[b][h][d][tok]).
__global__ __launch_bounds__(256, 1) void gemm_qkv(
    const unsigned short* __restrict__ A0, const unsigned short* __restrict__ A1,
    const unsigned short* __restrict__ A2,
    const unsigned short* __restrict__ B0, const unsigned short* __restrict__ B1,
    const unsigned short* __restrict__ B2,
    const float* __restrict__ bias0, const float* __restrict__ bias1,
    const float* __restrict__ bias2,
    unsigned short* __restrict__ C0, unsigned short* __restrict__ C1,
    unsigned short* __restrict__ C2)
{
    const int z = blockIdx.z;
    const unsigned short* A  = (z == 0) ? A0 : (z == 1) ? A1 : A2;
    const unsigned short* Bt = (z == 0) ? B0 : (z == 1) ? B1 : B2;
    const float* bias        = (z == 0) ? bias0 : (z == 1) ? bias1 : bias2;
    unsigned short* C        = (z == 0) ? C0 : (z == 1) ? C1 : C2;
    const int K = D_MODEL, N = D_MODEL;

    __shared__ unsigned short As[2][128 * BKK];
    __shared__ unsigned short Bs[2][128 * BKK];
    const int tid  = threadIdx.x;
    const int w    = tid >> 6;
    const int lane = tid & 63;
    const int lo   = lane & 15;
    const int hi   = lane >> 4;
    const int wm   = (w >> 1) * 64;
    const int wn   = (w & 1) * 64;
    const int m0   = blockIdx.y * 128;
    const int n0   = blockIdx.x * 128;

    const unsigned short* Ab = A  + (size_t)m0 * K;
    const unsigned short* Bb = Bt + (size_t)n0 * K;

    f32x4 acc[4][4];
    #pragma unroll
    for (int i = 0; i < 4; ++i)
        #pragma unroll
        for (int j = 0; j < 4; ++j) acc[i][j] = (f32x4){0.f, 0.f, 0.f, 0.f};

    const int NT = K / BKK;
    auto stage = [&](int buf, int t) {
        const int k0 = t * BKK;
        #pragma unroll
        for (int i = 0; i < 4; ++i) {
            const int c = i * 256 + tid;
            gload16(Ab + (size_t)(c >> 3) * K + k0 + (c & 7) * 8,
                    &As[buf][(i * 256 + w * 64) * 8], lane);
        }
        #pragma unroll
        for (int i = 0; i < 4; ++i) {
            const int c = i * 256 + tid;
            gload16(Bb + (size_t)(c >> 3) * K + k0 + (c & 7) * 8,
                    &Bs[buf][(i * 256 + w * 64) * 8], lane);
        }
    };

    stage(0, 0);
    __syncthreads();
    int cur = 0;
    for (int t = 0; t < NT; ++t) {
        if (t + 1 < NT) stage(cur ^ 1, t + 1);
        bf16x8 af[4][2], bfr[4][2];
        #pragma unroll
        for (int f = 0; f < 4; ++f)
            #pragma unroll
            for (int s = 0; s < 2; ++s) {
                af[f][s]  = *(const bf16x8*)&As[cur][(wm + f * 16 + lo) * BKK + s * 32 + hi * 8];
                bfr[f][s] = *(const bf16x8*)&Bs[cur][(wn + f * 16 + lo) * BKK + s * 32 + hi * 8];
            }
        #pragma unroll
        for (int s = 0; s < 2; ++s)
            #pragma unroll
            for (int fm = 0; fm < 4; ++fm)
                #pragma unroll
                for (int fn = 0; fn < 4; ++fn)
                    acc[fm][fn] = __builtin_amdgcn_mfma_f32_16x16x32_bf16(
                        af[fm][s], bfr[fn][s], acc[fm][fn], 0, 0, 0);
        __syncthreads();
        cur ^= 1;
    }

    #pragma unroll
    for (int fm = 0; fm < 4; ++fm) {
        const int row = m0 + wm + fm * 16 + hi * 4;
        #pragma unroll
        for (int fn = 0; fn < 4; ++fn) {
            const int col = n0 + wn + fn * 16 + lo;
            const float bv = bias[col];
            #pragma unroll
            for (int r = 0; r < 4; ++r) {
                float o = acc[fm][fn][r] + bv;
                if (z == 0) o *= SCLF;            // fold softmax scale into Q
                if (z < 2)
                    C[(size_t)(row + r) * N + col] = f2bf(o);
                else
                    C[(size_t)((row + r) >> 11) * 2097152
                      + (size_t)col * 2048 + ((row + r) & 2047)] = f2bf(o);
            }
        }
    }
}

// Out-projection GEMM: fp32 out + residual add.
__global__ __launch_bounds__(256, 1) void gemm_out(
    const unsigned short* __restrict__ A, const unsigned short* __restrict__ Bt,
    const float* __restrict__ bias, const float* __restrict__ resid,
    float* __restrict__ C)
{
    const int K = D_MODEL, N = D_MODEL;
    __shared__ unsigned short As[2][128 * BKK];
    __shared__ unsigned short Bs[2][128 * BKK];
    const int tid  = threadIdx.x;
    const int w    = tid >> 6;
    const int lane = tid & 63;
    const int lo   = lane & 15;
    const int hi   = lane >> 4;
    const int wm   = (w >> 1) * 64;
    const int wn   = (w & 1) * 64;
    const int m0   = blockIdx.y * 128;
    const int n0   = blockIdx.x * 128;

    const unsigned short* Ab = A  + (size_t)m0 * K;
    const unsigned short* Bb = Bt + (size_t)n0 * K;

    f32x4 acc[4][4];
    #pragma unroll
    for (int i = 0; i < 4; ++i)
        #pragma unroll
        for (int j = 0; j < 4; ++j) acc[i][j] = (f32x4){0.f, 0.f, 0.f, 0.f};

    const int NT = K / BKK;
    auto stage = [&](int buf, int t) {
        const int k0 = t * BKK;
        #pragma unroll
        for (int i = 0; i < 4; ++i) {
            const int c = i * 256 + tid;
            gload16(Ab + (size_t)(c >> 3) * K + k0 + (c & 7) * 8,
                    &As[buf][(i * 256 + w * 64) * 8], lane);
        }
        #pragma unroll
        for (int i = 0; i < 4; ++i) {
            const int c = i * 256 + tid;
            gload16(Bb + (size_t)(c >> 3) * K + k0 + (c & 7) * 8,
                    &Bs[buf][(i * 256 + w * 64) * 8], lane);
        }
    };

    stage(0, 0);
    __syncthreads();
    int cur = 0;
    for (int t = 0; t < NT; ++t) {
        if (t + 1 < NT) stage(cur ^ 1, t + 1);
        bf16x8 af[4][2], bfr[4][2];
        #pragma unroll
        for (int f = 0; f < 4; ++f)
            #pragma unroll
            for (int s = 0; s < 2; ++s) {
                af[f][s]  = *(const bf16x8*)&As[cur][(wm + f * 16 + lo) * BKK + s * 32 + hi * 8];
                bfr[f][s] = *(const bf16x8*)&Bs[cur][(wn + f * 16 + lo) * BKK + s * 32 + hi * 8];
            }
        #pragma unroll
        for (int s = 0; s < 2; ++s)
            #pragma unroll
            for (int fm = 0; fm < 4; ++fm)
                #pragma unroll
                for (int fn = 0; fn < 4; ++fn)
                    acc[fm][fn] = __builtin_amdgcn_mfma_f32_16x16x32_bf16(
                        af[fm][s], bfr[fn][s], acc[fm][fn], 0, 0, 0);
        __syncthreads();
        cur ^= 1;
    }

    #pragma unroll
    for (int fm = 0; fm < 4; ++fm) {
        const int row = m0 + wm + fm * 16 + hi * 4;
        #pragma unroll
        for (int fn = 0; fn < 4; ++fn) {
            const int col = n0 + wn + fn * 16 + lo;
            const float bv = bias[col];
            #pragma unroll
            for (int r = 0; r < 4; ++r)
                C[(size_t)(row + r) * N + col] =
                    acc[fm][fn][r] + bv + resid[(size_t)(row + r) * N + col];
        }
    }
}

// ---------------------------------------------------------------------------
// Swapped-QK^T 32x32 MFMA flash attention with in-block K-split.
// Block = (b, h, 128 q-rows): 8 waves = 2 k-groups (g) x 4 q-waves (wq).
// Each group: independent online softmax over 16 k-tiles, own dbuf K/V LDS.
// End: flash-combine partials (m,l,O) through LDS (staging buffers reused).
// Q pre-scaled by SCLF in projection; exp2-domain softmax; defer-max (T13);
// P->A-frag via cvt_pk + permlane32_swap (T12); s_setprio on MFMA (T5).
// ---------------------------------------------------------------------------
__global__ __launch_bounds__(512, 4) void attn_mfma32(
    const unsigned short* __restrict__ qb, const unsigned short* __restrict__ kbm,
    const unsigned short* __restrict__ vt,
    const unsigned long long* __restrict__ mbits, unsigned short* __restrict__ ctx)
{
    __shared__ unsigned char smem[65536];   // [0,32K): K staging; [32K,64K): V staging
    const int tid  = threadIdx.x;
    const int w8   = tid >> 6;
    const int g    = w8 >> 2;        // k-group (0: tiles 0..15, 1: tiles 16..31)
    const int wq   = w8 & 3;         // q-wave within group
    const int lane = tid & 63;
    const int l31  = lane & 31;
    const int hi   = lane >> 5;
    const int q0   = blockIdx.x * 128;
    const int h    = blockIdx.y;
    const int b    = blockIdx.z;

    unsigned short* KsG = (unsigned short*)smem + (size_t)g * 8192;            // [buf][4096]
    unsigned short* VsG = (unsigned short*)(smem + 32768) + (size_t)g * 8192;  // [buf][4096]

    const size_t qkbase = (size_t)b * SEQ * D_MODEL + (size_t)h * DHEAD;
    const size_t vtbase = ((size_t)b * D_MODEL + h * DHEAD) * SEQ;

    const int qtok = q0 + wq * 32 + l31;
    bf16x8 qA[4];
    #pragma unroll
    for (int s = 0; s < 4; ++s)
        qA[s] = *(const bf16x8*)(qb + qkbase + (size_t)qtok * D_MODEL + s * 16 + hi * 8);

    f32x16 o0 = {}, o1 = {};
    float m_i = -INFINITY, l_i = 0.f;

    const unsigned long long* mrow = mbits + ((size_t)b * SEQ + qtok) * (SEQ / 64);

    const int srow = lane >> 3;
    const int sc   = lane & 7;

    auto stage = [&](int buf, int t) {
        const int kt = g * 16 + t;
        #pragma unroll
        for (int cc = 0; cc < 2; ++cc) {
            const int rb = wq * 16 + cc * 8;
            const int r  = rb + srow;
            const int swz = sc ^ (r & 7);
            gload16(kbm + qkbase + (size_t)(kt * 64 + r) * D_MODEL + swz * 8,
                    &KsG[buf * 4096 + rb * 64], lane);
            gload16(vt + vtbase + (size_t)r * SEQ + kt * 64 + swz * 8,
                    &VsG[buf * 4096 + rb * 64], lane);
        }
    };

    stage(0, 0);
    __syncthreads();
    int cur = 0;

    for (int t = 0; t < 16; ++t) {
        if (t + 1 < 16) stage(cur ^ 1, t + 1);
        const unsigned long long mw64 = mrow[g * 16 + t];
        const unsigned int ml = (unsigned int)(mw64 >> (4 * hi));
        const unsigned int mh = (unsigned int)(mw64 >> (32 + 4 * hi));

        // ---- QK^T (pre-scaled Q): S^T[key][q] ----
        f32x16 st0 = {}, st1 = {};
        __builtin_amdgcn_s_setprio(1);
        #pragma unroll
        for (int s = 0; s < 4; ++s) {
            bf16x8 kf0 = *(const bf16x8*)&KsG[cur * 4096 + l31 * 64 + ((2 * s + hi) ^ (l31 & 7)) * 8];
            st0 = __builtin_amdgcn_mfma_f32_32x32x16_bf16(kf0, qA[s], st0, 0, 0, 0);
            bf16x8 kf1 = *(const bf16x8*)&KsG[cur * 4096 + (32 + l31) * 64 + ((2 * s + hi) ^ (l31 & 7)) * 8];
            st1 = __builtin_amdgcn_mfma_f32_32x32x16_bf16(kf1, qA[s], st1, 0, 0, 0);
        }
        __builtin_amdgcn_s_setprio(0);

        // ---- mask + lane-local max ----
        float rmax = -3.0e38f;
        #pragma unroll
        for (int r = 0; r < 16; ++r) {
            const int klo = (r & 3) + 8 * (r >> 2);
            float x0 = st0[r], x1 = st1[r];
            if ((ml >> klo) & 1u) x0 = -1e9f;
            if ((mh >> klo) & 1u) x1 = -1e9f;
            st0[r] = x0; st1[r] = x1;
            rmax = fmaxf(rmax, fmaxf(x0, x1));
        }
        rmax = fmaxf(rmax, __shfl_xor(rmax, 32, 64));

        // ---- defer-max (T13) ----
        const bool defer = (bool)__all(rmax - m_i <= 8.0f);
        float alpha = 1.f;
        if (!defer) {
            const float mn = fmaxf(m_i, rmax);
            alpha = exp2f(m_i - mn);
            m_i = mn;
        }
        float ls = 0.f;
        #pragma unroll
        for (int r = 0; r < 16; ++r) {
            float e0 = exp2f(st0[r] - m_i);
            float e1 = exp2f(st1[r] - m_i);
            st0[r] = e0; st1[r] = e1;
            ls += e0 + e1;
        }
        ls += __shfl_xor(ls, 32, 64);
        if (!defer) {
            l_i = l_i * alpha + ls;
            #pragma unroll
            for (int r = 0; r < 16; ++r) {
                const float aq = __shfl(alpha, (r & 3) + 8 * (r >> 2) + 4 * hi, 64);
                o0[r] *= aq; o1[r] *= aq;
            }
        } else {
            l_i += ls;
        }

        // ---- P -> bf16 A-frags (T12) ----
        bf16x8 pa[4];
        #pragma unroll
        for (int s = 0; s < 4; ++s) {
            const int base = (s & 1) * 8;
            unsigned av, bv2, cv, dv;
            if (s < 2) {
                av  = cvtpk_bf16(st0[base + 0], st0[base + 1]);
                bv2 = cvtpk_bf16(st0[base + 4], st0[base + 5]);
                cv  = cvtpk_bf16(st0[base + 2], st0[base + 3]);
                dv  = cvtpk_bf16(st0[base + 6], st0[base + 7]);
            } else {
                av  = cvtpk_bf16(st1[base + 0], st1[base + 1]);
                bv2 = cvtpk_bf16(st1[base + 4], st1[base + 5]);
                cv  = cvtpk_bf16(st1[base + 2], st1[base + 3]);
                dv  = cvtpk_bf16(st1[base + 6], st1[base + 7]);
            }
            asm("v_permlane32_swap_b32 %0, %1" : "+v"(av), "+v"(bv2));
            asm("v_permlane32_swap_b32 %0, %1" : "+v"(cv), "+v"(dv));
            int4 pk = make_int4((int)av, (int)cv, (int)bv2, (int)dv);
            pa[s] = __builtin_bit_cast(bf16x8, pk);
        }

        // ---- PV ----
        __builtin_amdgcn_s_setprio(1);
        #pragma unroll
        for (int s = 0; s < 4; ++s) {
            bf16x8 vf0 = *(const bf16x8*)&VsG[cur * 4096 + l31 * 64 + ((2 * s + hi) ^ (l31 & 7)) * 8];
            o0 = __builtin_amdgcn_mfma_f32_32x32x16_bf16(pa[s], vf0, o0, 0, 0, 0);
            bf16x8 vf1 = *(const bf16x8*)&VsG[cur * 4096 + (32 + l31) * 64 + ((2 * s + hi) ^ (l31 & 7)) * 8];
            o1 = __builtin_amdgcn_mfma_f32_32x32x16_bf16(pa[s], vf1, o1, 0, 0, 0);
        }
        __builtin_amdgcn_s_setprio(0);
        __syncthreads();
        cur ^= 1;
    }

    // ---- flash-combine of the two k-group partials (reuse staging LDS) ----
    __syncthreads();
    float* comb = (float*)smem;          // [wq][lane][35] floats, stride 35 (odd)
    if (g == 1) {
        float* p = comb + (size_t)(wq * 64 + lane) * 35;
        #pragma unroll
        for (int r = 0; r < 16; ++r) { p[r] = o0[r]; p[16 + r] = o1[r]; }
        p[32] = m_i; p[33] = l_i;
    }
    __syncthreads();
    if (g == 0) {
        const float* p = comb + (size_t)(wq * 64 + lane) * 35;
        const float mb = p[32], lb = p[33];
        const float ms = fmaxf(m_i, mb);
        const float sa = exp2f(m_i - ms);
        const float sb = exp2f(mb - ms);
        const float inv = 1.f / (l_i * sa + lb * sb);
        #pragma unroll
        for (int r = 0; r < 16; ++r) {
            const int qloc = (r & 3) + 8 * (r >> 2) + 4 * hi;
            const float sar = __shfl(sa, qloc, 64);
            const float sbr = __shfl(sb, qloc, 64);
            const float ivr = __shfl(inv, qloc, 64);
            unsigned short* dst = ctx + qkbase + (size_t)(q0 + wq * 32 + qloc) * D_MODEL;
            dst[l31]      = f2bf((o0[r] * sar + p[r] * sbr) * ivr);
            dst[32 + l31] = f2bf((o1[r] * sar + p[16 + r] * sbr) * ivr);
        }
    }
}

// ---------------------------------------------------------------------------
// LayerNorm over last dim (1024). One block per row.
// ---------------------------------------------------------------------------
__global__ __launch_bounds__(256) void layernorm1024(
    const float* __restrict__ x, const float* __restrict__ gamma,
    const float* __restrict__ beta, float* __restrict__ out)
{
    const int row = blockIdx.x;
    const int tid = threadIdx.x;
    const float* xr = x + (size_t)row * D_MODEL;
    float4 v = *(const float4*)(xr + (tid << 2));
    float s = v.x + v.y + v.z + v.w;
    float q = v.x * v.x + v.y * v.y + v.z * v.z + v.w * v.w;
    #pragma unroll
    for (int off = 1; off < 64; off <<= 1) {
        s += __shfl_xor(s, off, 64);
        q += __shfl_xor(q, off, 64);
    }
    __shared__ float sw[4], qw_[4];
    const int wid = tid >> 6;
    if ((tid & 63) == 0) { sw[wid] = s; qw_[wid] = q; }
    __syncthreads();
    s = sw[0] + sw[1] + sw[2] + sw[3];
    q = qw_[0] + qw_[1] + qw_[2] + qw_[3];
    const float mu  = s * (1.f / D_MODEL);
    const float var = q * (1.f / D_MODEL) - mu * mu;
    const float a = var + 1e-5f;
    float inv = rsqrtf(a);
    inv = inv * (1.5f - 0.5f * a * inv * inv);
    float4 gg = *(const float4*)(gamma + (tid << 2));
    float4 bt = *(const float4*)(beta + (tid << 2));
    float4 o;
    o.x = (v.x - mu) * inv * gg.x + bt.x;
    o.y = (v.y - mu) * inv * gg.y + bt.y;
    o.z = (v.z - mu) * inv * gg.z + bt.z;
    o.w = (v.w - mu) * inv * gg.w + bt.w;
    *(float4*)(out + (size_t)row * D_MODEL + (tid << 2)) = o;
}

// ---------------------------------------------------------------------------
extern "C" void kernel_launch(void* const* d_in, const int* in_sizes, int n_in,
                              void* d_out, int out_size, void* d_ws, size_t ws_size,
                              hipStream_t stream)
{
    const float* Q    = (const float*)d_in[0];
    const float* K    = (const float*)d_in[1];
    const float* V    = (const float*)d_in[2];
    const void*  mask = d_in[3];
    const float* Wq   = (const float*)d_in[4];
    const float* bq   = (const float*)d_in[5];
    const float* Wk   = (const float*)d_in[6];
    const float* bk   = (const float*)d_in[7];
    const float* Wv   = (const float*)d_in[8];
    const float* bv   = (const float*)d_in[9];
    const float* Wo   = (const float*)d_in[10];
    const float* bo   = (const float*)d_in[11];
    const float* gam  = (const float*)d_in[12];
    const float* bet  = (const float*)d_in[13];
    float* out = (float*)d_out;

    const size_t NE = (size_t)MROWS * D_MODEL;           // 4,194,304 elems
    const size_t WE = (size_t)D_MODEL * D_MODEL;
    unsigned short* Qbf = (unsigned short*)d_ws;         // reused as ctxb
    unsigned short* Kbf = Qbf + NE;                      // reused as outp
    unsigned short* Vbf = Kbf + NE;
    unsigned short* qb  = Vbf + NE;
    unsigned short* kb  = qb + NE;
    unsigned short* vt  = kb + NE;                       // [b][h][d][tok]
    unsigned short* Wt0 = vt + NE;
    unsigned short* Wt1 = Wt0 + WE;
    unsigned short* Wt2 = Wt1 + WE;
    unsigned short* Wt3 = Wt2 + WE;
    unsigned long long* mbits = (unsigned long long*)(Wt3 + WE);
    const size_t NMW = (size_t)BATCH * SEQ * (SEQ / 64);
    int* mflags = (int*)(mbits + NMW);
    unsigned short* ctxb = Qbf;
    float* outp = (float*)Kbf;
    if (ws_size < 6 * NE * 2 + 4 * WE * 2 + NMW * 8 + 64) return;

    hipMemsetAsync(mflags, 0, 2 * sizeof(int), stream);
    detect_mask_par<<<256, 256, 0, stream>>>((const unsigned int*)mask, 65536, mflags);
    pack_mask<<<(int)((NMW + 255) / 256), 256, 0, stream>>>(mask, mflags, mbits, (int)NMW);

    cvt_bf16<<<dim3(NE / 8 / 256, 3), 256, 0, stream>>>(Q, K, V, Qbf, Kbf, Vbf);
    cvt_wT<<<dim3(16, 16, 4), 256, 0, stream>>>(Wq, Wk, Wv, Wo, Wt0, Wt1, Wt2, Wt3);

    gemm_qkv<<<dim3(8, 32, 3), 256, 0, stream>>>(Qbf, Kbf, Vbf, Wt0, Wt1, Wt2,
                                                 bq, bk, bv, qb, kb, vt);

    dim3 ag(SEQ / 128, NHEADS, BATCH);     // (16, 16, 2), 512 threads
    attn_mfma32<<<ag, 512, 0, stream>>>(qb, kb, vt, mbits, ctxb);

    gemm_out<<<dim3(8, 32), 256, 0, stream>>>(ctxb, Wt3, bo, Q, outp);

    layernorm1024<<<MROWS, 256, 0, stream>>>(outp, gam, bet, out);
}

// Round 7
// 242.107 us; speedup vs baseline: 8.5013x; 1.0264x over previous
//
#include <hip/hip_runtime.h>
#include <hip/hip_bf16.h>
#include <math.h>

// Fused MHA block: proj(Q,K,V) -> masked softmax attention -> out proj + residual -> LayerNorm
// Round 7: fix round-6 regression source — __launch_bounds__(512,4) squeezed attn to
// 64 VGPRs (spilled f32x16 accumulators to scratch). Now (512,2). Plus: tree-form
// max/sum reductions (break 32-deep dependent chains), mask-word prefetch, and
// ballot-based coalesced pack_mask. GEMM cores unchanged.

#define D_MODEL 1024
#define NHEADS  16
#define DHEAD   64
#define BATCH   2
#define SEQ     2048
#define MROWS   (BATCH * SEQ)   // 4096
#define SCLF    0.18033688f     // 0.125 * log2(e), folded into Q projection

typedef __attribute__((ext_vector_type(8)))  short bf16x8;
typedef __attribute__((ext_vector_type(4)))  float f32x4;
typedef __attribute__((ext_vector_type(16))) float f32x16;

__device__ inline unsigned short f2bf(float f) {
    unsigned int u = __builtin_bit_cast(unsigned int, f);
    unsigned int r = (u + 0x7FFFu + ((u >> 16) & 1u)) >> 16;   // RNE
    return (unsigned short)r;
}

__device__ inline unsigned cvtpk_bf16(float lo, float hi2) {
    unsigned r;
    asm("v_cvt_pk_bf16_f32 %0, %1, %2" : "=v"(r) : "v"(lo), "v"(hi2));
    return r;
}

// global -> LDS direct copy, 16B per lane. lbase must be wave-uniform.
__device__ inline void gload16(const unsigned short* g, unsigned short* lbase, int lane) {
#if __has_builtin(__builtin_amdgcn_global_load_lds)
    __builtin_amdgcn_global_load_lds(
        (const __attribute__((address_space(1))) unsigned int*)g,
        (__attribute__((address_space(3))) unsigned int*)lbase, 16, 0, 0);
#else
    *(bf16x8*)(lbase + lane * 8) = *(const bf16x8*)g;
#endif
}

// ---------------------------------------------------------------------------
// Parallel mask dtype probe. flags[0]: any word not in {0,1};
// flags[1]: any word not in {0, 0x3F800000}. flags pre-zeroed via memset.
// ---------------------------------------------------------------------------
__global__ __launch_bounds__(256) void detect_mask_par(
    const unsigned int* __restrict__ m, int nwords, int* __restrict__ flags)
{
    const int i = blockIdx.x * 256 + threadIdx.x;
    int a = 0, b = 0;
    if (i < nwords) {
        const unsigned int w = m[i];
        a = (w != 0u && w != 1u);
        b = (w != 0u && w != 0x3F800000u);
    }
    const int wa = (int)__any(a);
    const int wb = (int)__any(b);
    if ((threadIdx.x & 63) == 0) {
        if (wa) atomicOr(&flags[0], 1);
        if (wb) atomicOr(&flags[1], 1);
    }
}

// ---------------------------------------------------------------------------
// Ballot pack: one 64-key mask word per wave iteration. Lane i reads element i
// (coalesced); __ballot(v!=0) IS the packed word (bit i = key i).
// ---------------------------------------------------------------------------
__global__ __launch_bounds__(256) void pack_mask_ballot(
    const void* __restrict__ mask, const int* __restrict__ flags,
    unsigned long long* __restrict__ mbits, int nwords)
{
    const int lane   = threadIdx.x & 63;
    const int wv     = blockIdx.x * 4 + (threadIdx.x >> 6);
    const int nwaves = gridDim.x * 4;
    const int mf = (flags[0] == 0) ? 0 : (flags[1] == 0) ? 1 : 2;
    for (int w = wv; w < nwords; w += nwaves) {
        bool bit;
        if (mf == 0)      bit = ((const unsigned int*)mask)[(size_t)w * 64 + lane] != 0u;
        else if (mf == 1) bit = ((const float*)mask)[(size_t)w * 64 + lane] != 0.f;
        else              bit = ((const unsigned char*)mask)[(size_t)w * 64 + lane] != 0;
        const unsigned long long b = __ballot(bit);
        if (lane == 0) mbits[w] = b;
    }
}

// ---------------------------------------------------------------------------
// fp32 -> bf16 convert for Q,K,V (blockIdx.y selects tensor). 8 elems/thread.
// ---------------------------------------------------------------------------
__global__ __launch_bounds__(256) void cvt_bf16(
    const float* __restrict__ s0, const float* __restrict__ s1,
    const float* __restrict__ s2,
    unsigned short* __restrict__ d0, unsigned short* __restrict__ d1,
    unsigned short* __restrict__ d2)
{
    const float* s = (blockIdx.y == 0) ? s0 : (blockIdx.y == 1) ? s1 : s2;
    unsigned short* d = (blockIdx.y == 0) ? d0 : (blockIdx.y == 1) ? d1 : d2;
    const int i = blockIdx.x * 256 + threadIdx.x;
    float4 a = ((const float4*)s)[i * 2];
    float4 b = ((const float4*)s)[i * 2 + 1];
    ushort4 u0, u1;
    u0.x = f2bf(a.x); u0.y = f2bf(a.y); u0.z = f2bf(a.z); u0.w = f2bf(a.w);
    u1.x = f2bf(b.x); u1.y = f2bf(b.y); u1.z = f2bf(b.z); u1.w = f2bf(b.w);
    ((ushort4*)d)[i * 2] = u0;
    ((ushort4*)d)[i * 2 + 1] = u1;
}

// ---------------------------------------------------------------------------
// Weight transpose-convert: W fp32 [K][N] -> Wt bf16 [N][K].
// ---------------------------------------------------------------------------
__global__ __launch_bounds__(256) void cvt_wT(
    const float* __restrict__ w0, const float* __restrict__ w1,
    const float* __restrict__ w2, const float* __restrict__ w3,
    unsigned short* __restrict__ t0, unsigned short* __restrict__ t1,
    unsigned short* __restrict__ t2, unsigned short* __restrict__ t3)
{
    __shared__ float tile[64][65];
    const float* W = (blockIdx.z == 0) ? w0 : (blockIdx.z == 1) ? w1
                   : (blockIdx.z == 2) ? w2 : w3;
    unsigned short* T = (blockIdx.z == 0) ? t0 : (blockIdx.z == 1) ? t1
                      : (blockIdx.z == 2) ? t2 : t3;
    const int k0 = blockIdx.y * 64;
    const int n0 = blockIdx.x * 64;
    const int t  = threadIdx.x;
    const int r  = t >> 4;
    const int c4 = (t & 15) * 4;
    #pragma unroll
    for (int u = 0; u < 4; ++u) {
        float4 v = *(const float4*)(W + (size_t)(k0 + r + u * 16) * D_MODEL + n0 + c4);
        tile[r + u * 16][c4 + 0] = v.x;
        tile[r + u * 16][c4 + 1] = v.y;
        tile[r + u * 16][c4 + 2] = v.z;
        tile[r + u * 16][c4 + 3] = v.w;
    }
    __syncthreads();
    #pragma unroll
    for (int u = 0; u < 4; ++u) {
        const int nr = r + u * 16;
        ushort4 o;
        o.x = f2bf(tile[c4 + 0][nr]);
        o.y = f2bf(tile[c4 + 1][nr]);
        o.z = f2bf(tile[c4 + 2][nr]);
        o.w = f2bf(tile[c4 + 3][nr]);
        *(ushort4*)(T + (size_t)(n0 + nr) * D_MODEL + k0 + c4) = o;
    }
}

// ---------------------------------------------------------------------------
// MFMA GEMM core: 128x128 tile, BK=64, 256 threads, dbuf LDS, gload_lds 16B.
// ---------------------------------------------------------------------------
#define BKK 64

// Merged Q/K/V projection GEMM. z=0: Q (scaled by SCLF, row-major bf16);
// z=1: K (row-major bf16); z=2: V (per-head transposed vt[b][h][d][tok]).
__global__ __launch_bounds__(256, 1) void gemm_qkv(
    const unsigned short* __restrict__ A0, const unsigned short* __restrict__ A1,
    const unsigned short* __restrict__ A2,
    const unsigned short* __restrict__ B0, const unsigned short* __restrict__ B1,
    const unsigned short* __restrict__ B2,
    const float* __restrict__ bias0, const float* __restrict__ bias1,
    const float* __restrict__ bias2,
    unsigned short* __restrict__ C0, unsigned short* __restrict__ C1,
    unsigned short* __restrict__ C2)
{
    const int z = blockIdx.z;
    const unsigned short* A  = (z == 0) ? A0 : (z == 1) ? A1 : A2;
    const unsigned short* Bt = (z == 0) ? B0 : (z == 1) ? B1 : B2;
    const float* bias        = (z == 0) ? bias0 : (z == 1) ? bias1 : bias2;
    unsigned short* C        = (z == 0) ? C0 : (z == 1) ? C1 : C2;
    const int K = D_MODEL, N = D_MODEL;

    __shared__ unsigned short As[2][128 * BKK];
    __shared__ unsigned short Bs[2][128 * BKK];
    const int tid  = threadIdx.x;
    const int w    = tid >> 6;
    const int lane = tid & 63;
    const int lo   = lane & 15;
    const int hi   = lane >> 4;
    const int wm   = (w >> 1) * 64;
    const int wn   = (w & 1) * 64;
    const int m0   = blockIdx.y * 128;
    const int n0   = blockIdx.x * 128;

    const unsigned short* Ab = A  + (size_t)m0 * K;
    const unsigned short* Bb = Bt + (size_t)n0 * K;

    f32x4 acc[4][4];
    #pragma unroll
    for (int i = 0; i < 4; ++i)
        #pragma unroll
        for (int j = 0; j < 4; ++j) acc[i][j] = (f32x4){0.f, 0.f, 0.f, 0.f};

    const int NT = K / BKK;
    auto stage = [&](int buf, int t) {
        const int k0 = t * BKK;
        #pragma unroll
        for (int i = 0; i < 4; ++i) {
            const int c = i * 256 + tid;
            gload16(Ab + (size_t)(c >> 3) * K + k0 + (c & 7) * 8,
                    &As[buf][(i * 256 + w * 64) * 8], lane);
        }
        #pragma unroll
        for (int i = 0; i < 4; ++i) {
            const int c = i * 256 + tid;
            gload16(Bb + (size_t)(c >> 3) * K + k0 + (c & 7) * 8,
                    &Bs[buf][(i * 256 + w * 64) * 8], lane);
        }
    };

    stage(0, 0);
    __syncthreads();
    int cur = 0;
    for (int t = 0; t < NT; ++t) {
        if (t + 1 < NT) stage(cur ^ 1, t + 1);
        bf16x8 af[4][2], bfr[4][2];
        #pragma unroll
        for (int f = 0; f < 4; ++f)
            #pragma unroll
            for (int s = 0; s < 2; ++s) {
                af[f][s]  = *(const bf16x8*)&As[cur][(wm + f * 16 + lo) * BKK + s * 32 + hi * 8];
                bfr[f][s] = *(const bf16x8*)&Bs[cur][(wn + f * 16 + lo) * BKK + s * 32 + hi * 8];
            }
        #pragma unroll
        for (int s = 0; s < 2; ++s)
            #pragma unroll
            for (int fm = 0; fm < 4; ++fm)
                #pragma unroll
                for (int fn = 0; fn < 4; ++fn)
                    acc[fm][fn] = __builtin_amdgcn_mfma_f32_16x16x32_bf16(
                        af[fm][s], bfr[fn][s], acc[fm][fn], 0, 0, 0);
        __syncthreads();
        cur ^= 1;
    }

    #pragma unroll
    for (int fm = 0; fm < 4; ++fm) {
        const int row = m0 + wm + fm * 16 + hi * 4;
        #pragma unroll
        for (int fn = 0; fn < 4; ++fn) {
            const int col = n0 + wn + fn * 16 + lo;
            const float bv = bias[col];
            #pragma unroll
            for (int r = 0; r < 4; ++r) {
                float o = acc[fm][fn][r] + bv;
                if (z == 0) o *= SCLF;            // fold softmax scale into Q
                if (z < 2)
                    C[(size_t)(row + r) * N + col] = f2bf(o);
                else
                    C[(size_t)((row + r) >> 11) * 2097152
                      + (size_t)col * 2048 + ((row + r) & 2047)] = f2bf(o);
            }
        }
    }
}

// Out-projection GEMM: fp32 out + residual add.
__global__ __launch_bounds__(256, 1) void gemm_out(
    const unsigned short* __restrict__ A, const unsigned short* __restrict__ Bt,
    const float* __restrict__ bias, const float* __restrict__ resid,
    float* __restrict__ C)
{
    const int K = D_MODEL, N = D_MODEL;
    __shared__ unsigned short As[2][128 * BKK];
    __shared__ unsigned short Bs[2][128 * BKK];
    const int tid  = threadIdx.x;
    const int w    = tid >> 6;
    const int lane = tid & 63;
    const int lo   = lane & 15;
    const int hi   = lane >> 4;
    const int wm   = (w >> 1) * 64;
    const int wn   = (w & 1) * 64;
    const int m0   = blockIdx.y * 128;
    const int n0   = blockIdx.x * 128;

    const unsigned short* Ab = A  + (size_t)m0 * K;
    const unsigned short* Bb = Bt + (size_t)n0 * K;

    f32x4 acc[4][4];
    #pragma unroll
    for (int i = 0; i < 4; ++i)
        #pragma unroll
        for (int j = 0; j < 4; ++j) acc[i][j] = (f32x4){0.f, 0.f, 0.f, 0.f};

    const int NT = K / BKK;
    auto stage = [&](int buf, int t) {
        const int k0 = t * BKK;
        #pragma unroll
        for (int i = 0; i < 4; ++i) {
            const int c = i * 256 + tid;
            gload16(Ab + (size_t)(c >> 3) * K + k0 + (c & 7) * 8,
                    &As[buf][(i * 256 + w * 64) * 8], lane);
        }
        #pragma unroll
        for (int i = 0; i < 4; ++i) {
            const int c = i * 256 + tid;
            gload16(Bb + (size_t)(c >> 3) * K + k0 + (c & 7) * 8,
                    &Bs[buf][(i * 256 + w * 64) * 8], lane);
        }
    };

    stage(0, 0);
    __syncthreads();
    int cur = 0;
    for (int t = 0; t < NT; ++t) {
        if (t + 1 < NT) stage(cur ^ 1, t + 1);
        bf16x8 af[4][2], bfr[4][2];
        #pragma unroll
        for (int f = 0; f < 4; ++f)
            #pragma unroll
            for (int s = 0; s < 2; ++s) {
                af[f][s]  = *(const bf16x8*)&As[cur][(wm + f * 16 + lo) * BKK + s * 32 + hi * 8];
                bfr[f][s] = *(const bf16x8*)&Bs[cur][(wn + f * 16 + lo) * BKK + s * 32 + hi * 8];
            }
        #pragma unroll
        for (int s = 0; s < 2; ++s)
            #pragma unroll
            for (int fm = 0; fm < 4; ++fm)
                #pragma unroll
                for (int fn = 0; fn < 4; ++fn)
                    acc[fm][fn] = __builtin_amdgcn_mfma_f32_16x16x32_bf16(
                        af[fm][s], bfr[fn][s], acc[fm][fn], 0, 0, 0);
        __syncthreads();
        cur ^= 1;
    }

    #pragma unroll
    for (int fm = 0; fm < 4; ++fm) {
        const int row = m0 + wm + fm * 16 + hi * 4;
        #pragma unroll
        for (int fn = 0; fn < 4; ++fn) {
            const int col = n0 + wn + fn * 16 + lo;
            const float bv = bias[col];
            #pragma unroll
            for (int r = 0; r < 4; ++r)
                C[(size_t)(row + r) * N + col] =
                    acc[fm][fn][r] + bv + resid[(size_t)(row + r) * N + col];
        }
    }
}

// ---------------------------------------------------------------------------
// Swapped-QK^T 32x32 MFMA flash attention with in-block K-split.
// Block = (b, h, 128 q-rows): 8 waves = 2 k-groups (g) x 4 q-waves (wq).
// (512,2): allow ~full VGPR budget — round 6's (512,4) forced 64 VGPRs and
// spilled the f32x16 accumulators. Occupancy is LDS-limited (2 blocks/CU).
// ---------------------------------------------------------------------------
__global__ __launch_bounds__(512, 2) void attn_mfma32(
    const unsigned short* __restrict__ qb, const unsigned short* __restrict__ kbm,
    const unsigned short* __restrict__ vt,
    const unsigned long long* __restrict__ mbits, unsigned short* __restrict__ ctx)
{
    __shared__ unsigned char smem[65536];   // [0,32K): K staging; [32K,64K): V staging
    const int tid  = threadIdx.x;
    const int w8   = tid >> 6;
    const int g    = w8 >> 2;        // k-group (0: tiles 0..15, 1: tiles 16..31)
    const int wq   = w8 & 3;         // q-wave within group
    const int lane = tid & 63;
    const int l31  = lane & 31;
    const int hi   = lane >> 5;
    const int q0   = blockIdx.x * 128;
    const int h    = blockIdx.y;
    const int b    = blockIdx.z;

    unsigned short* KsG = (unsigned short*)smem + (size_t)g * 8192;            // [buf][4096]
    unsigned short* VsG = (unsigned short*)(smem + 32768) + (size_t)g * 8192;  // [buf][4096]

    const size_t qkbase = (size_t)b * SEQ * D_MODEL + (size_t)h * DHEAD;
    const size_t vtbase = ((size_t)b * D_MODEL + h * DHEAD) * SEQ;

    const int qtok = q0 + wq * 32 + l31;
    bf16x8 qA[4];
    #pragma unroll
    for (int s = 0; s < 4; ++s)
        qA[s] = *(const bf16x8*)(qb + qkbase + (size_t)qtok * D_MODEL + s * 16 + hi * 8);

    f32x16 o0 = {}, o1 = {};
    float m_i = -INFINITY, l_i = 0.f;

    const unsigned long long* mrow = mbits + ((size_t)b * SEQ + qtok) * (SEQ / 64);

    const int srow = lane >> 3;
    const int sc   = lane & 7;

    auto stage = [&](int buf, int t) {
        const int kt = g * 16 + t;
        #pragma unroll
        for (int cc = 0; cc < 2; ++cc) {
            const int rb = wq * 16 + cc * 8;
            const int r  = rb + srow;
            const int swz = sc ^ (r & 7);
            gload16(kbm + qkbase + (size_t)(kt * 64 + r) * D_MODEL + swz * 8,
                    &KsG[buf * 4096 + rb * 64], lane);
            gload16(vt + vtbase + (size_t)r * SEQ + kt * 64 + swz * 8,
                    &VsG[buf * 4096 + rb * 64], lane);
        }
    };

    stage(0, 0);
    unsigned long long mw64 = mrow[g * 16];     // prefetch tile 0's mask word
    __syncthreads();
    int cur = 0;

    for (int t = 0; t < 16; ++t) {
        if (t + 1 < 16) stage(cur ^ 1, t + 1);
        const unsigned long long mwc = mw64;
        if (t + 1 < 16) mw64 = mrow[g * 16 + t + 1];   // prefetch next (L2 latency off path)
        const unsigned int ml = (unsigned int)(mwc >> (4 * hi));
        const unsigned int mh = (unsigned int)(mwc >> (32 + 4 * hi));

        // ---- QK^T (pre-scaled Q): S^T[key][q] ----
        f32x16 st0 = {}, st1 = {};
        __builtin_amdgcn_s_setprio(1);
        #pragma unroll
        for (int s = 0; s < 4; ++s) {
            bf16x8 kf0 = *(const bf16x8*)&KsG[cur * 4096 + l31 * 64 + ((2 * s + hi) ^ (l31 & 7)) * 8];
            st0 = __builtin_amdgcn_mfma_f32_32x32x16_bf16(kf0, qA[s], st0, 0, 0, 0);
            bf16x8 kf1 = *(const bf16x8*)&KsG[cur * 4096 + (32 + l31) * 64 + ((2 * s + hi) ^ (l31 & 7)) * 8];
            st1 = __builtin_amdgcn_mfma_f32_32x32x16_bf16(kf1, qA[s], st1, 0, 0, 0);
        }
        __builtin_amdgcn_s_setprio(0);

        // ---- mask + lane-local max (4-partial tree, not a 32-deep chain) ----
        float rx[4] = {-3.0e38f, -3.0e38f, -3.0e38f, -3.0e38f};
        #pragma unroll
        for (int r = 0; r < 16; ++r) {
            const int klo = (r & 3) + 8 * (r >> 2);
            float x0 = st0[r], x1 = st1[r];
            if ((ml >> klo) & 1u) x0 = -1e9f;
            if ((mh >> klo) & 1u) x1 = -1e9f;
            st0[r] = x0; st1[r] = x1;
            rx[r & 3] = fmaxf(rx[r & 3], fmaxf(x0, x1));
        }
        float rmax = fmaxf(fmaxf(rx[0], rx[1]), fmaxf(rx[2], rx[3]));
        rmax = fmaxf(rmax, __shfl_xor(rmax, 32, 64));

        // ---- defer-max (T13) ----
        const bool defer = (bool)__all(rmax - m_i <= 8.0f);
        float alpha = 1.f;
        if (!defer) {
            const float mn = fmaxf(m_i, rmax);
            alpha = exp2f(m_i - mn);
            m_i = mn;
        }
        float sp[4] = {0.f, 0.f, 0.f, 0.f};
        #pragma unroll
        for (int r = 0; r < 16; ++r) {
            float e0 = exp2f(st0[r] - m_i);
            float e1 = exp2f(st1[r] - m_i);
            st0[r] = e0; st1[r] = e1;
            sp[r & 3] += e0 + e1;
        }
        float ls = (sp[0] + sp[1]) + (sp[2] + sp[3]);
        ls += __shfl_xor(ls, 32, 64);
        if (!defer) {
            l_i = l_i * alpha + ls;
            #pragma unroll
            for (int r = 0; r < 16; ++r) {
                const float aq = __shfl(alpha, (r & 3) + 8 * (r >> 2) + 4 * hi, 64);
                o0[r] *= aq; o1[r] *= aq;
            }
        } else {
            l_i += ls;
        }

        // ---- P -> bf16 A-frags (T12) ----
        bf16x8 pa[4];
        #pragma unroll
        for (int s = 0; s < 4; ++s) {
            const int base = (s & 1) * 8;
            unsigned av, bv2, cv, dv;
            if (s < 2) {
                av  = cvtpk_bf16(st0[base + 0], st0[base + 1]);
                bv2 = cvtpk_bf16(st0[base + 4], st0[base + 5]);
                cv  = cvtpk_bf16(st0[base + 2], st0[base + 3]);
                dv  = cvtpk_bf16(st0[base + 6], st0[base + 7]);
            } else {
                av  = cvtpk_bf16(st1[base + 0], st1[base + 1]);
                bv2 = cvtpk_bf16(st1[base + 4], st1[base + 5]);
                cv  = cvtpk_bf16(st1[base + 2], st1[base + 3]);
                dv  = cvtpk_bf16(st1[base + 6], st1[base + 7]);
            }
            asm("v_permlane32_swap_b32 %0, %1" : "+v"(av), "+v"(bv2));
            asm("v_permlane32_swap_b32 %0, %1" : "+v"(cv), "+v"(dv));
            int4 pk = make_int4((int)av, (int)cv, (int)bv2, (int)dv);
            pa[s] = __builtin_bit_cast(bf16x8, pk);
        }

        // ---- PV ----
        __builtin_amdgcn_s_setprio(1);
        #pragma unroll
        for (int s = 0; s < 4; ++s) {
            bf16x8 vf0 = *(const bf16x8*)&VsG[cur * 4096 + l31 * 64 + ((2 * s + hi) ^ (l31 & 7)) * 8];
            o0 = __builtin_amdgcn_mfma_f32_32x32x16_bf16(pa[s], vf0, o0, 0, 0, 0);
            bf16x8 vf1 = *(const bf16x8*)&VsG[cur * 4096 + (32 + l31) * 64 + ((2 * s + hi) ^ (l31 & 7)) * 8];
            o1 = __builtin_amdgcn_mfma_f32_32x32x16_bf16(pa[s], vf1, o1, 0, 0, 0);
        }
        __builtin_amdgcn_s_setprio(0);
        __syncthreads();
        cur ^= 1;
    }

    // ---- flash-combine of the two k-group partials (reuse staging LDS) ----
    __syncthreads();
    float* comb = (float*)smem;          // [wq][lane][35] floats, stride 35 (odd)
    if (g == 1) {
        float* p = comb + (size_t)(wq * 64 + lane) * 35;
        #pragma unroll
        for (int r = 0; r < 16; ++r) { p[r] = o0[r]; p[16 + r] = o1[r]; }
        p[32] = m_i; p[33] = l_i;
    }
    __syncthreads();
    if (g == 0) {
        const float* p = comb + (size_t)(wq * 64 + lane) * 35;
        const float mb = p[32], lb = p[33];
        const float ms = fmaxf(m_i, mb);
        const float sa = exp2f(m_i - ms);
        const float sb = exp2f(mb - ms);
        const float inv = 1.f / (l_i * sa + lb * sb);
        #pragma unroll
        for (int r = 0; r < 16; ++r) {
            const int qloc = (r & 3) + 8 * (r >> 2) + 4 * hi;
            const float sar = __shfl(sa, qloc, 64);
            const float sbr = __shfl(sb, qloc, 64);
            const float ivr = __shfl(inv, qloc, 64);
            unsigned short* dst = ctx + qkbase + (size_t)(q0 + wq * 32 + qloc) * D_MODEL;
            dst[l31]      = f2bf((o0[r] * sar + p[r] * sbr) * ivr);
            dst[32 + l31] = f2bf((o1[r] * sar + p[16 + r] * sbr) * ivr);
        }
    }
}

// ---------------------------------------------------------------------------
// LayerNorm over last dim (1024). One block per row.
// ---------------------------------------------------------------------------
__global__ __launch_bounds__(256) void layernorm1024(
    const float* __restrict__ x, const float* __restrict__ gamma,
    const float* __restrict__ beta, float* __restrict__ out)
{
    const int row = blockIdx.x;
    const int tid = threadIdx.x;
    const float* xr = x + (size_t)row * D_MODEL;
    float4 v = *(const float4*)(xr + (tid << 2));
    float s = v.x + v.y + v.z + v.w;
    float q = v.x * v.x + v.y * v.y + v.z * v.z + v.w * v.w;
    #pragma unroll
    for (int off = 1; off < 64; off <<= 1) {
        s += __shfl_xor(s, off, 64);
        q += __shfl_xor(q, off, 64);
    }
    __shared__ float sw[4], qw_[4];
    const int wid = tid >> 6;
    if ((tid & 63) == 0) { sw[wid] = s; qw_[wid] = q; }
    __syncthreads();
    s = sw[0] + sw[1] + sw[2] + sw[3];
    q = qw_[0] + qw_[1] + qw_[2] + qw_[3];
    const float mu  = s * (1.f / D_MODEL);
    const float var = q * (1.f / D_MODEL) - mu * mu;
    const float a = var + 1e-5f;
    float inv = rsqrtf(a);
    inv = inv * (1.5f - 0.5f * a * inv * inv);
    float4 gg = *(const float4*)(gamma + (tid << 2));
    float4 bt = *(const float4*)(beta + (tid << 2));
    float4 o;
    o.x = (v.x - mu) * inv * gg.x + bt.x;
    o.y = (v.y - mu) * inv * gg.y + bt.y;
    o.z = (v.z - mu) * inv * gg.z + bt.z;
    o.w = (v.w - mu) * inv * gg.w + bt.w;
    *(float4*)(out + (size_t)row * D_MODEL + (tid << 2)) = o;
}

// ---------------------------------------------------------------------------
extern "C" void kernel_launch(void* const* d_in, const int* in_sizes, int n_in,
                              void* d_out, int out_size, void* d_ws, size_t ws_size,
                              hipStream_t stream)
{
    const float* Q    = (const float*)d_in[0];
    const float* K    = (const float*)d_in[1];
    const float* V    = (const float*)d_in[2];
    const void*  mask = d_in[3];
    const float* Wq   = (const float*)d_in[4];
    const float* bq   = (const float*)d_in[5];
    const float* Wk   = (const float*)d_in[6];
    const float* bk   = (const float*)d_in[7];
    const float* Wv   = (const float*)d_in[8];
    const float* bv   = (const float*)d_in[9];
    const float* Wo   = (const float*)d_in[10];
    const float* bo   = (const float*)d_in[11];
    const float* gam  = (const float*)d_in[12];
    const float* bet  = (const float*)d_in[13];
    float* out = (float*)d_out;

    const size_t NE = (size_t)MROWS * D_MODEL;           // 4,194,304 elems
    const size_t WE = (size_t)D_MODEL * D_MODEL;
    unsigned short* Qbf = (unsigned short*)d_ws;         // reused as ctxb
    unsigned short* Kbf = Qbf + NE;                      // reused as outp
    unsigned short* Vbf = Kbf + NE;
    unsigned short* qb  = Vbf + NE;
    unsigned short* kb  = qb + NE;
    unsigned short* vt  = kb + NE;                       // [b][h][d][tok]
    unsigned short* Wt0 = vt + NE;
    unsigned short* Wt1 = Wt0 + WE;
    unsigned short* Wt2 = Wt1 + WE;
    unsigned short* Wt3 = Wt2 + WE;
    unsigned long long* mbits = (unsigned long long*)(Wt3 + WE);
    const size_t NMW = (size_t)BATCH * SEQ * (SEQ / 64);
    int* mflags = (int*)(mbits + NMW);
    unsigned short* ctxb = Qbf;
    float* outp = (float*)Kbf;
    if (ws_size < 6 * NE * 2 + 4 * WE * 2 + NMW * 8 + 64) return;

    hipMemsetAsync(mflags, 0, 2 * sizeof(int), stream);
    detect_mask_par<<<256, 256, 0, stream>>>((const unsigned int*)mask, 65536, mflags);
    pack_mask_ballot<<<2048, 256, 0, stream>>>(mask, mflags, mbits, (int)NMW);

    cvt_bf16<<<dim3(NE / 8 / 256, 3), 256, 0, stream>>>(Q, K, V, Qbf, Kbf, Vbf);
    cvt_wT<<<dim3(16, 16, 4), 256, 0, stream>>>(Wq, Wk, Wv, Wo, Wt0, Wt1, Wt2, Wt3);

    gemm_qkv<<<dim3(8, 32, 3), 256, 0, stream>>>(Qbf, Kbf, Vbf, Wt0, Wt1, Wt2,
                                                 bq, bk, bv, qb, kb, vt);

    dim3 ag(SEQ / 128, NHEADS, BATCH);     // (16, 16, 2), 512 threads
    attn_mfma32<<<ag, 512, 0, stream>>>(qb, kb, vt, mbits, ctxb);

    gemm_out<<<dim3(8, 32), 256, 0, stream>>>(ctxb, Wt3, bo, Q, outp);

    layernorm1024<<<MROWS, 256, 0, stream>>>(outp, gam, bet, out);
}

// Round 8
// 234.961 us; speedup vs baseline: 8.7599x; 1.0304x over previous
//
#include <hip/hip_runtime.h>
#include <hip/hip_bf16.h>
#include <math.h>

// Fused MHA block: proj(Q,K,V) -> masked softmax attention -> out proj + residual -> LayerNorm
// Round 8: cvt_bf16 kernel deleted (fp32->bf16 fused into gemm_qkv A-staging via
// v_cvt_pk_bf16_f32 + ds_write_b128); gemm_out restructured to 128x64 tiles
// (512 blocks = 2/CU; was 1/CU with barrier stalls exposed); attn staging pointers
// made incremental. Attention core otherwise unchanged from round 7.

#define D_MODEL 1024
#define NHEADS  16
#define DHEAD   64
#define BATCH   2
#define SEQ     2048
#define MROWS   (BATCH * SEQ)   // 4096
#define SCLF    0.18033688f     // 0.125 * log2(e), folded into Q projection

typedef __attribute__((ext_vector_type(8)))  short bf16x8;
typedef __attribute__((ext_vector_type(4)))  float f32x4;
typedef __attribute__((ext_vector_type(16))) float f32x16;

__device__ inline unsigned short f2bf(float f) {
    unsigned int u = __builtin_bit_cast(unsigned int, f);
    unsigned int r = (u + 0x7FFFu + ((u >> 16) & 1u)) >> 16;   // RNE
    return (unsigned short)r;
}

__device__ inline unsigned cvtpk_bf16(float lo, float hi2) {
    unsigned r;
    asm("v_cvt_pk_bf16_f32 %0, %1, %2" : "=v"(r) : "v"(lo), "v"(hi2));
    return r;
}

// global -> LDS direct copy, 16B per lane. lbase must be wave-uniform.
__device__ inline void gload16(const unsigned short* g, unsigned short* lbase, int lane) {
#if __has_builtin(__builtin_amdgcn_global_load_lds)
    __builtin_amdgcn_global_load_lds(
        (const __attribute__((address_space(1))) unsigned int*)g,
        (__attribute__((address_space(3))) unsigned int*)lbase, 16, 0, 0);
#else
    *(bf16x8*)(lbase + lane * 8) = *(const bf16x8*)g;
#endif
}

// ---------------------------------------------------------------------------
// Parallel mask dtype probe. flags[0]: any word not in {0,1};
// flags[1]: any word not in {0, 0x3F800000}. flags pre-zeroed via memset.
// ---------------------------------------------------------------------------
__global__ __launch_bounds__(256) void detect_mask_par(
    const unsigned int* __restrict__ m, int nwords, int* __restrict__ flags)
{
    const int i = blockIdx.x * 256 + threadIdx.x;
    int a = 0, b = 0;
    if (i < nwords) {
        const unsigned int w = m[i];
        a = (w != 0u && w != 1u);
        b = (w != 0u && w != 0x3F800000u);
    }
    const int wa = (int)__any(a);
    const int wb = (int)__any(b);
    if ((threadIdx.x & 63) == 0) {
        if (wa) atomicOr(&flags[0], 1);
        if (wb) atomicOr(&flags[1], 1);
    }
}

// ---------------------------------------------------------------------------
// Ballot pack: lane i reads element i of a 64-key row (coalesced);
// __ballot(v!=0) IS the packed word.
// ---------------------------------------------------------------------------
__global__ __launch_bounds__(256) void pack_mask_ballot(
    const void* __restrict__ mask, const int* __restrict__ flags,
    unsigned long long* __restrict__ mbits, int nwords)
{
    const int lane   = threadIdx.x & 63;
    const int wv     = blockIdx.x * 4 + (threadIdx.x >> 6);
    const int nwaves = gridDim.x * 4;
    const int mf = (flags[0] == 0) ? 0 : (flags[1] == 0) ? 1 : 2;
    for (int w = wv; w < nwords; w += nwaves) {
        bool bit;
        if (mf == 0)      bit = ((const unsigned int*)mask)[(size_t)w * 64 + lane] != 0u;
        else if (mf == 1) bit = ((const float*)mask)[(size_t)w * 64 + lane] != 0.f;
        else              bit = ((const unsigned char*)mask)[(size_t)w * 64 + lane] != 0;
        const unsigned long long b = __ballot(bit);
        if (lane == 0) mbits[w] = b;
    }
}

// ---------------------------------------------------------------------------
// Weight transpose-convert: W fp32 [K][N] -> Wt bf16 [N][K].
// ---------------------------------------------------------------------------
__global__ __launch_bounds__(256) void cvt_wT(
    const float* __restrict__ w0, const float* __restrict__ w1,
    const float* __restrict__ w2, const float* __restrict__ w3,
    unsigned short* __restrict__ t0, unsigned short* __restrict__ t1,
    unsigned short* __restrict__ t2, unsigned short* __restrict__ t3)
{
    __shared__ float tile[64][65];
    const float* W = (blockIdx.z == 0) ? w0 : (blockIdx.z == 1) ? w1
                   : (blockIdx.z == 2) ? w2 : w3;
    unsigned short* T = (blockIdx.z == 0) ? t0 : (blockIdx.z == 1) ? t1
                      : (blockIdx.z == 2) ? t2 : t3;
    const int k0 = blockIdx.y * 64;
    const int n0 = blockIdx.x * 64;
    const int t  = threadIdx.x;
    const int r  = t >> 4;
    const int c4 = (t & 15) * 4;
    #pragma unroll
    for (int u = 0; u < 4; ++u) {
        float4 v = *(const float4*)(W + (size_t)(k0 + r + u * 16) * D_MODEL + n0 + c4);
        tile[r + u * 16][c4 + 0] = v.x;
        tile[r + u * 16][c4 + 1] = v.y;
        tile[r + u * 16][c4 + 2] = v.z;
        tile[r + u * 16][c4 + 3] = v.w;
    }
    __syncthreads();
    #pragma unroll
    for (int u = 0; u < 4; ++u) {
        const int nr = r + u * 16;
        ushort4 o;
        o.x = f2bf(tile[c4 + 0][nr]);
        o.y = f2bf(tile[c4 + 1][nr]);
        o.z = f2bf(tile[c4 + 2][nr]);
        o.w = f2bf(tile[c4 + 3][nr]);
        *(ushort4*)(T + (size_t)(n0 + nr) * D_MODEL + k0 + c4) = o;
    }
}

// ---------------------------------------------------------------------------
#define BKK 64

// Merged Q/K/V projection GEMM, fp32 A with fused bf16 convert in A-staging.
// z=0: Q (scaled by SCLF, row-major bf16); z=1: K (row-major bf16);
// z=2: V (per-head transposed vt[b][h][d][tok]).
__global__ __launch_bounds__(256, 1) void gemm_qkv(
    const float* __restrict__ A0, const float* __restrict__ A1,
    const float* __restrict__ A2,
    const unsigned short* __restrict__ B0, const unsigned short* __restrict__ B1,
    const unsigned short* __restrict__ B2,
    const float* __restrict__ bias0, const float* __restrict__ bias1,
    const float* __restrict__ bias2,
    unsigned short* __restrict__ C0, unsigned short* __restrict__ C1,
    unsigned short* __restrict__ C2)
{
    const int z = blockIdx.z;
    const float* A           = (z == 0) ? A0 : (z == 1) ? A1 : A2;
    const unsigned short* Bt = (z == 0) ? B0 : (z == 1) ? B1 : B2;
    const float* bias        = (z == 0) ? bias0 : (z == 1) ? bias1 : bias2;
    unsigned short* C        = (z == 0) ? C0 : (z == 1) ? C1 : C2;
    const int K = D_MODEL, N = D_MODEL;

    __shared__ unsigned short As[2][128 * BKK];
    __shared__ unsigned short Bs[2][128 * BKK];
    const int tid  = threadIdx.x;
    const int w    = tid >> 6;
    const int lane = tid & 63;
    const int lo   = lane & 15;
    const int hi   = lane >> 4;
    const int wm   = (w >> 1) * 64;
    const int wn   = (w & 1) * 64;
    const int m0   = blockIdx.y * 128;
    const int n0   = blockIdx.x * 128;

    const float* Ab          = A  + (size_t)m0 * K;
    const unsigned short* Bb = Bt + (size_t)n0 * K;

    f32x4 acc[4][4];
    #pragma unroll
    for (int i = 0; i < 4; ++i)
        #pragma unroll
        for (int j = 0; j < 4; ++j) acc[i][j] = (f32x4){0.f, 0.f, 0.f, 0.f};

    const int NT = K / BKK;
    auto stage = [&](int buf, int t) {
        const int k0 = t * BKK;
        // A: fp32 -> reg -> cvt_pk -> ds_write_b128 (fused conversion)
        #pragma unroll
        for (int i = 0; i < 4; ++i) {
            const int c = i * 256 + tid;
            const float* src = Ab + (size_t)(c >> 3) * K + k0 + (c & 7) * 8;
            float4 fa = *(const float4*)src;
            float4 fb = *(const float4*)(src + 4);
            unsigned u0 = cvtpk_bf16(fa.x, fa.y);
            unsigned u1 = cvtpk_bf16(fa.z, fa.w);
            unsigned u2 = cvtpk_bf16(fb.x, fb.y);
            unsigned u3 = cvtpk_bf16(fb.z, fb.w);
            int4 pk = make_int4((int)u0, (int)u1, (int)u2, (int)u3);
            *(int4*)&As[buf][(size_t)c * 8] = pk;
        }
        // B: direct global -> LDS
        #pragma unroll
        for (int i = 0; i < 4; ++i) {
            const int c = i * 256 + tid;
            gload16(Bb + (size_t)(c >> 3) * K + k0 + (c & 7) * 8,
                    &Bs[buf][(i * 256 + w * 64) * 8], lane);
        }
    };

    stage(0, 0);
    __syncthreads();
    int cur = 0;
    for (int t = 0; t < NT; ++t) {
        if (t + 1 < NT) stage(cur ^ 1, t + 1);
        bf16x8 af[4][2], bfr[4][2];
        #pragma unroll
        for (int f = 0; f < 4; ++f)
            #pragma unroll
            for (int s = 0; s < 2; ++s) {
                af[f][s]  = *(const bf16x8*)&As[cur][(wm + f * 16 + lo) * BKK + s * 32 + hi * 8];
                bfr[f][s] = *(const bf16x8*)&Bs[cur][(wn + f * 16 + lo) * BKK + s * 32 + hi * 8];
            }
        #pragma unroll
        for (int s = 0; s < 2; ++s)
            #pragma unroll
            for (int fm = 0; fm < 4; ++fm)
                #pragma unroll
                for (int fn = 0; fn < 4; ++fn)
                    acc[fm][fn] = __builtin_amdgcn_mfma_f32_16x16x32_bf16(
                        af[fm][s], bfr[fn][s], acc[fm][fn], 0, 0, 0);
        __syncthreads();
        cur ^= 1;
    }

    #pragma unroll
    for (int fm = 0; fm < 4; ++fm) {
        const int row = m0 + wm + fm * 16 + hi * 4;
        #pragma unroll
        for (int fn = 0; fn < 4; ++fn) {
            const int col = n0 + wn + fn * 16 + lo;
            const float bv = bias[col];
            #pragma unroll
            for (int r = 0; r < 4; ++r) {
                float o = acc[fm][fn][r] + bv;
                if (z == 0) o *= SCLF;            // fold softmax scale into Q
                if (z < 2)
                    C[(size_t)(row + r) * N + col] = f2bf(o);
                else
                    C[(size_t)((row + r) >> 11) * 2097152
                      + (size_t)col * 2048 + ((row + r) & 2047)] = f2bf(o);
            }
        }
    }
}

// ---------------------------------------------------------------------------
// Out-projection GEMM: 128x64 tile (512 blocks = 2/CU for pipeline overlap),
// fp32 out + residual add.
// ---------------------------------------------------------------------------
__global__ __launch_bounds__(256) void gemm_out64(
    const unsigned short* __restrict__ A, const unsigned short* __restrict__ Bt,
    const float* __restrict__ bias, const float* __restrict__ resid,
    float* __restrict__ C)
{
    const int K = D_MODEL, N = D_MODEL;
    __shared__ unsigned short As[2][128 * BKK];
    __shared__ unsigned short Bs[2][64 * BKK];
    const int tid  = threadIdx.x;
    const int w    = tid >> 6;
    const int lane = tid & 63;
    const int lo   = lane & 15;
    const int hi   = lane >> 4;
    const int wm   = (w >> 1) * 64;   // 2 wave-rows
    const int wn   = (w & 1) * 32;    // 2 wave-cols
    const int m0   = blockIdx.y * 128;
    const int n0   = blockIdx.x * 64;

    const unsigned short* Ab = A  + (size_t)m0 * K;
    const unsigned short* Bb = Bt + (size_t)n0 * K;

    f32x4 acc[4][2];
    #pragma unroll
    for (int i = 0; i < 4; ++i)
        #pragma unroll
        for (int j = 0; j < 2; ++j) acc[i][j] = (f32x4){0.f, 0.f, 0.f, 0.f};

    const int NT = K / BKK;
    auto stage = [&](int buf, int t) {
        const int k0 = t * BKK;
        #pragma unroll
        for (int i = 0; i < 4; ++i) {
            const int c = i * 256 + tid;
            gload16(Ab + (size_t)(c >> 3) * K + k0 + (c & 7) * 8,
                    &As[buf][(i * 256 + w * 64) * 8], lane);
        }
        #pragma unroll
        for (int i = 0; i < 2; ++i) {
            const int c = i * 256 + tid;
            gload16(Bb + (size_t)(c >> 3) * K + k0 + (c & 7) * 8,
                    &Bs[buf][(i * 256 + w * 64) * 8], lane);
        }
    };

    stage(0, 0);
    __syncthreads();
    int cur = 0;
    for (int t = 0; t < NT; ++t) {
        if (t + 1 < NT) stage(cur ^ 1, t + 1);
        bf16x8 af[4][2], bfr[2][2];
        #pragma unroll
        for (int f = 0; f < 4; ++f)
            #pragma unroll
            for (int s = 0; s < 2; ++s)
                af[f][s] = *(const bf16x8*)&As[cur][(wm + f * 16 + lo) * BKK + s * 32 + hi * 8];
        #pragma unroll
        for (int f = 0; f < 2; ++f)
            #pragma unroll
            for (int s = 0; s < 2; ++s)
                bfr[f][s] = *(const bf16x8*)&Bs[cur][(wn + f * 16 + lo) * BKK + s * 32 + hi * 8];
        #pragma unroll
        for (int s = 0; s < 2; ++s)
            #pragma unroll
            for (int fm = 0; fm < 4; ++fm)
                #pragma unroll
                for (int fn = 0; fn < 2; ++fn)
                    acc[fm][fn] = __builtin_amdgcn_mfma_f32_16x16x32_bf16(
                        af[fm][s], bfr[fn][s], acc[fm][fn], 0, 0, 0);
        __syncthreads();
        cur ^= 1;
    }

    #pragma unroll
    for (int fm = 0; fm < 4; ++fm) {
        const int row = m0 + wm + fm * 16 + hi * 4;
        #pragma unroll
        for (int fn = 0; fn < 2; ++fn) {
            const int col = n0 + wn + fn * 16 + lo;
            const float bv = bias[col];
            #pragma unroll
            for (int r = 0; r < 4; ++r)
                C[(size_t)(row + r) * N + col] =
                    acc[fm][fn][r] + bv + resid[(size_t)(row + r) * N + col];
        }
    }
}

// ---------------------------------------------------------------------------
// Swapped-QK^T 32x32 MFMA flash attention with in-block K-split.
// Block = (b, h, 128 q-rows): 8 waves = 2 k-groups (g) x 4 q-waves (wq).
// Incremental staging pointers (stride per tile; swizzle is row-mod-8 invariant).
// ---------------------------------------------------------------------------
__global__ __launch_bounds__(512, 2) void attn_mfma32(
    const unsigned short* __restrict__ qb, const unsigned short* __restrict__ kbm,
    const unsigned short* __restrict__ vt,
    const unsigned long long* __restrict__ mbits, unsigned short* __restrict__ ctx)
{
    __shared__ unsigned char smem[65536];   // [0,32K): K staging; [32K,64K): V staging
    const int tid  = threadIdx.x;
    const int w8   = tid >> 6;
    const int g    = w8 >> 2;        // k-group (0: tiles 0..15, 1: tiles 16..31)
    const int wq   = w8 & 3;         // q-wave within group
    const int lane = tid & 63;
    const int l31  = lane & 31;
    const int hi   = lane >> 5;
    const int q0   = blockIdx.x * 128;
    const int h    = blockIdx.y;
    const int b    = blockIdx.z;

    unsigned short* KsG = (unsigned short*)smem + (size_t)g * 8192;            // [buf][4096]
    unsigned short* VsG = (unsigned short*)(smem + 32768) + (size_t)g * 8192;  // [buf][4096]

    const size_t qkbase = (size_t)b * SEQ * D_MODEL + (size_t)h * DHEAD;
    const size_t vtbase = ((size_t)b * D_MODEL + h * DHEAD) * SEQ;

    const int qtok = q0 + wq * 32 + l31;
    bf16x8 qA[4];
    #pragma unroll
    for (int s = 0; s < 4; ++s)
        qA[s] = *(const bf16x8*)(qb + qkbase + (size_t)qtok * D_MODEL + s * 16 + hi * 8);

    f32x16 o0 = {}, o1 = {};
    float m_i = -INFINITY, l_i = 0.f;

    const unsigned long long* mrow = mbits + ((size_t)b * SEQ + qtok) * (SEQ / 64);

    const int srow = lane >> 3;
    const int sc   = lane & 7;
    const int r0   = wq * 16 + srow;          // row-in-tile for this lane (cc=0)
    const int swz  = sc ^ (r0 & 7);           // (r0+8)&7 == r0&7, shared by cc=1

    // incremental per-tile staging pointers
    const unsigned short* kl0 = kbm + qkbase + (size_t)(g * 1024 + r0) * D_MODEL + swz * 8;
    const unsigned short* kl1 = kl0 + (size_t)8 * D_MODEL;
    const unsigned short* vl0 = vt + vtbase + (size_t)r0 * SEQ + g * 1024 + swz * 8;
    const unsigned short* vl1 = vl0 + (size_t)8 * SEQ;
    const int ldk0 = (wq * 16) * 64;
    const int ldk1 = (wq * 16 + 8) * 64;

    auto stage = [&](int buf) {
        gload16(kl0, &KsG[buf * 4096 + ldk0], lane);
        gload16(kl1, &KsG[buf * 4096 + ldk1], lane);
        gload16(vl0, &VsG[buf * 4096 + ldk0], lane);
        gload16(vl1, &VsG[buf * 4096 + ldk1], lane);
        kl0 += (size_t)64 * D_MODEL;
        kl1 += (size_t)64 * D_MODEL;
        vl0 += 64;
        vl1 += 64;
    };

    stage(0);
    unsigned long long mw64 = mrow[g * 16];     // prefetch tile 0's mask word
    __syncthreads();
    int cur = 0;

    for (int t = 0; t < 16; ++t) {
        if (t + 1 < 16) stage(cur ^ 1);
        const unsigned long long mwc = mw64;
        if (t + 1 < 16) mw64 = mrow[g * 16 + t + 1];   // prefetch next
        const unsigned int ml = (unsigned int)(mwc >> (4 * hi));
        const unsigned int mh = (unsigned int)(mwc >> (32 + 4 * hi));

        // ---- QK^T (pre-scaled Q): S^T[key][q] ----
        f32x16 st0 = {}, st1 = {};
        __builtin_amdgcn_s_setprio(1);
        #pragma unroll
        for (int s = 0; s < 4; ++s) {
            bf16x8 kf0 = *(const bf16x8*)&KsG[cur * 4096 + l31 * 64 + ((2 * s + hi) ^ (l31 & 7)) * 8];
            st0 = __builtin_amdgcn_mfma_f32_32x32x16_bf16(kf0, qA[s], st0, 0, 0, 0);
            bf16x8 kf1 = *(const bf16x8*)&KsG[cur * 4096 + (32 + l31) * 64 + ((2 * s + hi) ^ (l31 & 7)) * 8];
            st1 = __builtin_amdgcn_mfma_f32_32x32x16_bf16(kf1, qA[s], st1, 0, 0, 0);
        }
        __builtin_amdgcn_s_setprio(0);

        // ---- mask + lane-local max (4-partial tree) ----
        float rx[4] = {-3.0e38f, -3.0e38f, -3.0e38f, -3.0e38f};
        #pragma unroll
        for (int r = 0; r < 16; ++r) {
            const int klo = (r & 3) + 8 * (r >> 2);
            float x0 = st0[r], x1 = st1[r];
            if ((ml >> klo) & 1u) x0 = -1e9f;
            if ((mh >> klo) & 1u) x1 = -1e9f;
            st0[r] = x0; st1[r] = x1;
            rx[r & 3] = fmaxf(rx[r & 3], fmaxf(x0, x1));
        }
        float rmax = fmaxf(fmaxf(rx[0], rx[1]), fmaxf(rx[2], rx[3]));
        rmax = fmaxf(rmax, __shfl_xor(rmax, 32, 64));

        // ---- defer-max (T13) ----
        const bool defer = (bool)__all(rmax - m_i <= 8.0f);
        float alpha = 1.f;
        if (!defer) {
            const float mn = fmaxf(m_i, rmax);
            alpha = exp2f(m_i - mn);
            m_i = mn;
        }
        float sp[4] = {0.f, 0.f, 0.f, 0.f};
        #pragma unroll
        for (int r = 0; r < 16; ++r) {
            float e0 = exp2f(st0[r] - m_i);
            float e1 = exp2f(st1[r] - m_i);
            st0[r] = e0; st1[r] = e1;
            sp[r & 3] += e0 + e1;
        }
        float ls = (sp[0] + sp[1]) + (sp[2] + sp[3]);
        ls += __shfl_xor(ls, 32, 64);
        if (!defer) {
            l_i = l_i * alpha + ls;
            #pragma unroll
            for (int r = 0; r < 16; ++r) {
                const float aq = __shfl(alpha, (r & 3) + 8 * (r >> 2) + 4 * hi, 64);
                o0[r] *= aq; o1[r] *= aq;
            }
        } else {
            l_i += ls;
        }

        // ---- P -> bf16 A-frags (T12) ----
        bf16x8 pa[4];
        #pragma unroll
        for (int s = 0; s < 4; ++s) {
            const int base = (s & 1) * 8;
            unsigned av, bv2, cv, dv;
            if (s < 2) {
                av  = cvtpk_bf16(st0[base + 0], st0[base + 1]);
                bv2 = cvtpk_bf16(st0[base + 4], st0[base + 5]);
                cv  = cvtpk_bf16(st0[base + 2], st0[base + 3]);
                dv  = cvtpk_bf16(st0[base + 6], st0[base + 7]);
            } else {
                av  = cvtpk_bf16(st1[base + 0], st1[base + 1]);
                bv2 = cvtpk_bf16(st1[base + 4], st1[base + 5]);
                cv  = cvtpk_bf16(st1[base + 2], st1[base + 3]);
                dv  = cvtpk_bf16(st1[base + 6], st1[base + 7]);
            }
            asm("v_permlane32_swap_b32 %0, %1" : "+v"(av), "+v"(bv2));
            asm("v_permlane32_swap_b32 %0, %1" : "+v"(cv), "+v"(dv));
            int4 pk = make_int4((int)av, (int)cv, (int)bv2, (int)dv);
            pa[s] = __builtin_bit_cast(bf16x8, pk);
        }

        // ---- PV ----
        __builtin_amdgcn_s_setprio(1);
        #pragma unroll
        for (int s = 0; s < 4; ++s) {
            bf16x8 vf0 = *(const bf16x8*)&VsG[cur * 4096 + l31 * 64 + ((2 * s + hi) ^ (l31 & 7)) * 8];
            o0 = __builtin_amdgcn_mfma_f32_32x32x16_bf16(pa[s], vf0, o0, 0, 0, 0);
            bf16x8 vf1 = *(const bf16x8*)&VsG[cur * 4096 + (32 + l31) * 64 + ((2 * s + hi) ^ (l31 & 7)) * 8];
            o1 = __builtin_amdgcn_mfma_f32_32x32x16_bf16(pa[s], vf1, o1, 0, 0, 0);
        }
        __builtin_amdgcn_s_setprio(0);
        __syncthreads();
        cur ^= 1;
    }

    // ---- flash-combine of the two k-group partials (reuse staging LDS) ----
    __syncthreads();
    float* comb = (float*)smem;          // [wq][lane][35] floats, stride 35 (odd)
    if (g == 1) {
        float* p = comb + (size_t)(wq * 64 + lane) * 35;
        #pragma unroll
        for (int r = 0; r < 16; ++r) { p[r] = o0[r]; p[16 + r] = o1[r]; }
        p[32] = m_i; p[33] = l_i;
    }
    __syncthreads();
    if (g == 0) {
        const float* p = comb + (size_t)(wq * 64 + lane) * 35;
        const float mb = p[32], lb = p[33];
        const float ms = fmaxf(m_i, mb);
        const float sa = exp2f(m_i - ms);
        const float sb = exp2f(mb - ms);
        const float inv = 1.f / (l_i * sa + lb * sb);
        #pragma unroll
        for (int r = 0; r < 16; ++r) {
            const int qloc = (r & 3) + 8 * (r >> 2) + 4 * hi;
            const float sar = __shfl(sa, qloc, 64);
            const float sbr = __shfl(sb, qloc, 64);
            const float ivr = __shfl(inv, qloc, 64);
            unsigned short* dst = ctx + qkbase + (size_t)(q0 + wq * 32 + qloc) * D_MODEL;
            dst[l31]      = f2bf((o0[r] * sar + p[r] * sbr) * ivr);
            dst[32 + l31] = f2bf((o1[r] * sar + p[16 + r] * sbr) * ivr);
        }
    }
}

// ---------------------------------------------------------------------------
// LayerNorm over last dim (1024). One block per row.
// ---------------------------------------------------------------------------
__global__ __launch_bounds__(256) void layernorm1024(
    const float* __restrict__ x, const float* __restrict__ gamma,
    const float* __restrict__ beta, float* __restrict__ out)
{
    const int row = blockIdx.x;
    const int tid = threadIdx.x;
    const float* xr = x + (size_t)row * D_MODEL;
    float4 v = *(const float4*)(xr + (tid << 2));
    float s = v.x + v.y + v.z + v.w;
    float q = v.x * v.x + v.y * v.y + v.z * v.z + v.w * v.w;
    #pragma unroll
    for (int off = 1; off < 64; off <<= 1) {
        s += __shfl_xor(s, off, 64);
        q += __shfl_xor(q, off, 64);
    }
    __shared__ float sw[4], qw_[4];
    const int wid = tid >> 6;
    if ((tid & 63) == 0) { sw[wid] = s; qw_[wid] = q; }
    __syncthreads();
    s = sw[0] + sw[1] + sw[2] + sw[3];
    q = qw_[0] + qw_[1] + qw_[2] + qw_[3];
    const float mu  = s * (1.f / D_MODEL);
    const float var = q * (1.f / D_MODEL) - mu * mu;
    const float a = var + 1e-5f;
    float inv = rsqrtf(a);
    inv = inv * (1.5f - 0.5f * a * inv * inv);
    float4 gg = *(const float4*)(gamma + (tid << 2));
    float4 bt = *(const float4*)(beta + (tid << 2));
    float4 o;
    o.x = (v.x - mu) * inv * gg.x + bt.x;
    o.y = (v.y - mu) * inv * gg.y + bt.y;
    o.z = (v.z - mu) * inv * gg.z + bt.z;
    o.w = (v.w - mu) * inv * gg.w + bt.w;
    *(float4*)(out + (size_t)row * D_MODEL + (tid << 2)) = o;
}

// ---------------------------------------------------------------------------
extern "C" void kernel_launch(void* const* d_in, const int* in_sizes, int n_in,
                              void* d_out, int out_size, void* d_ws, size_t ws_size,
                              hipStream_t stream)
{
    const float* Q    = (const float*)d_in[0];
    const float* K    = (const float*)d_in[1];
    const float* V    = (const float*)d_in[2];
    const void*  mask = d_in[3];
    const float* Wq   = (const float*)d_in[4];
    const float* bq   = (const float*)d_in[5];
    const float* Wk   = (const float*)d_in[6];
    const float* bk   = (const float*)d_in[7];
    const float* Wv   = (const float*)d_in[8];
    const float* bv   = (const float*)d_in[9];
    const float* Wo   = (const float*)d_in[10];
    const float* bo   = (const float*)d_in[11];
    const float* gam  = (const float*)d_in[12];
    const float* bet  = (const float*)d_in[13];
    float* out = (float*)d_out;

    const size_t NE = (size_t)MROWS * D_MODEL;           // 4,194,304 elems
    const size_t WE = (size_t)D_MODEL * D_MODEL;
    const size_t NMW = (size_t)BATCH * SEQ * (SEQ / 64); // 131072 mask words
    unsigned short* qb  = (unsigned short*)d_ws;
    unsigned short* kb  = qb + NE;
    unsigned short* vt  = kb + NE;                       // [b][h][d][tok]
    unsigned short* Wt0 = vt + NE;
    unsigned short* Wt1 = Wt0 + WE;
    unsigned short* Wt2 = Wt1 + WE;
    unsigned short* Wt3 = Wt2 + WE;
    unsigned long long* mbits = (unsigned long long*)(Wt3 + WE);
    int* mflags = (int*)(mbits + NMW);
    unsigned short* ctxb = (unsigned short*)(mflags + 16);
    float* outp = (float*)(ctxb + NE);
    if (ws_size < 6 * NE * 2 + 4 * WE * 2 + NMW * 8 + 64) return;

    hipMemsetAsync(mflags, 0, 2 * sizeof(int), stream);
    detect_mask_par<<<256, 256, 0, stream>>>((const unsigned int*)mask, 65536, mflags);
    pack_mask_ballot<<<2048, 256, 0, stream>>>(mask, mflags, mbits, (int)NMW);

    cvt_wT<<<dim3(16, 16, 4), 256, 0, stream>>>(Wq, Wk, Wv, Wo, Wt0, Wt1, Wt2, Wt3);

    gemm_qkv<<<dim3(8, 32, 3), 256, 0, stream>>>(Q, K, V, Wt0, Wt1, Wt2,
                                                 bq, bk, bv, qb, kb, vt);

    dim3 ag(SEQ / 128, NHEADS, BATCH);     // (16, 16, 2), 512 threads
    attn_mfma32<<<ag, 512, 0, stream>>>(qb, kb, vt, mbits, ctxb);

    gemm_out64<<<dim3(16, 32), 256, 0, stream>>>(ctxb, Wt3, bo, Q, outp);

    layernorm1024<<<MROWS, 256, 0, stream>>>(outp, gam, bet, out);
}

// Round 9
// 226.091 us; speedup vs baseline: 9.1036x; 1.0392x over previous
//
#include <hip/hip_runtime.h>
#include <hip/hip_bf16.h>
#include <math.h>

// Fused MHA block: proj(Q,K,V) -> masked softmax attention -> out proj + residual -> LayerNorm
// Round 9: fix round-8 gemm_qkv stall — T14 async-stage split (A-loads issued before
// MFMA, cvt+ds_write after) + m-major grids so blocks sharing an A-panel land on one
// XCD (L2 reuse; was 8x A re-fetch). attn grid flipped h-major for K/V L2 reuse.

#define D_MODEL 1024
#define NHEADS  16
#define DHEAD   64
#define BATCH   2
#define SEQ     2048
#define MROWS   (BATCH * SEQ)   // 4096
#define SCLF    0.18033688f     // 0.125 * log2(e), folded into Q projection

typedef __attribute__((ext_vector_type(8)))  short bf16x8;
typedef __attribute__((ext_vector_type(4)))  float f32x4;
typedef __attribute__((ext_vector_type(16))) float f32x16;

__device__ inline unsigned short f2bf(float f) {
    unsigned int u = __builtin_bit_cast(unsigned int, f);
    unsigned int r = (u + 0x7FFFu + ((u >> 16) & 1u)) >> 16;   // RNE
    return (unsigned short)r;
}

__device__ inline unsigned cvtpk_bf16(float lo, float hi2) {
    unsigned r;
    asm("v_cvt_pk_bf16_f32 %0, %1, %2" : "=v"(r) : "v"(lo), "v"(hi2));
    return r;
}

// global -> LDS direct copy, 16B per lane. lbase must be wave-uniform.
__device__ inline void gload16(const unsigned short* g, unsigned short* lbase, int lane) {
#if __has_builtin(__builtin_amdgcn_global_load_lds)
    __builtin_amdgcn_global_load_lds(
        (const __attribute__((address_space(1))) unsigned int*)g,
        (__attribute__((address_space(3))) unsigned int*)lbase, 16, 0, 0);
#else
    *(bf16x8*)(lbase + lane * 8) = *(const bf16x8*)g;
#endif
}

// ---------------------------------------------------------------------------
// Parallel mask dtype probe. flags[0]: any word not in {0,1};
// flags[1]: any word not in {0, 0x3F800000}. flags pre-zeroed via memset.
// ---------------------------------------------------------------------------
__global__ __launch_bounds__(256) void detect_mask_par(
    const unsigned int* __restrict__ m, int nwords, int* __restrict__ flags)
{
    const int i = blockIdx.x * 256 + threadIdx.x;
    int a = 0, b = 0;
    if (i < nwords) {
        const unsigned int w = m[i];
        a = (w != 0u && w != 1u);
        b = (w != 0u && w != 0x3F800000u);
    }
    const int wa = (int)__any(a);
    const int wb = (int)__any(b);
    if ((threadIdx.x & 63) == 0) {
        if (wa) atomicOr(&flags[0], 1);
        if (wb) atomicOr(&flags[1], 1);
    }
}

// ---------------------------------------------------------------------------
// Ballot pack: lane i reads element i of a 64-key row (coalesced);
// __ballot(v!=0) IS the packed word.
// ---------------------------------------------------------------------------
__global__ __launch_bounds__(256) void pack_mask_ballot(
    const void* __restrict__ mask, const int* __restrict__ flags,
    unsigned long long* __restrict__ mbits, int nwords)
{
    const int lane   = threadIdx.x & 63;
    const int wv     = blockIdx.x * 4 + (threadIdx.x >> 6);
    const int nwaves = gridDim.x * 4;
    const int mf = (flags[0] == 0) ? 0 : (flags[1] == 0) ? 1 : 2;
    for (int w = wv; w < nwords; w += nwaves) {
        bool bit;
        if (mf == 0)      bit = ((const unsigned int*)mask)[(size_t)w * 64 + lane] != 0u;
        else if (mf == 1) bit = ((const float*)mask)[(size_t)w * 64 + lane] != 0.f;
        else              bit = ((const unsigned char*)mask)[(size_t)w * 64 + lane] != 0;
        const unsigned long long b = __ballot(bit);
        if (lane == 0) mbits[w] = b;
    }
}

// ---------------------------------------------------------------------------
// Weight transpose-convert: W fp32 [K][N] -> Wt bf16 [N][K].
// ---------------------------------------------------------------------------
__global__ __launch_bounds__(256) void cvt_wT(
    const float* __restrict__ w0, const float* __restrict__ w1,
    const float* __restrict__ w2, const float* __restrict__ w3,
    unsigned short* __restrict__ t0, unsigned short* __restrict__ t1,
    unsigned short* __restrict__ t2, unsigned short* __restrict__ t3)
{
    __shared__ float tile[64][65];
    const float* W = (blockIdx.z == 0) ? w0 : (blockIdx.z == 1) ? w1
                   : (blockIdx.z == 2) ? w2 : w3;
    unsigned short* T = (blockIdx.z == 0) ? t0 : (blockIdx.z == 1) ? t1
                      : (blockIdx.z == 2) ? t2 : t3;
    const int k0 = blockIdx.y * 64;
    const int n0 = blockIdx.x * 64;
    const int t  = threadIdx.x;
    const int r  = t >> 4;
    const int c4 = (t & 15) * 4;
    #pragma unroll
    for (int u = 0; u < 4; ++u) {
        float4 v = *(const float4*)(W + (size_t)(k0 + r + u * 16) * D_MODEL + n0 + c4);
        tile[r + u * 16][c4 + 0] = v.x;
        tile[r + u * 16][c4 + 1] = v.y;
        tile[r + u * 16][c4 + 2] = v.z;
        tile[r + u * 16][c4 + 3] = v.w;
    }
    __syncthreads();
    #pragma unroll
    for (int u = 0; u < 4; ++u) {
        const int nr = r + u * 16;
        ushort4 o;
        o.x = f2bf(tile[c4 + 0][nr]);
        o.y = f2bf(tile[c4 + 1][nr]);
        o.z = f2bf(tile[c4 + 2][nr]);
        o.w = f2bf(tile[c4 + 3][nr]);
        *(ushort4*)(T + (size_t)(n0 + nr) * D_MODEL + k0 + c4) = o;
    }
}

// ---------------------------------------------------------------------------
#define BKK 64

// Merged Q/K/V projection GEMM, fp32 A with fused bf16 convert.
// T14 split-stage: A-loads issued BEFORE the MFMA block, cvt+ds_write AFTER.
// Grid is m-major (x = m-tile) so the 8 n-blocks sharing an A-panel map to
// one XCD (bid%8 = x%8) -> A fetched once per panel.
// z=0: Q (scaled by SCLF); z=1: K; z=2: V transposed vt[b][h][d][tok].
__global__ __launch_bounds__(256, 1) void gemm_qkv(
    const float* __restrict__ A0, const float* __restrict__ A1,
    const float* __restrict__ A2,
    const unsigned short* __restrict__ B0, const unsigned short* __restrict__ B1,
    const unsigned short* __restrict__ B2,
    const float* __restrict__ bias0, const float* __restrict__ bias1,
    const float* __restrict__ bias2,
    unsigned short* __restrict__ C0, unsigned short* __restrict__ C1,
    unsigned short* __restrict__ C2)
{
    const int z = blockIdx.z;
    const float* A           = (z == 0) ? A0 : (z == 1) ? A1 : A2;
    const unsigned short* Bt = (z == 0) ? B0 : (z == 1) ? B1 : B2;
    const float* bias        = (z == 0) ? bias0 : (z == 1) ? bias1 : bias2;
    unsigned short* C        = (z == 0) ? C0 : (z == 1) ? C1 : C2;
    const int K = D_MODEL, N = D_MODEL;

    __shared__ unsigned short As[2][128 * BKK];
    __shared__ unsigned short Bs[2][128 * BKK];
    const int tid  = threadIdx.x;
    const int w    = tid >> 6;
    const int lane = tid & 63;
    const int lo   = lane & 15;
    const int hi   = lane >> 4;
    const int wm   = (w >> 1) * 64;
    const int wn   = (w & 1) * 64;
    const int m0   = blockIdx.x * 128;   // m-major
    const int n0   = blockIdx.y * 128;

    const float* Ab          = A  + (size_t)m0 * K;
    const unsigned short* Bb = Bt + (size_t)n0 * K;

    f32x4 acc[4][4];
    #pragma unroll
    for (int i = 0; i < 4; ++i)
        #pragma unroll
        for (int j = 0; j < 4; ++j) acc[i][j] = (f32x4){0.f, 0.f, 0.f, 0.f};

    const int NT = K / BKK;

    float4 fa[4], fb[4];                 // in-flight A chunks (T14)
    auto loadA = [&](int t) {
        const int k0 = t * BKK;
        #pragma unroll
        for (int i = 0; i < 4; ++i) {
            const int c = i * 256 + tid;
            const float* src = Ab + (size_t)(c >> 3) * K + k0 + (c & 7) * 8;
            fa[i] = *(const float4*)src;
            fb[i] = *(const float4*)(src + 4);
        }
    };
    auto writeA = [&](int buf) {
        #pragma unroll
        for (int i = 0; i < 4; ++i) {
            const int c = i * 256 + tid;
            unsigned u0 = cvtpk_bf16(fa[i].x, fa[i].y);
            unsigned u1 = cvtpk_bf16(fa[i].z, fa[i].w);
            unsigned u2 = cvtpk_bf16(fb[i].x, fb[i].y);
            unsigned u3 = cvtpk_bf16(fb[i].z, fb[i].w);
            *(int4*)&As[buf][(size_t)c * 8] = make_int4((int)u0, (int)u1, (int)u2, (int)u3);
        }
    };
    auto stageB = [&](int buf, int t) {
        const int k0 = t * BKK;
        #pragma unroll
        for (int i = 0; i < 4; ++i) {
            const int c = i * 256 + tid;
            gload16(Bb + (size_t)(c >> 3) * K + k0 + (c & 7) * 8,
                    &Bs[buf][(i * 256 + w * 64) * 8], lane);
        }
    };

    loadA(0); writeA(0); stageB(0, 0);
    __syncthreads();
    int cur = 0;
    for (int t = 0; t < NT; ++t) {
        if (t + 1 < NT) { loadA(t + 1); stageB(cur ^ 1, t + 1); }  // issue early
        bf16x8 af[4][2], bfr[4][2];
        #pragma unroll
        for (int f = 0; f < 4; ++f)
            #pragma unroll
            for (int s = 0; s < 2; ++s) {
                af[f][s]  = *(const bf16x8*)&As[cur][(wm + f * 16 + lo) * BKK + s * 32 + hi * 8];
                bfr[f][s] = *(const bf16x8*)&Bs[cur][(wn + f * 16 + lo) * BKK + s * 32 + hi * 8];
            }
        #pragma unroll
        for (int s = 0; s < 2; ++s)
            #pragma unroll
            for (int fm = 0; fm < 4; ++fm)
                #pragma unroll
                for (int fn = 0; fn < 4; ++fn)
                    acc[fm][fn] = __builtin_amdgcn_mfma_f32_16x16x32_bf16(
                        af[fm][s], bfr[fn][s], acc[fm][fn], 0, 0, 0);
        if (t + 1 < NT) writeA(cur ^ 1);   // write late: HBM latency hidden by MFMAs
        __syncthreads();
        cur ^= 1;
    }

    #pragma unroll
    for (int fm = 0; fm < 4; ++fm) {
        const int row = m0 + wm + fm * 16 + hi * 4;
        #pragma unroll
        for (int fn = 0; fn < 4; ++fn) {
            const int col = n0 + wn + fn * 16 + lo;
            const float bv = bias[col];
            #pragma unroll
            for (int r = 0; r < 4; ++r) {
                float o = acc[fm][fn][r] + bv;
                if (z == 0) o *= SCLF;            // fold softmax scale into Q
                if (z < 2)
                    C[(size_t)(row + r) * N + col] = f2bf(o);
                else
                    C[(size_t)((row + r) >> 11) * 2097152
                      + (size_t)col * 2048 + ((row + r) & 2047)] = f2bf(o);
            }
        }
    }
}

// ---------------------------------------------------------------------------
// Out-projection GEMM: 128x64 tile, m-major grid (x = m-tile) for A L2 reuse.
// fp32 out + residual add.
// ---------------------------------------------------------------------------
__global__ __launch_bounds__(256) void gemm_out64(
    const unsigned short* __restrict__ A, const unsigned short* __restrict__ Bt,
    const float* __restrict__ bias, const float* __restrict__ resid,
    float* __restrict__ C)
{
    const int K = D_MODEL, N = D_MODEL;
    __shared__ unsigned short As[2][128 * BKK];
    __shared__ unsigned short Bs[2][64 * BKK];
    const int tid  = threadIdx.x;
    const int w    = tid >> 6;
    const int lane = tid & 63;
    const int lo   = lane & 15;
    const int hi   = lane >> 4;
    const int wm   = (w >> 1) * 64;
    const int wn   = (w & 1) * 32;
    const int m0   = blockIdx.x * 128;   // m-major
    const int n0   = blockIdx.y * 64;

    const unsigned short* Ab = A  + (size_t)m0 * K;
    const unsigned short* Bb = Bt + (size_t)n0 * K;

    f32x4 acc[4][2];
    #pragma unroll
    for (int i = 0; i < 4; ++i)
        #pragma unroll
        for (int j = 0; j < 2; ++j) acc[i][j] = (f32x4){0.f, 0.f, 0.f, 0.f};

    const int NT = K / BKK;
    auto stage = [&](int buf, int t) {
        const int k0 = t * BKK;
        #pragma unroll
        for (int i = 0; i < 4; ++i) {
            const int c = i * 256 + tid;
            gload16(Ab + (size_t)(c >> 3) * K + k0 + (c & 7) * 8,
                    &As[buf][(i * 256 + w * 64) * 8], lane);
        }
        #pragma unroll
        for (int i = 0; i < 2; ++i) {
            const int c = i * 256 + tid;
            gload16(Bb + (size_t)(c >> 3) * K + k0 + (c & 7) * 8,
                    &Bs[buf][(i * 256 + w * 64) * 8], lane);
        }
    };

    stage(0, 0);
    __syncthreads();
    int cur = 0;
    for (int t = 0; t < NT; ++t) {
        if (t + 1 < NT) stage(cur ^ 1, t + 1);
        bf16x8 af[4][2], bfr[2][2];
        #pragma unroll
        for (int f = 0; f < 4; ++f)
            #pragma unroll
            for (int s = 0; s < 2; ++s)
                af[f][s] = *(const bf16x8*)&As[cur][(wm + f * 16 + lo) * BKK + s * 32 + hi * 8];
        #pragma unroll
        for (int f = 0; f < 2; ++f)
            #pragma unroll
            for (int s = 0; s < 2; ++s)
                bfr[f][s] = *(const bf16x8*)&Bs[cur][(wn + f * 16 + lo) * BKK + s * 32 + hi * 8];
        #pragma unroll
        for (int s = 0; s < 2; ++s)
            #pragma unroll
            for (int fm = 0; fm < 4; ++fm)
                #pragma unroll
                for (int fn = 0; fn < 2; ++fn)
                    acc[fm][fn] = __builtin_amdgcn_mfma_f32_16x16x32_bf16(
                        af[fm][s], bfr[fn][s], acc[fm][fn], 0, 0, 0);
        __syncthreads();
        cur ^= 1;
    }

    #pragma unroll
    for (int fm = 0; fm < 4; ++fm) {
        const int row = m0 + wm + fm * 16 + hi * 4;
        #pragma unroll
        for (int fn = 0; fn < 2; ++fn) {
            const int col = n0 + wn + fn * 16 + lo;
            const float bv = bias[col];
            #pragma unroll
            for (int r = 0; r < 4; ++r)
                C[(size_t)(row + r) * N + col] =
                    acc[fm][fn][r] + bv + resid[(size_t)(row + r) * N + col];
        }
    }
}

// ---------------------------------------------------------------------------
// Swapped-QK^T 32x32 MFMA flash attention with in-block K-split.
// Grid is h-major (x = head, y = q-tile): all 16 q-blocks of one (b,h) share
// an XCD -> K/V slices fetched once per XCD instead of 16x.
// Block: 8 waves = 2 k-groups (g) x 4 q-waves (wq).
// ---------------------------------------------------------------------------
__global__ __launch_bounds__(512, 2) void attn_mfma32(
    const unsigned short* __restrict__ qb, const unsigned short* __restrict__ kbm,
    const unsigned short* __restrict__ vt,
    const unsigned long long* __restrict__ mbits, unsigned short* __restrict__ ctx)
{
    __shared__ unsigned char smem[65536];   // [0,32K): K staging; [32K,64K): V staging
    const int tid  = threadIdx.x;
    const int w8   = tid >> 6;
    const int g    = w8 >> 2;        // k-group (0: tiles 0..15, 1: tiles 16..31)
    const int wq   = w8 & 3;         // q-wave within group
    const int lane = tid & 63;
    const int l31  = lane & 31;
    const int hi   = lane >> 5;
    const int h    = blockIdx.x;     // h-major for K/V L2 locality
    const int q0   = blockIdx.y * 128;
    const int b    = blockIdx.z;

    unsigned short* KsG = (unsigned short*)smem + (size_t)g * 8192;            // [buf][4096]
    unsigned short* VsG = (unsigned short*)(smem + 32768) + (size_t)g * 8192;  // [buf][4096]

    const size_t qkbase = (size_t)b * SEQ * D_MODEL + (size_t)h * DHEAD;
    const size_t vtbase = ((size_t)b * D_MODEL + h * DHEAD) * SEQ;

    const int qtok = q0 + wq * 32 + l31;
    bf16x8 qA[4];
    #pragma unroll
    for (int s = 0; s < 4; ++s)
        qA[s] = *(const bf16x8*)(qb + qkbase + (size_t)qtok * D_MODEL + s * 16 + hi * 8);

    f32x16 o0 = {}, o1 = {};
    float m_i = -INFINITY, l_i = 0.f;

    const unsigned long long* mrow = mbits + ((size_t)b * SEQ + qtok) * (SEQ / 64);

    const int srow = lane >> 3;
    const int sc   = lane & 7;
    const int r0   = wq * 16 + srow;          // row-in-tile for this lane (cc=0)
    const int swz  = sc ^ (r0 & 7);           // (r0+8)&7 == r0&7, shared by cc=1

    // incremental per-tile staging pointers
    const unsigned short* kl0 = kbm + qkbase + (size_t)(g * 1024 + r0) * D_MODEL + swz * 8;
    const unsigned short* kl1 = kl0 + (size_t)8 * D_MODEL;
    const unsigned short* vl0 = vt + vtbase + (size_t)r0 * SEQ + g * 1024 + swz * 8;
    const unsigned short* vl1 = vl0 + (size_t)8 * SEQ;
    const int ldk0 = (wq * 16) * 64;
    const int ldk1 = (wq * 16 + 8) * 64;

    auto stage = [&](int buf) {
        gload16(kl0, &KsG[buf * 4096 + ldk0], lane);
        gload16(kl1, &KsG[buf * 4096 + ldk1], lane);
        gload16(vl0, &VsG[buf * 4096 + ldk0], lane);
        gload16(vl1, &VsG[buf * 4096 + ldk1], lane);
        kl0 += (size_t)64 * D_MODEL;
        kl1 += (size_t)64 * D_MODEL;
        vl0 += 64;
        vl1 += 64;
    };

    stage(0);
    unsigned long long mw64 = mrow[g * 16];     // prefetch tile 0's mask word
    __syncthreads();
    int cur = 0;

    for (int t = 0; t < 16; ++t) {
        if (t + 1 < 16) stage(cur ^ 1);
        const unsigned long long mwc = mw64;
        if (t + 1 < 16) mw64 = mrow[g * 16 + t + 1];   // prefetch next
        const unsigned int ml = (unsigned int)(mwc >> (4 * hi));
        const unsigned int mh = (unsigned int)(mwc >> (32 + 4 * hi));

        // ---- QK^T (pre-scaled Q): S^T[key][q] ----
        f32x16 st0 = {}, st1 = {};
        __builtin_amdgcn_s_setprio(1);
        #pragma unroll
        for (int s = 0; s < 4; ++s) {
            bf16x8 kf0 = *(const bf16x8*)&KsG[cur * 4096 + l31 * 64 + ((2 * s + hi) ^ (l31 & 7)) * 8];
            st0 = __builtin_amdgcn_mfma_f32_32x32x16_bf16(kf0, qA[s], st0, 0, 0, 0);
            bf16x8 kf1 = *(const bf16x8*)&KsG[cur * 4096 + (32 + l31) * 64 + ((2 * s + hi) ^ (l31 & 7)) * 8];
            st1 = __builtin_amdgcn_mfma_f32_32x32x16_bf16(kf1, qA[s], st1, 0, 0, 0);
        }
        __builtin_amdgcn_s_setprio(0);

        // ---- mask + lane-local max (4-partial tree) ----
        float rx[4] = {-3.0e38f, -3.0e38f, -3.0e38f, -3.0e38f};
        #pragma unroll
        for (int r = 0; r < 16; ++r) {
            const int klo = (r & 3) + 8 * (r >> 2);
            float x0 = st0[r], x1 = st1[r];
            if ((ml >> klo) & 1u) x0 = -1e9f;
            if ((mh >> klo) & 1u) x1 = -1e9f;
            st0[r] = x0; st1[r] = x1;
            rx[r & 3] = fmaxf(rx[r & 3], fmaxf(x0, x1));
        }
        float rmax = fmaxf(fmaxf(rx[0], rx[1]), fmaxf(rx[2], rx[3]));
        rmax = fmaxf(rmax, __shfl_xor(rmax, 32, 64));

        // ---- defer-max (T13) ----
        const bool defer = (bool)__all(rmax - m_i <= 8.0f);
        float alpha = 1.f;
        if (!defer) {
            const float mn = fmaxf(m_i, rmax);
            alpha = exp2f(m_i - mn);
            m_i = mn;
        }
        float sp[4] = {0.f, 0.f, 0.f, 0.f};
        #pragma unroll
        for (int r = 0; r < 16; ++r) {
            float e0 = exp2f(st0[r] - m_i);
            float e1 = exp2f(st1[r] - m_i);
            st0[r] = e0; st1[r] = e1;
            sp[r & 3] += e0 + e1;
        }
        float ls = (sp[0] + sp[1]) + (sp[2] + sp[3]);
        ls += __shfl_xor(ls, 32, 64);
        if (!defer) {
            l_i = l_i * alpha + ls;
            #pragma unroll
            for (int r = 0; r < 16; ++r) {
                const float aq = __shfl(alpha, (r & 3) + 8 * (r >> 2) + 4 * hi, 64);
                o0[r] *= aq; o1[r] *= aq;
            }
        } else {
            l_i += ls;
        }

        // ---- P -> bf16 A-frags (T12) ----
        bf16x8 pa[4];
        #pragma unroll
        for (int s = 0; s < 4; ++s) {
            const int base = (s & 1) * 8;
            unsigned av, bv2, cv, dv;
            if (s < 2) {
                av  = cvtpk_bf16(st0[base + 0], st0[base + 1]);
                bv2 = cvtpk_bf16(st0[base + 4], st0[base + 5]);
                cv  = cvtpk_bf16(st0[base + 2], st0[base + 3]);
                dv  = cvtpk_bf16(st0[base + 6], st0[base + 7]);
            } else {
                av  = cvtpk_bf16(st1[base + 0], st1[base + 1]);
                bv2 = cvtpk_bf16(st1[base + 4], st1[base + 5]);
                cv  = cvtpk_bf16(st1[base + 2], st1[base + 3]);
                dv  = cvtpk_bf16(st1[base + 6], st1[base + 7]);
            }
            asm("v_permlane32_swap_b32 %0, %1" : "+v"(av), "+v"(bv2));
            asm("v_permlane32_swap_b32 %0, %1" : "+v"(cv), "+v"(dv));
            int4 pk = make_int4((int)av, (int)cv, (int)bv2, (int)dv);
            pa[s] = __builtin_bit_cast(bf16x8, pk);
        }

        // ---- PV ----
        __builtin_amdgcn_s_setprio(1);
        #pragma unroll
        for (int s = 0; s < 4; ++s) {
            bf16x8 vf0 = *(const bf16x8*)&VsG[cur * 4096 + l31 * 64 + ((2 * s + hi) ^ (l31 & 7)) * 8];
            o0 = __builtin_amdgcn_mfma_f32_32x32x16_bf16(pa[s], vf0, o0, 0, 0, 0);
            bf16x8 vf1 = *(const bf16x8*)&VsG[cur * 4096 + (32 + l31) * 64 + ((2 * s + hi) ^ (l31 & 7)) * 8];
            o1 = __builtin_amdgcn_mfma_f32_32x32x16_bf16(pa[s], vf1, o1, 0, 0, 0);
        }
        __builtin_amdgcn_s_setprio(0);
        __syncthreads();
        cur ^= 1;
    }

    // ---- flash-combine of the two k-group partials (reuse staging LDS) ----
    __syncthreads();
    float* comb = (float*)smem;          // [wq][lane][35] floats, stride 35 (odd)
    if (g == 1) {
        float* p = comb + (size_t)(wq * 64 + lane) * 35;
        #pragma unroll
        for (int r = 0; r < 16; ++r) { p[r] = o0[r]; p[16 + r] = o1[r]; }
        p[32] = m_i; p[33] = l_i;
    }
    __syncthreads();
    if (g == 0) {
        const float* p = comb + (size_t)(wq * 64 + lane) * 35;
        const float mb = p[32], lb = p[33];
        const float ms = fmaxf(m_i, mb);
        const float sa = exp2f(m_i - ms);
        const float sb = exp2f(mb - ms);
        const float inv = 1.f / (l_i * sa + lb * sb);
        #pragma unroll
        for (int r = 0; r < 16; ++r) {
            const int qloc = (r & 3) + 8 * (r >> 2) + 4 * hi;
            const float sar = __shfl(sa, qloc, 64);
            const float sbr = __shfl(sb, qloc, 64);
            const float ivr = __shfl(inv, qloc, 64);
            unsigned short* dst = ctx + qkbase + (size_t)(q0 + wq * 32 + qloc) * D_MODEL;
            dst[l31]      = f2bf((o0[r] * sar + p[r] * sbr) * ivr);
            dst[32 + l31] = f2bf((o1[r] * sar + p[16 + r] * sbr) * ivr);
        }
    }
}

// ---------------------------------------------------------------------------
// LayerNorm over last dim (1024). One block per row.
// ---------------------------------------------------------------------------
__global__ __launch_bounds__(256) void layernorm1024(
    const float* __restrict__ x, const float* __restrict__ gamma,
    const float* __restrict__ beta, float* __restrict__ out)
{
    const int row = blockIdx.x;
    const int tid = threadIdx.x;
    const float* xr = x + (size_t)row * D_MODEL;
    float4 v = *(const float4*)(xr + (tid << 2));
    float s = v.x + v.y + v.z + v.w;
    float q = v.x * v.x + v.y * v.y + v.z * v.z + v.w * v.w;
    #pragma unroll
    for (int off = 1; off < 64; off <<= 1) {
        s += __shfl_xor(s, off, 64);
        q += __shfl_xor(q, off, 64);
    }
    __shared__ float sw[4], qw_[4];
    const int wid = tid >> 6;
    if ((tid & 63) == 0) { sw[wid] = s; qw_[wid] = q; }
    __syncthreads();
    s = sw[0] + sw[1] + sw[2] + sw[3];
    q = qw_[0] + qw_[1] + qw_[2] + qw_[3];
    const float mu  = s * (1.f / D_MODEL);
    const float var = q * (1.f / D_MODEL) - mu * mu;
    const float a = var + 1e-5f;
    float inv = rsqrtf(a);
    inv = inv * (1.5f - 0.5f * a * inv * inv);
    float4 gg = *(const float4*)(gamma + (tid << 2));
    float4 bt = *(const float4*)(beta + (tid << 2));
    float4 o;
    o.x = (v.x - mu) * inv * gg.x + bt.x;
    o.y = (v.y - mu) * inv * gg.y + bt.y;
    o.z = (v.z - mu) * inv * gg.z + bt.z;
    o.w = (v.w - mu) * inv * gg.w + bt.w;
    *(float4*)(out + (size_t)row * D_MODEL + (tid << 2)) = o;
}

// ---------------------------------------------------------------------------
extern "C" void kernel_launch(void* const* d_in, const int* in_sizes, int n_in,
                              void* d_out, int out_size, void* d_ws, size_t ws_size,
                              hipStream_t stream)
{
    const float* Q    = (const float*)d_in[0];
    const float* K    = (const float*)d_in[1];
    const float* V    = (const float*)d_in[2];
    const void*  mask = d_in[3];
    const float* Wq   = (const float*)d_in[4];
    const float* bq   = (const float*)d_in[5];
    const float* Wk   = (const float*)d_in[6];
    const float* bk   = (const float*)d_in[7];
    const float* Wv   = (const float*)d_in[8];
    const float* bv   = (const float*)d_in[9];
    const float* Wo   = (const float*)d_in[10];
    const float* bo   = (const float*)d_in[11];
    const float* gam  = (const float*)d_in[12];
    const float* bet  = (const float*)d_in[13];
    float* out = (float*)d_out;

    const size_t NE = (size_t)MROWS * D_MODEL;           // 4,194,304 elems
    const size_t WE = (size_t)D_MODEL * D_MODEL;
    const size_t NMW = (size_t)BATCH * SEQ * (SEQ / 64); // 131072 mask words
    unsigned short* qb  = (unsigned short*)d_ws;
    unsigned short* kb  = qb + NE;
    unsigned short* vt  = kb + NE;                       // [b][h][d][tok]
    unsigned short* Wt0 = vt + NE;
    unsigned short* Wt1 = Wt0 + WE;
    unsigned short* Wt2 = Wt1 + WE;
    unsigned short* Wt3 = Wt2 + WE;
    unsigned long long* mbits = (unsigned long long*)(Wt3 + WE);
    int* mflags = (int*)(mbits + NMW);
    unsigned short* ctxb = (unsigned short*)(mflags + 16);
    float* outp = (float*)(ctxb + NE);
    if (ws_size < 6 * NE * 2 + 4 * WE * 2 + NMW * 8 + 64) return;

    hipMemsetAsync(mflags, 0, 2 * sizeof(int), stream);
    detect_mask_par<<<256, 256, 0, stream>>>((const unsigned int*)mask, 65536, mflags);
    pack_mask_ballot<<<2048, 256, 0, stream>>>(mask, mflags, mbits, (int)NMW);

    cvt_wT<<<dim3(16, 16, 4), 256, 0, stream>>>(Wq, Wk, Wv, Wo, Wt0, Wt1, Wt2, Wt3);

    gemm_qkv<<<dim3(32, 8, 3), 256, 0, stream>>>(Q, K, V, Wt0, Wt1, Wt2,
                                                 bq, bk, bv, qb, kb, vt);

    dim3 ag(NHEADS, SEQ / 128, BATCH);     // h-major: (16, 16, 2), 512 threads
    attn_mfma32<<<ag, 512, 0, stream>>>(qb, kb, vt, mbits, ctxb);

    gemm_out64<<<dim3(32, 16), 256, 0, stream>>>(ctxb, Wt3, bo, Q, outp);

    layernorm1024<<<MROWS, 256, 0, stream>>>(outp, gam, bet, out);
}